// Round 1
// baseline (939.790 us; speedup 1.0000x reference)
//
#include <hip/hip_runtime.h>
#include <hip/hip_bf16.h>

// ---------------------------------------------------------------------------
// Problem constants
// ---------------------------------------------------------------------------
#define TB 2
#define TT 2048
#define TC 1024
#define TH 16
#define TKV 4
#define THD 64
#define TE 8
#define TFE 1024
#define TFS 2048
#define NTOK 4096           // B*T
#define NSLOT 8192          // NTOK * K(=2)

typedef __attribute__((ext_vector_type(4))) float f32x4;
typedef __attribute__((ext_vector_type(8))) short s16x8;

__device__ __forceinline__ float bf2f(short s) {
    unsigned int u = ((unsigned int)(unsigned short)s) << 16;
    return __builtin_bit_cast(float, u);
}
__device__ __forceinline__ short f2bf(float f) {
    unsigned int u = __builtin_bit_cast(unsigned int, f);
    u = u + 0x7fffu + ((u >> 16) & 1u);     // RNE
    return (short)(u >> 16);
}

// ---------------------------------------------------------------------------
// Transpose + f32->bf16 convert:  in f32 [R][Cd] -> out bf16 [Cd][R], batched
// grid (Cd/32, R/32, batch), block 256
// ---------------------------------------------------------------------------
__global__ __launch_bounds__(256) void k_transp(const float* __restrict__ in,
                                                short* __restrict__ out,
                                                int R, int Cd,
                                                size_t bs_in, size_t bs_out) {
    __shared__ float tile[32][33];
    const float* ip = in + bs_in * blockIdx.z;
    short* op = out + bs_out * blockIdx.z;
    int tx = threadIdx.x & 31, ty = threadIdx.x >> 5;
    int r0 = blockIdx.y * 32, c0 = blockIdx.x * 32;
    #pragma unroll
    for (int r = ty; r < 32; r += 8)
        tile[r][tx] = ip[(size_t)(r0 + r) * Cd + c0 + tx];
    __syncthreads();
    #pragma unroll
    for (int r = ty; r < 32; r += 8)
        op[(size_t)(c0 + r) * R + r0 + tx] = f2bf(tile[tx][r]);
}

// ---------------------------------------------------------------------------
// RoPE table: [T][32][2] f32  (cos, sin)
// ---------------------------------------------------------------------------
__global__ void k_rope_table(float* __restrict__ rope) {
    int idx = blockIdx.x * 256 + threadIdx.x;
    if (idx >= TT * 32) return;
    int t = idx >> 5, i = idx & 31;
    float freq = expf(-(float)i * (1.0f / 32.0f) * 9.210340371976184f); // 10000^(-i/32)
    float ang = (float)t * freq;
    rope[idx * 2 + 0] = cosf(ang);
    rope[idx * 2 + 1] = sinf(ang);
}

// ---------------------------------------------------------------------------
// RMSNorm: f32 [4096][1024] -> bf16 [4096][1024].  block 256 = one row
// ---------------------------------------------------------------------------
__global__ __launch_bounds__(256) void k_rmsnorm(const float* __restrict__ x,
                                                 const float* __restrict__ w,
                                                 short* __restrict__ out) {
    int row = blockIdx.x, t = threadIdx.x;
    float4 v = ((const float4*)(x + (size_t)row * TC))[t];
    float ss = v.x * v.x + v.y * v.y + v.z * v.z + v.w * v.w;
    #pragma unroll
    for (int off = 32; off; off >>= 1) ss += __shfl_xor(ss, off);
    __shared__ float red[4];
    if ((t & 63) == 0) red[t >> 6] = ss;
    __syncthreads();
    float rs = rsqrtf((red[0] + red[1] + red[2] + red[3]) * (1.0f / 1024.0f) + 1e-6f);
    float4 wv = ((const float4*)w)[t];
    short4 o;
    o.x = f2bf(v.x * rs * wv.x);
    o.y = f2bf(v.y * rs * wv.y);
    o.z = f2bf(v.z * rs * wv.z);
    o.w = f2bf(v.w * rs * wv.w);
    ((short4*)(out + (size_t)row * TC))[t] = o;
}

// ---------------------------------------------------------------------------
// Plain 128x128 GEMM: C[M,N] = A[M,K](bf16) * Bt[N,K](bf16)
// EPI 0: out bf16 = acc;   EPI 1: out f32 = acc + resid
// grid (N/128, M/128), block 256
// ---------------------------------------------------------------------------
template <int EPI>
__global__ __launch_bounds__(256) void k_gemm128(const short* __restrict__ A,
                                                 const short* __restrict__ Bt,
                                                 void* __restrict__ outp,
                                                 const float* __restrict__ resid,
                                                 int M, int N, int K) {
    __shared__ short As[128 * 32];
    __shared__ short Bs[128 * 32];
    int tid = threadIdx.x;
    int brow = blockIdx.y * 128, bcol = blockIdx.x * 128;
    int wid = tid >> 6, lane = tid & 63;
    int wr = wid >> 1, wc = wid & 1, g = lane >> 4, c = lane & 15;
    int ar = tid >> 1, ac = (tid & 1) * 16;
    const short* Ap = A + (size_t)(brow + ar) * K + ac;
    const short* Bp = Bt + (size_t)(bcol + ar) * K + ac;
    f32x4 acc[4][4] = {};
    for (int kk = 0; kk < K; kk += 32) {
        __syncthreads();
        *(s16x8*)(As + ar * 32 + ac)     = *(const s16x8*)(Ap + kk);
        *(s16x8*)(As + ar * 32 + ac + 8) = *(const s16x8*)(Ap + kk + 8);
        *(s16x8*)(Bs + ar * 32 + ac)     = *(const s16x8*)(Bp + kk);
        *(s16x8*)(Bs + ar * 32 + ac + 8) = *(const s16x8*)(Bp + kk + 8);
        __syncthreads();
        s16x8 af[4], bf[4];
        #pragma unroll
        for (int m = 0; m < 4; m++) af[m] = *(const s16x8*)(As + (wr * 64 + m * 16 + c) * 32 + g * 8);
        #pragma unroll
        for (int n = 0; n < 4; n++) bf[n] = *(const s16x8*)(Bs + (wc * 64 + n * 16 + c) * 32 + g * 8);
        #pragma unroll
        for (int m = 0; m < 4; m++)
            #pragma unroll
            for (int n = 0; n < 4; n++)
                acc[m][n] = __builtin_amdgcn_mfma_f32_16x16x32_bf16(af[m], bf[n], acc[m][n], 0, 0, 0);
    }
    #pragma unroll
    for (int m = 0; m < 4; m++)
        #pragma unroll
        for (int n = 0; n < 4; n++)
            #pragma unroll
            for (int j = 0; j < 4; j++) {
                int row = brow + wr * 64 + m * 16 + g * 4 + j;
                int col = bcol + wc * 64 + n * 16 + c;
                float v = acc[m][n][j];
                if (EPI == 0)
                    ((short*)outp)[(size_t)row * N + col] = f2bf(v);
                else
                    ((float*)outp)[(size_t)row * N + col] = v + resid[(size_t)row * N + col];
            }
}

// ---------------------------------------------------------------------------
// RoPE apply + scatter to attention layouts.
//   qkv bf16 [4096][1536]  (q:0..1023, k:1024..1279, v:1280..1535)
//   -> q_r bf16 [B][H][T][HD], k_r bf16 [B][KV][T][HD], v_t bf16 [B][KV][HD][T]
// thread per (row, p) with p in [0,768): q pairs 512, k pairs 128, v pairs 128
// ---------------------------------------------------------------------------
__global__ void k_rope_apply(const short* __restrict__ qkv,
                             const float* __restrict__ rope,
                             short* __restrict__ q_r,
                             short* __restrict__ k_r,
                             short* __restrict__ v_t) {
    int idx = blockIdx.x * 256 + threadIdx.x;
    if (idx >= NTOK * 768) return;
    int row = idx / 768;
    int p = idx - row * 768;
    int b = row >> 11, t = row & 2047;
    const short* src = qkv + (size_t)row * 1536;
    if (p < 512) {            // q
        int h = p >> 5, i = p & 31;
        float x0 = bf2f(src[h * 64 + 2 * i]);
        float x1 = bf2f(src[h * 64 + 2 * i + 1]);
        float cs = rope[(t * 32 + i) * 2], sn = rope[(t * 32 + i) * 2 + 1];
        size_t o = ((size_t)(b * TH + h) * TT + t) * THD + 2 * i;
        q_r[o]     = f2bf(x0 * cs - x1 * sn);
        q_r[o + 1] = f2bf(x1 * cs + x0 * sn);
    } else if (p < 640) {     // k
        int pk = p - 512;
        int kv = pk >> 5, i = pk & 31;
        float x0 = bf2f(src[1024 + kv * 64 + 2 * i]);
        float x1 = bf2f(src[1024 + kv * 64 + 2 * i + 1]);
        float cs = rope[(t * 32 + i) * 2], sn = rope[(t * 32 + i) * 2 + 1];
        size_t o = ((size_t)(b * TKV + kv) * TT + t) * THD + 2 * i;
        k_r[o]     = f2bf(x0 * cs - x1 * sn);
        k_r[o + 1] = f2bf(x1 * cs + x0 * sn);
    } else {                  // v (transpose copy)
        int pv = p - 640;
        int kv = pv >> 5, i = pv & 31;
        int d = 2 * i;
        short v0 = src[1280 + kv * 64 + d];
        short v1 = src[1280 + kv * 64 + d + 1];
        size_t base = ((size_t)(b * TKV + kv) * THD + d) * TT + t;
        v_t[base]      = v0;
        v_t[base + TT] = v1;
    }
}

// ---------------------------------------------------------------------------
// Flash attention (causal, GQA).  grid (T/64, B*H), block 256 (4 waves).
// Wave w handles 16 q rows.  KV tile = 64 keys.
// ---------------------------------------------------------------------------
__global__ __launch_bounds__(256) void k_attn(const short* __restrict__ q_r,
                                              const short* __restrict__ k_r,
                                              const short* __restrict__ v_t,
                                              short* __restrict__ attn_o) {
    int qb = blockIdx.x;
    int bh = blockIdx.y;
    int b = bh >> 4, h = bh & 15, kv = h >> 2;
    int tid = threadIdx.x;
    int w = tid >> 6, lane = tid & 63, g = lane >> 4, c = lane & 15;
    int qrow = qb * 64 + w * 16;

    const short* qp = q_r + ((size_t)(b * TH + h) * TT + qrow) * THD;
    const short* kp = k_r + ((size_t)(b * TKV + kv) * TT) * THD;
    const short* vp = v_t + ((size_t)(b * TKV + kv) * THD) * TT;

    s16x8 aq[2];
    aq[0] = *(const s16x8*)(qp + c * THD + g * 8);
    aq[1] = *(const s16x8*)(qp + c * THD + 32 + g * 8);

    f32x4 o[4] = {};
    float m[4]  = {-1e30f, -1e30f, -1e30f, -1e30f};
    float lsum[4] = {0.f, 0.f, 0.f, 0.f};

    __shared__ short pbuf[4][16 * 64];
    short* pb = &pbuf[w][0];

    for (int kt = 0; kt <= qb; ++kt) {
        const short* kpt = kp + (size_t)kt * 64 * THD;
        f32x4 S[4] = {};
        #pragma unroll
        for (int nt = 0; nt < 4; nt++) {
            s16x8 bk0 = *(const s16x8*)(kpt + (nt * 16 + c) * THD + g * 8);
            s16x8 bk1 = *(const s16x8*)(kpt + (nt * 16 + c) * THD + 32 + g * 8);
            S[nt] = __builtin_amdgcn_mfma_f32_16x16x32_bf16(aq[0], bk0, S[nt], 0, 0, 0);
            S[nt] = __builtin_amdgcn_mfma_f32_16x16x32_bf16(aq[1], bk1, S[nt], 0, 0, 0);
        }
        // scale + causal mask
        #pragma unroll
        for (int nt = 0; nt < 4; nt++)
            #pragma unroll
            for (int j = 0; j < 4; j++) {
                float s = S[nt][j] * 0.125f;
                if (kt == qb) {
                    int kpos = kt * 64 + nt * 16 + c;
                    int qpos = qb * 64 + w * 16 + g * 4 + j;
                    if (kpos > qpos) s = -1e30f;
                }
                S[nt][j] = s;
            }
        // row max (16 lanes of the group share a row-set)
        float mn[4];
        #pragma unroll
        for (int j = 0; j < 4; j++) {
            mn[j] = fmaxf(fmaxf(S[0][j], S[1][j]), fmaxf(S[2][j], S[3][j]));
            mn[j] = fmaxf(mn[j], __shfl_xor(mn[j], 1));
            mn[j] = fmaxf(mn[j], __shfl_xor(mn[j], 2));
            mn[j] = fmaxf(mn[j], __shfl_xor(mn[j], 4));
            mn[j] = fmaxf(mn[j], __shfl_xor(mn[j], 8));
        }
        #pragma unroll
        for (int j = 0; j < 4; j++) {
            float mnew = fmaxf(m[j], mn[j]);
            float al = __expf(m[j] - mnew);
            m[j] = mnew;
            lsum[j] *= al;
            #pragma unroll
            for (int nt = 0; nt < 4; nt++) o[nt][j] *= al;
        }
        float rsum[4] = {0.f, 0.f, 0.f, 0.f};
        #pragma unroll
        for (int nt = 0; nt < 4; nt++)
            #pragma unroll
            for (int j = 0; j < 4; j++) {
                float pv = __expf(S[nt][j] - m[j]);
                S[nt][j] = pv;
                rsum[j] += pv;
            }
        #pragma unroll
        for (int j = 0; j < 4; j++) {
            rsum[j] += __shfl_xor(rsum[j], 1);
            rsum[j] += __shfl_xor(rsum[j], 2);
            rsum[j] += __shfl_xor(rsum[j], 4);
            rsum[j] += __shfl_xor(rsum[j], 8);
            lsum[j] += rsum[j];
        }
        // P -> LDS (D-layout -> A-layout round trip)
        __syncthreads();
        #pragma unroll
        for (int nt = 0; nt < 4; nt++)
            #pragma unroll
            for (int j = 0; j < 4; j++)
                pb[(g * 4 + j) * 64 + nt * 16 + c] = f2bf(S[nt][j]);
        __syncthreads();
        s16x8 pa0 = *(const s16x8*)(pb + c * 64 + g * 8);
        s16x8 pa1 = *(const s16x8*)(pb + c * 64 + 32 + g * 8);
        #pragma unroll
        for (int nt = 0; nt < 4; nt++) {
            s16x8 bv0 = *(const s16x8*)(vp + (size_t)(nt * 16 + c) * TT + kt * 64 + g * 8);
            s16x8 bv1 = *(const s16x8*)(vp + (size_t)(nt * 16 + c) * TT + kt * 64 + 32 + g * 8);
            o[nt] = __builtin_amdgcn_mfma_f32_16x16x32_bf16(pa0, bv0, o[nt], 0, 0, 0);
            o[nt] = __builtin_amdgcn_mfma_f32_16x16x32_bf16(pa1, bv1, o[nt], 0, 0, 0);
        }
    }
    #pragma unroll
    for (int nt = 0; nt < 4; nt++)
        #pragma unroll
        for (int j = 0; j < 4; j++) {
            float v = o[nt][j] / lsum[j];
            attn_o[(size_t)(b * TT + qb * 64 + w * 16 + g * 4 + j) * TC + h * THD + nt * 16 + c] = f2bf(v);
        }
}

// ---------------------------------------------------------------------------
// Gate: f32 logits from x1 (recompute rms in f32), softmax, top-2, counts.
// block 256 = 4 waves = 4 tokens.
// ---------------------------------------------------------------------------
__global__ __launch_bounds__(256) void k_gate(const float* __restrict__ x1,
                                              const float* __restrict__ n2w,
                                              const float* __restrict__ gate_w,
                                              float* __restrict__ gl,
                                              int* __restrict__ cnt,
                                              int* __restrict__ te,
                                              int* __restrict__ tls,
                                              float* __restrict__ tw) {
    int w = threadIdx.x >> 6, lane = threadIdx.x & 63;
    int n = blockIdx.x * 4 + w;
    const float* xp = x1 + (size_t)n * TC;
    float ss = 0.f;
    for (int i = lane; i < TC; i += 64) { float v = xp[i]; ss += v * v; }
    #pragma unroll
    for (int off = 32; off; off >>= 1) ss += __shfl_xor(ss, off);
    float rs = rsqrtf(ss * (1.0f / 1024.0f) + 1e-6f);
    int e = lane & 7, ch = lane >> 3;
    float acc = 0.f;
    for (int i = 0; i < 128; i++) {
        int cc = ch * 128 + i;
        acc += xp[cc] * rs * n2w[cc] * gate_w[(size_t)cc * TE + e];
    }
    acc += __shfl_xor(acc, 8);
    acc += __shfl_xor(acc, 16);
    acc += __shfl_xor(acc, 32);
    float logit = acc;
    if (lane < 8) gl[(size_t)n * TE + lane] = logit;
    // softmax over 8 experts
    float mx = logit;
    mx = fmaxf(mx, __shfl_xor(mx, 1)); mx = fmaxf(mx, __shfl_xor(mx, 2)); mx = fmaxf(mx, __shfl_xor(mx, 4));
    float ex = __expf(logit - mx);
    float sm = ex;
    sm += __shfl_xor(sm, 1); sm += __shfl_xor(sm, 2); sm += __shfl_xor(sm, 4);
    float pp = ex / sm;
    // top-1
    float m1 = pp;
    m1 = fmaxf(m1, __shfl_xor(m1, 1)); m1 = fmaxf(m1, __shfl_xor(m1, 2)); m1 = fmaxf(m1, __shfl_xor(m1, 4));
    int cand = (pp == m1) ? e : 8;
    int e0 = cand;
    e0 = min(e0, __shfl_xor(e0, 1)); e0 = min(e0, __shfl_xor(e0, 2)); e0 = min(e0, __shfl_xor(e0, 4));
    // top-2
    float p2 = (e == e0) ? -1.0f : pp;
    float m2 = p2;
    m2 = fmaxf(m2, __shfl_xor(m2, 1)); m2 = fmaxf(m2, __shfl_xor(m2, 2)); m2 = fmaxf(m2, __shfl_xor(m2, 4));
    int cand2 = (p2 == m2) ? e : 8;
    int e1 = cand2;
    e1 = min(e1, __shfl_xor(e1, 1)); e1 = min(e1, __shfl_xor(e1, 2)); e1 = min(e1, __shfl_xor(e1, 4));
    if (lane == 0) {
        int ls0 = atomicAdd(&cnt[e0], 1);
        int ls1 = atomicAdd(&cnt[e1], 1);
        te[n * 2] = e0; te[n * 2 + 1] = e1;
        tls[n * 2] = ls0; tls[n * 2 + 1] = ls1;
        tw[n * 2] = m1; tw[n * 2 + 1] = m2;
    }
}

__global__ void k_prefix(const int* __restrict__ cnt, int* __restrict__ basep) {
    if (threadIdx.x == 0) {
        int s = 0;
        for (int e = 0; e < TE; e++) { basep[e] = s; s += cnt[e]; }
    }
}

__global__ void k_scatter(const int* __restrict__ te, const int* __restrict__ tls,
                          const float* __restrict__ tw, const int* __restrict__ basep,
                          int* __restrict__ tlist, float* __restrict__ slotw,
                          int* __restrict__ sot) {
    int n = blockIdx.x * 256 + threadIdx.x;
    if (n >= NTOK) return;
    int s0 = basep[te[n * 2]] + tls[n * 2];
    int s1 = basep[te[n * 2 + 1]] + tls[n * 2 + 1];
    tlist[s0] = n; tlist[s1] = n;
    slotw[s0] = tw[n * 2]; slotw[s1] = tw[n * 2 + 1];
    sot[n * 2] = s0; sot[n * 2 + 1] = s1;
}

// ---------------------------------------------------------------------------
// Dual GEMM (silu(A*B1t) * (A*B2t)), BM=128 BN=64, optionally gathered rows.
// GATHER=1: MoE expert FFN in (grid z = expert); GATHER=0: shared FFN.
// grid (N/64, ceil(M/128), E), block 256
// ---------------------------------------------------------------------------
template <int GATHER>
__global__ __launch_bounds__(256) void k_dual(const short* __restrict__ A,
                                              const short* __restrict__ B1t,
                                              const short* __restrict__ B2t,
                                              short* __restrict__ Out,
                                              const int* __restrict__ cnt,
                                              const int* __restrict__ basep,
                                              const int* __restrict__ tlist,
                                              const float* __restrict__ slotw,
                                              size_t wrows, int ldout, int K) {
    int e = blockIdx.z;
    int mt = blockIdx.y, nt = blockIdx.x;
    int ce = 0, base = 0;
    if (GATHER) {
        ce = cnt[e];
        if (mt * 128 >= ce) return;
        base = basep[e];
    }
    __shared__ short As[128 * 32];
    __shared__ short B1s[64 * 32];
    __shared__ short B2s[64 * 32];
    int tid = threadIdx.x, wid = tid >> 6, lane = tid & 63;
    int wr = wid >> 1, wc = wid & 1, g = lane >> 4, c = lane & 15;
    int ar = tid >> 1, ac = (tid & 1) * 16;
    int br = tid >> 2, bc = (tid & 3) * 8;
    size_t arow;
    if (GATHER) {
        int lr = mt * 128 + ar;
        if (lr >= ce) lr = 0;
        arow = (size_t)tlist[base + lr];
    } else {
        arow = (size_t)(mt * 128 + ar);
    }
    const short* Ap  = A + arow * (size_t)K + ac;
    const short* B1p = B1t + ((size_t)e * wrows + (size_t)(nt * 64 + br)) * K + bc;
    const short* B2p = B2t + ((size_t)e * wrows + (size_t)(nt * 64 + br)) * K + bc;
    f32x4 a1[4][2] = {}, a2[4][2] = {};
    for (int kk = 0; kk < K; kk += 32) {
        __syncthreads();
        *(s16x8*)(As + ar * 32 + ac)     = *(const s16x8*)(Ap + kk);
        *(s16x8*)(As + ar * 32 + ac + 8) = *(const s16x8*)(Ap + kk + 8);
        *(s16x8*)(B1s + br * 32 + bc)    = *(const s16x8*)(B1p + kk);
        *(s16x8*)(B2s + br * 32 + bc)    = *(const s16x8*)(B2p + kk);
        __syncthreads();
        s16x8 af[4], b1[2], b2[2];
        #pragma unroll
        for (int m2_ = 0; m2_ < 4; m2_++) af[m2_] = *(const s16x8*)(As + (wr * 64 + m2_ * 16 + c) * 32 + g * 8);
        #pragma unroll
        for (int n = 0; n < 2; n++) {
            b1[n] = *(const s16x8*)(B1s + (wc * 32 + n * 16 + c) * 32 + g * 8);
            b2[n] = *(const s16x8*)(B2s + (wc * 32 + n * 16 + c) * 32 + g * 8);
        }
        #pragma unroll
        for (int m_ = 0; m_ < 4; m_++)
            #pragma unroll
            for (int n = 0; n < 2; n++) {
                a1[m_][n] = __builtin_amdgcn_mfma_f32_16x16x32_bf16(af[m_], b1[n], a1[m_][n], 0, 0, 0);
                a2[m_][n] = __builtin_amdgcn_mfma_f32_16x16x32_bf16(af[m_], b2[n], a2[m_][n], 0, 0, 0);
            }
    }
    #pragma unroll
    for (int m_ = 0; m_ < 4; m_++)
        #pragma unroll
        for (int n = 0; n < 2; n++)
            #pragma unroll
            for (int j = 0; j < 4; j++) {
                int lrow = mt * 128 + wr * 64 + m_ * 16 + g * 4 + j;
                if (GATHER && lrow >= ce) continue;
                int col = nt * 64 + wc * 32 + n * 16 + c;
                float g1 = a1[m_][n][j], g2 = a2[m_][n][j];
                float v = g1 / (1.0f + __expf(-g1)) * g2;
                size_t orow = GATHER ? (size_t)(base + lrow) : (size_t)lrow;
                if (GATHER) v *= slotw[base + lrow];
                Out[orow * (size_t)ldout + col] = f2bf(v);
            }
}

// ---------------------------------------------------------------------------
// MoE down-proj per expert: ye[slot] = he[slot] @ wp_e  (bf16 out, weights folded)
// grid (1024/128, ceil(M/128), E)
// ---------------------------------------------------------------------------
__global__ __launch_bounds__(256) void k_moe2(const short* __restrict__ he,
                                              const short* __restrict__ Wpt,
                                              short* __restrict__ ye,
                                              const int* __restrict__ cnt,
                                              const int* __restrict__ basep) {
    int e = blockIdx.z;
    int ce = cnt[e];
    int mt = blockIdx.y;
    if (mt * 128 >= ce) return;
    int base = basep[e];
    int nt = blockIdx.x;
    __shared__ short As[128 * 32];
    __shared__ short Bs[128 * 32];
    int tid = threadIdx.x, wid = tid >> 6, lane = tid & 63;
    int wr = wid >> 1, wc = wid & 1, g = lane >> 4, c = lane & 15;
    int ar = tid >> 1, ac = (tid & 1) * 16;
    int lr = mt * 128 + ar;
    if (lr >= ce) lr = ce - 1;
    const short* Ap = he + (size_t)(base + lr) * TFE + ac;
    const short* Bp = Wpt + ((size_t)e * 1024 + nt * 128 + ar) * TFE + ac;
    f32x4 acc[4][4] = {};
    for (int kk = 0; kk < TFE; kk += 32) {
        __syncthreads();
        *(s16x8*)(As + ar * 32 + ac)     = *(const s16x8*)(Ap + kk);
        *(s16x8*)(As + ar * 32 + ac + 8) = *(const s16x8*)(Ap + kk + 8);
        *(s16x8*)(Bs + ar * 32 + ac)     = *(const s16x8*)(Bp + kk);
        *(s16x8*)(Bs + ar * 32 + ac + 8) = *(const s16x8*)(Bp + kk + 8);
        __syncthreads();
        s16x8 af[4], bf[4];
        #pragma unroll
        for (int m = 0; m < 4; m++) af[m] = *(const s16x8*)(As + (wr * 64 + m * 16 + c) * 32 + g * 8);
        #pragma unroll
        for (int n = 0; n < 4; n++) bf[n] = *(const s16x8*)(Bs + (wc * 64 + n * 16 + c) * 32 + g * 8);
        #pragma unroll
        for (int m = 0; m < 4; m++)
            #pragma unroll
            for (int n = 0; n < 4; n++)
                acc[m][n] = __builtin_amdgcn_mfma_f32_16x16x32_bf16(af[m], bf[n], acc[m][n], 0, 0, 0);
    }
    #pragma unroll
    for (int m = 0; m < 4; m++)
        #pragma unroll
        for (int n = 0; n < 4; n++)
            #pragma unroll
            for (int j = 0; j < 4; j++) {
                int lrow = mt * 128 + wr * 64 + m * 16 + g * 4 + j;
                if (lrow >= ce) continue;
                int col = nt * 128 + wc * 64 + n * 16 + c;
                ye[(size_t)(base + lrow) * TC + col] = f2bf(acc[m][n][j]);
            }
}

// ---------------------------------------------------------------------------
// Final: out = shm @ swp_t + x1 + ye[s0] + ye[s1].   M=4096 N=1024 K=2048
// ---------------------------------------------------------------------------
__global__ __launch_bounds__(256) void k_final(const short* __restrict__ A,
                                               const short* __restrict__ Bt,
                                               const float* __restrict__ x1,
                                               const short* __restrict__ ye,
                                               const int* __restrict__ sot,
                                               float* __restrict__ outp) {
    __shared__ short As[128 * 32];
    __shared__ short Bs[128 * 32];
    const int K = TFS;
    int tid = threadIdx.x;
    int brow = blockIdx.y * 128, bcol = blockIdx.x * 128;
    int wid = tid >> 6, lane = tid & 63;
    int wr = wid >> 1, wc = wid & 1, g = lane >> 4, c = lane & 15;
    int ar = tid >> 1, ac = (tid & 1) * 16;
    const short* Ap = A + (size_t)(brow + ar) * K + ac;
    const short* Bp = Bt + (size_t)(bcol + ar) * K + ac;
    f32x4 acc[4][4] = {};
    for (int kk = 0; kk < K; kk += 32) {
        __syncthreads();
        *(s16x8*)(As + ar * 32 + ac)     = *(const s16x8*)(Ap + kk);
        *(s16x8*)(As + ar * 32 + ac + 8) = *(const s16x8*)(Ap + kk + 8);
        *(s16x8*)(Bs + ar * 32 + ac)     = *(const s16x8*)(Bp + kk);
        *(s16x8*)(Bs + ar * 32 + ac + 8) = *(const s16x8*)(Bp + kk + 8);
        __syncthreads();
        s16x8 af[4], bf[4];
        #pragma unroll
        for (int m = 0; m < 4; m++) af[m] = *(const s16x8*)(As + (wr * 64 + m * 16 + c) * 32 + g * 8);
        #pragma unroll
        for (int n = 0; n < 4; n++) bf[n] = *(const s16x8*)(Bs + (wc * 64 + n * 16 + c) * 32 + g * 8);
        #pragma unroll
        for (int m = 0; m < 4; m++)
            #pragma unroll
            for (int n = 0; n < 4; n++)
                acc[m][n] = __builtin_amdgcn_mfma_f32_16x16x32_bf16(af[m], bf[n], acc[m][n], 0, 0, 0);
    }
    #pragma unroll
    for (int m = 0; m < 4; m++)
        #pragma unroll
        for (int n = 0; n < 4; n++)
            #pragma unroll
            for (int j = 0; j < 4; j++) {
                int row = brow + wr * 64 + m * 16 + g * 4 + j;
                int col = bcol + wc * 64 + n * 16 + c;
                int s0 = sot[row * 2], s1 = sot[row * 2 + 1];
                float v = acc[m][n][j] + x1[(size_t)row * TC + col]
                        + bf2f(ye[(size_t)s0 * TC + col]) + bf2f(ye[(size_t)s1 * TC + col]);
                outp[(size_t)row * TC + col] = v;
            }
}

// ---------------------------------------------------------------------------
// Launch
// ---------------------------------------------------------------------------
extern "C" void kernel_launch(void* const* d_in, const int* in_sizes, int n_in,
                              void* d_out, int out_size, void* d_ws, size_t ws_size,
                              hipStream_t stream) {
    const float* x     = (const float*)d_in[0];
    const float* n1w   = (const float*)d_in[1];
    const float* n2w   = (const float*)d_in[2];
    const float* wq    = (const float*)d_in[3];
    const float* wk    = (const float*)d_in[4];
    const float* wv    = (const float*)d_in[5];
    const float* wo    = (const float*)d_in[6];
    const float* gatew = (const float*)d_in[7];
    const float* ew1   = (const float*)d_in[8];
    const float* ew2   = (const float*)d_in[9];
    const float* ewp   = (const float*)d_in[10];
    const float* sw1   = (const float*)d_in[11];
    const float* sw2   = (const float*)d_in[12];
    const float* swp   = (const float*)d_in[13];
    float* outp = (float*)d_out;

    char* p = (char*)d_ws;
    auto alloc = [&](size_t bytes) -> char* {
        char* r = p;
        p += (bytes + 255) & ~(size_t)255;
        return r;
    };
    short* wqkv_t = (short*)alloc(1536 * 1024 * 2);   // [1536][1024]
    short* wo_t   = (short*)alloc(1024 * 1024 * 2);   // [1024][1024]
    short* ew1_t  = (short*)alloc((size_t)8 * 1024 * 1024 * 2); // [E][FE][C]
    short* ew2_t  = (short*)alloc((size_t)8 * 1024 * 1024 * 2);
    short* ewp_t  = (short*)alloc((size_t)8 * 1024 * 1024 * 2); // [E][C][FE]
    short* sw1_t  = (short*)alloc((size_t)2048 * 1024 * 2);     // [2048][1024]
    short* sw2_t  = (short*)alloc((size_t)2048 * 1024 * 2);
    short* swp_t  = (short*)alloc((size_t)1024 * 2048 * 2);     // [1024][2048]
    short* h1     = (short*)alloc((size_t)NTOK * 1024 * 2);
    short* qkv    = (short*)alloc((size_t)NTOK * 1536 * 2);
    short* q_r    = (short*)alloc((size_t)TB * TH * TT * THD * 2);
    short* k_r    = (short*)alloc((size_t)TB * TKV * TT * THD * 2);
    short* v_t    = (short*)alloc((size_t)TB * TKV * THD * TT * 2);
    short* attn_o = (short*)alloc((size_t)NTOK * 1024 * 2);
    float* x1     = (float*)alloc((size_t)NTOK * 1024 * 4);
    short* h2     = (short*)alloc((size_t)NTOK * 1024 * 2);
    float* rope   = (float*)alloc((size_t)TT * 32 * 2 * 4);
    int*   cnt    = (int*)alloc(256);
    int*   basep  = (int*)alloc(256);
    int*   te     = (int*)alloc((size_t)NTOK * 2 * 4);
    int*   tls    = (int*)alloc((size_t)NTOK * 2 * 4);
    float* tw     = (float*)alloc((size_t)NTOK * 2 * 4);
    int*   tlist  = (int*)alloc((size_t)NSLOT * 4);
    float* slotw  = (float*)alloc((size_t)NSLOT * 4);
    int*   sot    = (int*)alloc((size_t)NTOK * 2 * 4);
    short* he     = (short*)alloc((size_t)NSLOT * TFE * 2);
    short* ye     = (short*)alloc((size_t)NSLOT * TC * 2);
    short* shm    = (short*)alloc((size_t)NTOK * TFS * 2);

    dim3 blk(256);

    // weight transposes (f32 -> bf16, [K][N] -> [N][K])
    k_transp<<<dim3(32, 32, 1), blk, 0, stream>>>(wq, wqkv_t, 1024, 1024, 0, 0);
    k_transp<<<dim3(8, 32, 1), blk, 0, stream>>>(wk, wqkv_t + 1024 * 1024, 1024, 256, 0, 0);
    k_transp<<<dim3(8, 32, 1), blk, 0, stream>>>(wv, wqkv_t + 1280 * 1024, 1024, 256, 0, 0);
    k_transp<<<dim3(32, 32, 1), blk, 0, stream>>>(wo, wo_t, 1024, 1024, 0, 0);
    k_transp<<<dim3(32, 32, 8), blk, 0, stream>>>(ew1, ew1_t, 1024, 1024, 1048576, 1048576);
    k_transp<<<dim3(32, 32, 8), blk, 0, stream>>>(ew2, ew2_t, 1024, 1024, 1048576, 1048576);
    k_transp<<<dim3(32, 32, 8), blk, 0, stream>>>(ewp, ewp_t, 1024, 1024, 1048576, 1048576);
    k_transp<<<dim3(64, 32, 1), blk, 0, stream>>>(sw1, sw1_t, 1024, 2048, 0, 0);
    k_transp<<<dim3(64, 32, 1), blk, 0, stream>>>(sw2, sw2_t, 1024, 2048, 0, 0);
    k_transp<<<dim3(32, 64, 1), blk, 0, stream>>>(swp, swp_t, 2048, 1024, 0, 0);

    k_rope_table<<<(TT * 32 + 255) / 256, blk, 0, stream>>>(rope);

    // norm1 + QKV
    k_rmsnorm<<<NTOK, blk, 0, stream>>>(x, n1w, h1);
    k_gemm128<0><<<dim3(12, 32), blk, 0, stream>>>(h1, wqkv_t, qkv, nullptr, NTOK, 1536, 1024);
    k_rope_apply<<<(NTOK * 768 + 255) / 256, blk, 0, stream>>>(qkv, rope, q_r, k_r, v_t);

    // attention
    k_attn<<<dim3(TT / 64, TB * TH), blk, 0, stream>>>(q_r, k_r, v_t, attn_o);

    // wo projection + residual
    k_gemm128<1><<<dim3(8, 32), blk, 0, stream>>>(attn_o, wo_t, x1, x, NTOK, 1024, 1024);

    // norm2
    k_rmsnorm<<<NTOK, blk, 0, stream>>>(x1, n2w, h2);

    // gating
    hipMemsetAsync(cnt, 0, 64, stream);
    k_gate<<<NTOK / 4, blk, 0, stream>>>(x1, n2w, gatew, outp + (size_t)NTOK * TC, cnt, te, tls, tw);
    k_prefix<<<1, 64, 0, stream>>>(cnt, basep);
    k_scatter<<<NTOK / 256, blk, 0, stream>>>(te, tls, tw, basep, tlist, slotw, sot);

    // MoE expert FFN (gathered, dual, silu-mul, weight folded)
    k_dual<1><<<dim3(16, 32, 8), blk, 0, stream>>>(h2, ew1_t, ew2_t, he, cnt, basep, tlist, slotw,
                                                   1024, TFE, 1024);
    k_moe2<<<dim3(8, 32, 8), blk, 0, stream>>>(he, ewp_t, ye, cnt, basep);

    // shared FFN
    k_dual<0><<<dim3(32, 32, 1), blk, 0, stream>>>(h2, sw1_t, sw2_t, shm, nullptr, nullptr, nullptr,
                                                   nullptr, 0, TFS, 1024);

    // final down-proj + residual + MoE combine
    k_final<<<dim3(8, 32), blk, 0, stream>>>(shm, swp_t, x1, ye, sot, outp);

    (void)in_sizes; (void)n_in; (void)out_size; (void)ws_size;
}

// Round 2
// 846.863 us; speedup vs baseline: 1.1097x; 1.1097x over previous
//
#include <hip/hip_runtime.h>
#include <hip/hip_bf16.h>

// ---------------------------------------------------------------------------
// Problem constants
// ---------------------------------------------------------------------------
#define TB 2
#define TT 2048
#define TC 1024
#define TH 16
#define TKV 4
#define THD 64
#define TE 8
#define TFE 1024
#define TFS 2048
#define NTOK 4096           // B*T
#define NSLOT 8192          // NTOK * K(=2)

typedef __attribute__((ext_vector_type(4))) float f32x4;
typedef __attribute__((ext_vector_type(8))) short s16x8;

__device__ __forceinline__ float bf2f(short s) {
    unsigned int u = ((unsigned int)(unsigned short)s) << 16;
    return __builtin_bit_cast(float, u);
}
__device__ __forceinline__ short f2bf(float f) {
    unsigned int u = __builtin_bit_cast(unsigned int, f);
    u = u + 0x7fffu + ((u >> 16) & 1u);     // RNE
    return (short)(u >> 16);
}

// async global->LDS, 16B per lane. lds ptr must be wave-uniform base;
// HW writes lane l's 16B to base + l*16. Global source is per-lane.
__device__ __forceinline__ void gl_lds16(const void* g, void* l) {
    __builtin_amdgcn_global_load_lds((const __attribute__((address_space(1))) void*)g,
                                     (__attribute__((address_space(3))) void*)l,
                                     16, 0, 0);
}

// ---------------------------------------------------------------------------
// Transpose + f32->bf16 convert:  in f32 [R][Cd] -> out bf16 [Cd][R], batched
// grid (Cd/32, R/32, batch), block 256
// ---------------------------------------------------------------------------
__global__ __launch_bounds__(256) void k_transp(const float* __restrict__ in,
                                                short* __restrict__ out,
                                                int R, int Cd,
                                                size_t bs_in, size_t bs_out) {
    __shared__ float tile[32][33];
    const float* ip = in + bs_in * blockIdx.z;
    short* op = out + bs_out * blockIdx.z;
    int tx = threadIdx.x & 31, ty = threadIdx.x >> 5;
    int r0 = blockIdx.y * 32, c0 = blockIdx.x * 32;
    #pragma unroll
    for (int r = ty; r < 32; r += 8)
        tile[r][tx] = ip[(size_t)(r0 + r) * Cd + c0 + tx];
    __syncthreads();
    #pragma unroll
    for (int r = ty; r < 32; r += 8)
        op[(size_t)(c0 + r) * R + r0 + tx] = f2bf(tile[tx][r]);
}

// ---------------------------------------------------------------------------
// V transpose (bf16 -> bf16): qkv v-columns [T][64] per (b,kv) -> v_t [64][T]
// grid (2, 64, 8=b*4+kv), block 256
// ---------------------------------------------------------------------------
__global__ __launch_bounds__(256) void k_transp_v(const short* __restrict__ qkv,
                                                  short* __restrict__ v_t) {
    __shared__ short tile[32][33];
    int z = blockIdx.z;
    int b = z >> 2, kvh = z & 3;
    const short* ip = qkv + (size_t)b * TT * 1536 + 1280 + kvh * 64;
    short* op = v_t + (size_t)z * THD * TT;
    int tx = threadIdx.x & 31, ty = threadIdx.x >> 5;
    int t0 = blockIdx.y * 32, d0 = blockIdx.x * 32;
    #pragma unroll
    for (int r = ty; r < 32; r += 8)
        tile[r][tx] = ip[(size_t)(t0 + r) * 1536 + d0 + tx];
    __syncthreads();
    #pragma unroll
    for (int r = ty; r < 32; r += 8)
        op[(size_t)(d0 + r) * TT + t0 + tx] = tile[tx][r];
}

// ---------------------------------------------------------------------------
// RoPE table: [T][32][2] f32  (cos, sin)
// ---------------------------------------------------------------------------
__global__ void k_rope_table(float* __restrict__ rope) {
    int idx = blockIdx.x * 256 + threadIdx.x;
    if (idx >= TT * 32) return;
    int t = idx >> 5, i = idx & 31;
    float freq = expf(-(float)i * (1.0f / 32.0f) * 9.210340371976184f); // 10000^(-i/32)
    float ang = (float)t * freq;
    rope[idx * 2 + 0] = cosf(ang);
    rope[idx * 2 + 1] = sinf(ang);
}

// ---------------------------------------------------------------------------
// RMSNorm: f32 [4096][1024] -> bf16 [4096][1024].  block 256 = one row
// ---------------------------------------------------------------------------
__global__ __launch_bounds__(256) void k_rmsnorm(const float* __restrict__ x,
                                                 const float* __restrict__ w,
                                                 short* __restrict__ out) {
    int row = blockIdx.x, t = threadIdx.x;
    float4 v = ((const float4*)(x + (size_t)row * TC))[t];
    float ss = v.x * v.x + v.y * v.y + v.z * v.z + v.w * v.w;
    #pragma unroll
    for (int off = 32; off; off >>= 1) ss += __shfl_xor(ss, off);
    __shared__ float red[4];
    if ((t & 63) == 0) red[t >> 6] = ss;
    __syncthreads();
    float rs = rsqrtf((red[0] + red[1] + red[2] + red[3]) * (1.0f / 1024.0f) + 1e-6f);
    float4 wv = ((const float4*)w)[t];
    short4 o;
    o.x = f2bf(v.x * rs * wv.x);
    o.y = f2bf(v.y * rs * wv.y);
    o.z = f2bf(v.z * rs * wv.z);
    o.w = f2bf(v.w * rs * wv.w);
    ((short4*)(out + (size_t)row * TC))[t] = o;
}

// ---------------------------------------------------------------------------
// 128x128 GEMM, global_load_lds staging (m97 pattern):
// C[M,N] = A[M,K](bf16) * Bt[N,K](bf16)
// EPI 0: out bf16 = acc;   EPI 1: out f32 = acc + resid
// grid (N/128, M/128), block 256
// ---------------------------------------------------------------------------
template <int EPI>
__global__ __launch_bounds__(256) void k_gemm128(const short* __restrict__ A,
                                                 const short* __restrict__ Bt,
                                                 void* __restrict__ outp,
                                                 const float* __restrict__ resid,
                                                 int M, int N, int K) {
    __shared__ short As[128 * 32];
    __shared__ short Bs[128 * 32];
    int tid = threadIdx.x;
    int brow = blockIdx.y * 128, bcol = blockIdx.x * 128;
    int wid = tid >> 6, lane = tid & 63;
    int wr = wid >> 1, wc = wid & 1, g = lane >> 4, c = lane & 15;
    // staging: wave wid covers LDS bytes [wid*2048, wid*2048+2048)
    int srow = wid * 32 + (lane >> 2);
    int scol = (lane & 3) * 8;
    const short* Ag0 = A + (size_t)(brow + srow) * K + scol;
    const short* Ag1 = A + (size_t)(brow + srow + 16) * K + scol;
    const short* Bg0 = Bt + (size_t)(bcol + srow) * K + scol;
    const short* Bg1 = Bt + (size_t)(bcol + srow + 16) * K + scol;
    int loff = __builtin_amdgcn_readfirstlane(wid * 2048);
    char* Al0 = (char*)As + loff;
    char* Bl0 = (char*)Bs + loff;
    f32x4 acc[4][4] = {};
    for (int kk = 0; kk < K; kk += 32) {
        __syncthreads();
        gl_lds16(Ag0 + kk, Al0);
        gl_lds16(Ag1 + kk, Al0 + 1024);
        gl_lds16(Bg0 + kk, Bl0);
        gl_lds16(Bg1 + kk, Bl0 + 1024);
        __syncthreads();
        s16x8 af[4], bf[4];
        #pragma unroll
        for (int m = 0; m < 4; m++) af[m] = *(const s16x8*)(As + (wr * 64 + m * 16 + c) * 32 + g * 8);
        #pragma unroll
        for (int n = 0; n < 4; n++) bf[n] = *(const s16x8*)(Bs + (wc * 64 + n * 16 + c) * 32 + g * 8);
        #pragma unroll
        for (int m = 0; m < 4; m++)
            #pragma unroll
            for (int n = 0; n < 4; n++)
                acc[m][n] = __builtin_amdgcn_mfma_f32_16x16x32_bf16(af[m], bf[n], acc[m][n], 0, 0, 0);
    }
    #pragma unroll
    for (int m = 0; m < 4; m++)
        #pragma unroll
        for (int n = 0; n < 4; n++)
            #pragma unroll
            for (int j = 0; j < 4; j++) {
                int row = brow + wr * 64 + m * 16 + g * 4 + j;
                int col = bcol + wc * 64 + n * 16 + c;
                float v = acc[m][n][j];
                if (EPI == 0)
                    ((short*)outp)[(size_t)row * N + col] = f2bf(v);
                else
                    ((float*)outp)[(size_t)row * N + col] = v + resid[(size_t)row * N + col];
            }
}

// ---------------------------------------------------------------------------
// RoPE apply + scatter (q, k only; v handled by k_transp_v).
//   qkv bf16 [4096][1536] -> q_r bf16 [B][H][T][HD], k_r bf16 [B][KV][T][HD]
// ---------------------------------------------------------------------------
__global__ void k_rope_apply(const short* __restrict__ qkv,
                             const float* __restrict__ rope,
                             short* __restrict__ q_r,
                             short* __restrict__ k_r) {
    int idx = blockIdx.x * 256 + threadIdx.x;
    if (idx >= NTOK * 640) return;
    int row = idx / 640;
    int p = idx - row * 640;
    int b = row >> 11, t = row & 2047;
    const short* src = qkv + (size_t)row * 1536;
    if (p < 512) {            // q
        int h = p >> 5, i = p & 31;
        float x0 = bf2f(src[h * 64 + 2 * i]);
        float x1 = bf2f(src[h * 64 + 2 * i + 1]);
        float cs = rope[(t * 32 + i) * 2], sn = rope[(t * 32 + i) * 2 + 1];
        size_t o = ((size_t)(b * TH + h) * TT + t) * THD + 2 * i;
        q_r[o]     = f2bf(x0 * cs - x1 * sn);
        q_r[o + 1] = f2bf(x1 * cs + x0 * sn);
    } else {                  // k
        int pk = p - 512;
        int kv = pk >> 5, i = pk & 31;
        float x0 = bf2f(src[1024 + kv * 64 + 2 * i]);
        float x1 = bf2f(src[1024 + kv * 64 + 2 * i + 1]);
        float cs = rope[(t * 32 + i) * 2], sn = rope[(t * 32 + i) * 2 + 1];
        size_t o = ((size_t)(b * TKV + kv) * TT + t) * THD + 2 * i;
        k_r[o]     = f2bf(x0 * cs - x1 * sn);
        k_r[o + 1] = f2bf(x1 * cs + x0 * sn);
    }
}

// ---------------------------------------------------------------------------
// Flash attention (causal, GQA).  grid (T/64, B*H), block 256 (4 waves).
// Wave-independent (no barriers). Reversed qb order (long blocks first).
// K fragments register-double-buffered; V issued at iteration top.
// P round-trip through XOR-swizzled per-wave LDS.
// ---------------------------------------------------------------------------
__global__ __launch_bounds__(256) void k_attn(const short* __restrict__ q_r,
                                              const short* __restrict__ k_r,
                                              const short* __restrict__ v_t,
                                              short* __restrict__ attn_o) {
    int qb = (TT / 64 - 1) - blockIdx.x;        // long blocks first
    int bh = blockIdx.y;
    int b = bh >> 4, h = bh & 15, kv = h >> 2;
    int tid = threadIdx.x;
    int w = tid >> 6, lane = tid & 63, g = lane >> 4, c = lane & 15;
    int qrow = qb * 64 + w * 16;

    const short* qp = q_r + ((size_t)(b * TH + h) * TT + qrow) * THD;
    const short* kp = k_r + ((size_t)(b * TKV + kv) * TT) * THD;
    const short* vp = v_t + ((size_t)(b * TKV + kv) * THD) * TT;

    s16x8 aq[2];
    aq[0] = *(const s16x8*)(qp + c * THD + g * 8);
    aq[1] = *(const s16x8*)(qp + c * THD + 32 + g * 8);

    f32x4 o[4] = {};
    float m[4]  = {-1e30f, -1e30f, -1e30f, -1e30f};
    float lsum[4] = {0.f, 0.f, 0.f, 0.f};

    __shared__ short pbuf[4][16 * 64];
    short* pb = &pbuf[w][0];

    s16x8 kcur[8], knext[8], vf[8];
    #pragma unroll
    for (int nt = 0; nt < 4; nt++) {
        kcur[nt * 2]     = *(const s16x8*)(kp + (nt * 16 + c) * THD + g * 8);
        kcur[nt * 2 + 1] = *(const s16x8*)(kp + (nt * 16 + c) * THD + 32 + g * 8);
    }

    for (int kt = 0; kt <= qb; ++kt) {
        // issue V (current tile) + K (next tile) loads early; they complete
        // under the S-MFMA + softmax chain below.
        #pragma unroll
        for (int nt = 0; nt < 4; nt++) {
            vf[nt * 2]     = *(const s16x8*)(vp + (size_t)(nt * 16 + c) * TT + kt * 64 + g * 8);
            vf[nt * 2 + 1] = *(const s16x8*)(vp + (size_t)(nt * 16 + c) * TT + kt * 64 + 32 + g * 8);
        }
        {
            int ktn = kt < qb ? kt + 1 : kt;
            const short* kpn = kp + (size_t)ktn * 64 * THD;
            #pragma unroll
            for (int nt = 0; nt < 4; nt++) {
                knext[nt * 2]     = *(const s16x8*)(kpn + (nt * 16 + c) * THD + g * 8);
                knext[nt * 2 + 1] = *(const s16x8*)(kpn + (nt * 16 + c) * THD + 32 + g * 8);
            }
        }
        f32x4 S[4] = {};
        #pragma unroll
        for (int nt = 0; nt < 4; nt++) {
            S[nt] = __builtin_amdgcn_mfma_f32_16x16x32_bf16(aq[0], kcur[nt * 2], S[nt], 0, 0, 0);
            S[nt] = __builtin_amdgcn_mfma_f32_16x16x32_bf16(aq[1], kcur[nt * 2 + 1], S[nt], 0, 0, 0);
        }
        // scale + causal mask
        #pragma unroll
        for (int nt = 0; nt < 4; nt++)
            #pragma unroll
            for (int j = 0; j < 4; j++) {
                float s = S[nt][j] * 0.125f;
                if (kt == qb) {
                    int kpos = nt * 16 + c;
                    int qpos = w * 16 + g * 4 + j;
                    if (kpos > qpos) s = -1e30f;
                }
                S[nt][j] = s;
            }
        // row max over 16 lanes of the c-group
        float mn[4];
        #pragma unroll
        for (int j = 0; j < 4; j++) {
            mn[j] = fmaxf(fmaxf(S[0][j], S[1][j]), fmaxf(S[2][j], S[3][j]));
            mn[j] = fmaxf(mn[j], __shfl_xor(mn[j], 1));
            mn[j] = fmaxf(mn[j], __shfl_xor(mn[j], 2));
            mn[j] = fmaxf(mn[j], __shfl_xor(mn[j], 4));
            mn[j] = fmaxf(mn[j], __shfl_xor(mn[j], 8));
        }
        #pragma unroll
        for (int j = 0; j < 4; j++) {
            float mnew = fmaxf(m[j], mn[j]);
            float al = __expf(m[j] - mnew);
            m[j] = mnew;
            lsum[j] *= al;
            #pragma unroll
            for (int nt = 0; nt < 4; nt++) o[nt][j] *= al;
        }
        float rsum[4] = {0.f, 0.f, 0.f, 0.f};
        #pragma unroll
        for (int nt = 0; nt < 4; nt++)
            #pragma unroll
            for (int j = 0; j < 4; j++) {
                float pv = __expf(S[nt][j] - m[j]);
                S[nt][j] = pv;
                rsum[j] += pv;
            }
        #pragma unroll
        for (int j = 0; j < 4; j++) {
            rsum[j] += __shfl_xor(rsum[j], 1);
            rsum[j] += __shfl_xor(rsum[j], 2);
            rsum[j] += __shfl_xor(rsum[j], 4);
            rsum[j] += __shfl_xor(rsum[j], 8);
            lsum[j] += rsum[j];
        }
        // P -> per-wave LDS, XOR-swizzled (kills the 16-way b128 read conflict)
        #pragma unroll
        for (int nt = 0; nt < 4; nt++)
            #pragma unroll
            for (int j = 0; j < 4; j++) {
                int row = g * 4 + j;
                pb[(row * 64 + nt * 16 + c) ^ ((row & 7) << 3)] = f2bf(S[nt][j]);
            }
        s16x8 pa0 = *(const s16x8*)(pb + ((c * 64 + g * 8) ^ ((c & 7) << 3)));
        s16x8 pa1 = *(const s16x8*)(pb + ((c * 64 + 32 + g * 8) ^ ((c & 7) << 3)));
        #pragma unroll
        for (int nt = 0; nt < 4; nt++) {
            o[nt] = __builtin_amdgcn_mfma_f32_16x16x32_bf16(pa0, vf[nt * 2], o[nt], 0, 0, 0);
            o[nt] = __builtin_amdgcn_mfma_f32_16x16x32_bf16(pa1, vf[nt * 2 + 1], o[nt], 0, 0, 0);
        }
        #pragma unroll
        for (int i = 0; i < 8; i++) kcur[i] = knext[i];
    }
    float inv[4];
    #pragma unroll
    for (int j = 0; j < 4; j++) inv[j] = 1.0f / lsum[j];
    #pragma unroll
    for (int nt = 0; nt < 4; nt++)
        #pragma unroll
        for (int j = 0; j < 4; j++) {
            float v = o[nt][j] * inv[j];
            attn_o[(size_t)(b * TT + qb * 64 + w * 16 + g * 4 + j) * TC + h * THD + nt * 16 + c] = f2bf(v);
        }
    (void)qrow;
}

// ---------------------------------------------------------------------------
// Gate: f32 logits from x1 (recompute rms in f32), softmax, top-2, counts.
// block 256 = 4 waves = 4 tokens.
// ---------------------------------------------------------------------------
__global__ __launch_bounds__(256) void k_gate(const float* __restrict__ x1,
                                              const float* __restrict__ n2w,
                                              const float* __restrict__ gate_w,
                                              float* __restrict__ gl,
                                              int* __restrict__ cnt,
                                              int* __restrict__ te,
                                              int* __restrict__ tls,
                                              float* __restrict__ tw) {
    int w = threadIdx.x >> 6, lane = threadIdx.x & 63;
    int n = blockIdx.x * 4 + w;
    const float* xp = x1 + (size_t)n * TC;
    float ss = 0.f;
    for (int i = lane; i < TC; i += 64) { float v = xp[i]; ss += v * v; }
    #pragma unroll
    for (int off = 32; off; off >>= 1) ss += __shfl_xor(ss, off);
    float rs = rsqrtf(ss * (1.0f / 1024.0f) + 1e-6f);
    int e = lane & 7, ch = lane >> 3;
    float acc = 0.f;
    for (int i = 0; i < 128; i++) {
        int cc = ch * 128 + i;
        acc += xp[cc] * rs * n2w[cc] * gate_w[(size_t)cc * TE + e];
    }
    acc += __shfl_xor(acc, 8);
    acc += __shfl_xor(acc, 16);
    acc += __shfl_xor(acc, 32);
    float logit = acc;
    if (lane < 8) gl[(size_t)n * TE + lane] = logit;
    float mx = logit;
    mx = fmaxf(mx, __shfl_xor(mx, 1)); mx = fmaxf(mx, __shfl_xor(mx, 2)); mx = fmaxf(mx, __shfl_xor(mx, 4));
    float ex = __expf(logit - mx);
    float sm = ex;
    sm += __shfl_xor(sm, 1); sm += __shfl_xor(sm, 2); sm += __shfl_xor(sm, 4);
    float pp = ex / sm;
    float m1 = pp;
    m1 = fmaxf(m1, __shfl_xor(m1, 1)); m1 = fmaxf(m1, __shfl_xor(m1, 2)); m1 = fmaxf(m1, __shfl_xor(m1, 4));
    int cand = (pp == m1) ? e : 8;
    int e0 = cand;
    e0 = min(e0, __shfl_xor(e0, 1)); e0 = min(e0, __shfl_xor(e0, 2)); e0 = min(e0, __shfl_xor(e0, 4));
    float p2 = (e == e0) ? -1.0f : pp;
    float m2 = p2;
    m2 = fmaxf(m2, __shfl_xor(m2, 1)); m2 = fmaxf(m2, __shfl_xor(m2, 2)); m2 = fmaxf(m2, __shfl_xor(m2, 4));
    int cand2 = (p2 == m2) ? e : 8;
    int e1 = cand2;
    e1 = min(e1, __shfl_xor(e1, 1)); e1 = min(e1, __shfl_xor(e1, 2)); e1 = min(e1, __shfl_xor(e1, 4));
    if (lane == 0) {
        int ls0 = atomicAdd(&cnt[e0], 1);
        int ls1 = atomicAdd(&cnt[e1], 1);
        te[n * 2] = e0; te[n * 2 + 1] = e1;
        tls[n * 2] = ls0; tls[n * 2 + 1] = ls1;
        tw[n * 2] = m1; tw[n * 2 + 1] = m2;
    }
}

__global__ void k_prefix(const int* __restrict__ cnt, int* __restrict__ basep) {
    if (threadIdx.x == 0) {
        int s = 0;
        for (int e = 0; e < TE; e++) { basep[e] = s; s += cnt[e]; }
    }
}

__global__ void k_scatter(const int* __restrict__ te, const int* __restrict__ tls,
                          const float* __restrict__ tw, const int* __restrict__ basep,
                          int* __restrict__ tlist, float* __restrict__ slotw,
                          int* __restrict__ sot) {
    int n = blockIdx.x * 256 + threadIdx.x;
    if (n >= NTOK) return;
    int s0 = basep[te[n * 2]] + tls[n * 2];
    int s1 = basep[te[n * 2 + 1]] + tls[n * 2 + 1];
    tlist[s0] = n; tlist[s1] = n;
    slotw[s0] = tw[n * 2]; slotw[s1] = tw[n * 2 + 1];
    sot[n * 2] = s0; sot[n * 2 + 1] = s1;
}

// ---------------------------------------------------------------------------
// Dual GEMM (silu(A*B1t) * (A*B2t)), BM=128 BN=64, gload_lds staging.
// GATHER=1: MoE expert FFN in (grid z = expert); GATHER=0: shared FFN.
// grid (N/64, ceil(M/128), E), block 256
// ---------------------------------------------------------------------------
template <int GATHER>
__global__ __launch_bounds__(256) void k_dual(const short* __restrict__ A,
                                              const short* __restrict__ B1t,
                                              const short* __restrict__ B2t,
                                              short* __restrict__ Out,
                                              const int* __restrict__ cnt,
                                              const int* __restrict__ basep,
                                              const int* __restrict__ tlist,
                                              const float* __restrict__ slotw,
                                              size_t wrows, int ldout, int K) {
    int e = blockIdx.z;
    int mt = blockIdx.y, nt = blockIdx.x;
    int ce = 0, base = 0;
    if (GATHER) {
        ce = cnt[e];
        if (mt * 128 >= ce) return;
        base = basep[e];
    }
    __shared__ short As[128 * 32];
    __shared__ short B1s[64 * 32];
    __shared__ short B2s[64 * 32];
    int tid = threadIdx.x, wid = tid >> 6, lane = tid & 63;
    int wr = wid >> 1, wc = wid & 1, g = lane >> 4, c = lane & 15;
    // A staging rows
    int srow = wid * 32 + (lane >> 2);
    int scol = (lane & 3) * 8;
    size_t arow0, arow1;
    if (GATHER) {
        int l0 = mt * 128 + srow;      if (l0 >= ce) l0 = ce - 1;
        int l1 = mt * 128 + srow + 16; if (l1 >= ce) l1 = ce - 1;
        arow0 = (size_t)tlist[base + l0];
        arow1 = (size_t)tlist[base + l1];
    } else {
        arow0 = (size_t)(mt * 128 + srow);
        arow1 = arow0 + 16;
    }
    const short* Ag0 = A + arow0 * (size_t)K + scol;
    const short* Ag1 = A + arow1 * (size_t)K + scol;
    // B staging rows (64 rows, wave covers 16)
    int brow_s = wid * 16 + (lane >> 2);
    const short* B1g = B1t + ((size_t)e * wrows + (size_t)(nt * 64 + brow_s)) * K + scol;
    const short* B2g = B2t + ((size_t)e * wrows + (size_t)(nt * 64 + brow_s)) * K + scol;
    int loffA = __builtin_amdgcn_readfirstlane(wid * 2048);
    int loffB = __builtin_amdgcn_readfirstlane(wid * 1024);
    char* Al = (char*)As + loffA;
    char* B1l = (char*)B1s + loffB;
    char* B2l = (char*)B2s + loffB;
    f32x4 a1[4][2] = {}, a2[4][2] = {};
    for (int kk = 0; kk < K; kk += 32) {
        __syncthreads();
        gl_lds16(Ag0 + kk, Al);
        gl_lds16(Ag1 + kk, Al + 1024);
        gl_lds16(B1g + kk, B1l);
        gl_lds16(B2g + kk, B2l);
        __syncthreads();
        s16x8 af[4], b1[2], b2[2];
        #pragma unroll
        for (int m_ = 0; m_ < 4; m_++) af[m_] = *(const s16x8*)(As + (wr * 64 + m_ * 16 + c) * 32 + g * 8);
        #pragma unroll
        for (int n = 0; n < 2; n++) {
            b1[n] = *(const s16x8*)(B1s + (wc * 32 + n * 16 + c) * 32 + g * 8);
            b2[n] = *(const s16x8*)(B2s + (wc * 32 + n * 16 + c) * 32 + g * 8);
        }
        #pragma unroll
        for (int m_ = 0; m_ < 4; m_++)
            #pragma unroll
            for (int n = 0; n < 2; n++) {
                a1[m_][n] = __builtin_amdgcn_mfma_f32_16x16x32_bf16(af[m_], b1[n], a1[m_][n], 0, 0, 0);
                a2[m_][n] = __builtin_amdgcn_mfma_f32_16x16x32_bf16(af[m_], b2[n], a2[m_][n], 0, 0, 0);
            }
    }
    #pragma unroll
    for (int m_ = 0; m_ < 4; m_++)
        #pragma unroll
        for (int n = 0; n < 2; n++)
            #pragma unroll
            for (int j = 0; j < 4; j++) {
                int lrow = mt * 128 + wr * 64 + m_ * 16 + g * 4 + j;
                if (GATHER && lrow >= ce) continue;
                int col = nt * 64 + wc * 32 + n * 16 + c;
                float g1 = a1[m_][n][j], g2 = a2[m_][n][j];
                float v = g1 / (1.0f + __expf(-g1)) * g2;
                size_t orow = GATHER ? (size_t)(base + lrow) : (size_t)lrow;
                if (GATHER) v *= slotw[base + lrow];
                Out[orow * (size_t)ldout + col] = f2bf(v);
            }
}

// ---------------------------------------------------------------------------
// MoE down-proj per expert: ye[slot] = he[slot] @ wp_e, gload_lds staging.
// grid (1024/128, ceil(M/128), E)
// ---------------------------------------------------------------------------
__global__ __launch_bounds__(256) void k_moe2(const short* __restrict__ he,
                                              const short* __restrict__ Wpt,
                                              short* __restrict__ ye,
                                              const int* __restrict__ cnt,
                                              const int* __restrict__ basep) {
    int e = blockIdx.z;
    int ce = cnt[e];
    int mt = blockIdx.y;
    if (mt * 128 >= ce) return;
    int base = basep[e];
    int nt = blockIdx.x;
    __shared__ short As[128 * 32];
    __shared__ short Bs[128 * 32];
    int tid = threadIdx.x, wid = tid >> 6, lane = tid & 63;
    int wr = wid >> 1, wc = wid & 1, g = lane >> 4, c = lane & 15;
    int srow = wid * 32 + (lane >> 2);
    int scol = (lane & 3) * 8;
    // rows in he are contiguous slots; rows past ce read garbage (discarded)
    const short* Ag0 = he + (size_t)(base + mt * 128 + srow) * TFE + scol;
    const short* Ag1 = Ag0 + (size_t)16 * TFE;
    const short* Bg0 = Wpt + ((size_t)e * 1024 + nt * 128 + srow) * TFE + scol;
    const short* Bg1 = Bg0 + (size_t)16 * TFE;
    int loff = __builtin_amdgcn_readfirstlane(wid * 2048);
    char* Al = (char*)As + loff;
    char* Bl = (char*)Bs + loff;
    f32x4 acc[4][4] = {};
    for (int kk = 0; kk < TFE; kk += 32) {
        __syncthreads();
        gl_lds16(Ag0 + kk, Al);
        gl_lds16(Ag1 + kk, Al + 1024);
        gl_lds16(Bg0 + kk, Bl);
        gl_lds16(Bg1 + kk, Bl + 1024);
        __syncthreads();
        s16x8 af[4], bf[4];
        #pragma unroll
        for (int m = 0; m < 4; m++) af[m] = *(const s16x8*)(As + (wr * 64 + m * 16 + c) * 32 + g * 8);
        #pragma unroll
        for (int n = 0; n < 4; n++) bf[n] = *(const s16x8*)(Bs + (wc * 64 + n * 16 + c) * 32 + g * 8);
        #pragma unroll
        for (int m = 0; m < 4; m++)
            #pragma unroll
            for (int n = 0; n < 4; n++)
                acc[m][n] = __builtin_amdgcn_mfma_f32_16x16x32_bf16(af[m], bf[n], acc[m][n], 0, 0, 0);
    }
    #pragma unroll
    for (int m = 0; m < 4; m++)
        #pragma unroll
        for (int n = 0; n < 4; n++)
            #pragma unroll
            for (int j = 0; j < 4; j++) {
                int lrow = mt * 128 + wr * 64 + m * 16 + g * 4 + j;
                if (lrow >= ce) continue;
                int col = nt * 128 + wc * 64 + n * 16 + c;
                ye[(size_t)(base + lrow) * TC + col] = f2bf(acc[m][n][j]);
            }
}

// ---------------------------------------------------------------------------
// Final: out = shm @ swp_t + x1 + ye[s0] + ye[s1].  M=4096 N=1024 K=2048
// ---------------------------------------------------------------------------
__global__ __launch_bounds__(256) void k_final(const short* __restrict__ A,
                                               const short* __restrict__ Bt,
                                               const float* __restrict__ x1,
                                               const short* __restrict__ ye,
                                               const int* __restrict__ sot,
                                               float* __restrict__ outp) {
    __shared__ short As[128 * 32];
    __shared__ short Bs[128 * 32];
    const int K = TFS;
    int tid = threadIdx.x;
    int brow = blockIdx.y * 128, bcol = blockIdx.x * 128;
    int wid = tid >> 6, lane = tid & 63;
    int wr = wid >> 1, wc = wid & 1, g = lane >> 4, c = lane & 15;
    int srow = wid * 32 + (lane >> 2);
    int scol = (lane & 3) * 8;
    const short* Ag0 = A + (size_t)(brow + srow) * K + scol;
    const short* Ag1 = A + (size_t)(brow + srow + 16) * K + scol;
    const short* Bg0 = Bt + (size_t)(bcol + srow) * K + scol;
    const short* Bg1 = Bt + (size_t)(bcol + srow + 16) * K + scol;
    int loff = __builtin_amdgcn_readfirstlane(wid * 2048);
    char* Al = (char*)As + loff;
    char* Bl = (char*)Bs + loff;
    f32x4 acc[4][4] = {};
    for (int kk = 0; kk < K; kk += 32) {
        __syncthreads();
        gl_lds16(Ag0 + kk, Al);
        gl_lds16(Ag1 + kk, Al + 1024);
        gl_lds16(Bg0 + kk, Bl);
        gl_lds16(Bg1 + kk, Bl + 1024);
        __syncthreads();
        s16x8 af[4], bf[4];
        #pragma unroll
        for (int m = 0; m < 4; m++) af[m] = *(const s16x8*)(As + (wr * 64 + m * 16 + c) * 32 + g * 8);
        #pragma unroll
        for (int n = 0; n < 4; n++) bf[n] = *(const s16x8*)(Bs + (wc * 64 + n * 16 + c) * 32 + g * 8);
        #pragma unroll
        for (int m = 0; m < 4; m++)
            #pragma unroll
            for (int n = 0; n < 4; n++)
                acc[m][n] = __builtin_amdgcn_mfma_f32_16x16x32_bf16(af[m], bf[n], acc[m][n], 0, 0, 0);
    }
    #pragma unroll
    for (int m = 0; m < 4; m++)
        #pragma unroll
        for (int n = 0; n < 4; n++)
            #pragma unroll
            for (int j = 0; j < 4; j++) {
                int row = brow + wr * 64 + m * 16 + g * 4 + j;
                int col = bcol + wc * 64 + n * 16 + c;
                int s0 = sot[row * 2], s1 = sot[row * 2 + 1];
                float v = acc[m][n][j] + x1[(size_t)row * TC + col]
                        + bf2f(ye[(size_t)s0 * TC + col]) + bf2f(ye[(size_t)s1 * TC + col]);
                outp[(size_t)row * TC + col] = v;
            }
}

// ---------------------------------------------------------------------------
// Launch
// ---------------------------------------------------------------------------
extern "C" void kernel_launch(void* const* d_in, const int* in_sizes, int n_in,
                              void* d_out, int out_size, void* d_ws, size_t ws_size,
                              hipStream_t stream) {
    const float* x     = (const float*)d_in[0];
    const float* n1w   = (const float*)d_in[1];
    const float* n2w   = (const float*)d_in[2];
    const float* wq    = (const float*)d_in[3];
    const float* wk    = (const float*)d_in[4];
    const float* wv    = (const float*)d_in[5];
    const float* wo    = (const float*)d_in[6];
    const float* gatew = (const float*)d_in[7];
    const float* ew1   = (const float*)d_in[8];
    const float* ew2   = (const float*)d_in[9];
    const float* ewp   = (const float*)d_in[10];
    const float* sw1   = (const float*)d_in[11];
    const float* sw2   = (const float*)d_in[12];
    const float* swp   = (const float*)d_in[13];
    float* outp = (float*)d_out;

    char* p = (char*)d_ws;
    auto alloc = [&](size_t bytes) -> char* {
        char* r = p;
        p += (bytes + 255) & ~(size_t)255;
        return r;
    };
    short* wqkv_t = (short*)alloc(1536 * 1024 * 2);
    short* wo_t   = (short*)alloc(1024 * 1024 * 2);
    short* ew1_t  = (short*)alloc((size_t)8 * 1024 * 1024 * 2);
    short* ew2_t  = (short*)alloc((size_t)8 * 1024 * 1024 * 2);
    short* ewp_t  = (short*)alloc((size_t)8 * 1024 * 1024 * 2);
    short* sw1_t  = (short*)alloc((size_t)2048 * 1024 * 2);
    short* sw2_t  = (short*)alloc((size_t)2048 * 1024 * 2);
    short* swp_t  = (short*)alloc((size_t)1024 * 2048 * 2);
    short* h1     = (short*)alloc((size_t)NTOK * 1024 * 2);
    short* qkv    = (short*)alloc((size_t)NTOK * 1536 * 2);
    short* q_r    = (short*)alloc((size_t)TB * TH * TT * THD * 2);
    short* k_r    = (short*)alloc((size_t)TB * TKV * TT * THD * 2);
    short* v_t    = (short*)alloc((size_t)TB * TKV * THD * TT * 2);
    short* attn_o = (short*)alloc((size_t)NTOK * 1024 * 2);
    float* x1     = (float*)alloc((size_t)NTOK * 1024 * 4);
    short* h2     = (short*)alloc((size_t)NTOK * 1024 * 2);
    float* rope   = (float*)alloc((size_t)TT * 32 * 2 * 4);
    int*   cnt    = (int*)alloc(256);
    int*   basep  = (int*)alloc(256);
    int*   te     = (int*)alloc((size_t)NTOK * 2 * 4);
    int*   tls    = (int*)alloc((size_t)NTOK * 2 * 4);
    float* tw     = (float*)alloc((size_t)NTOK * 2 * 4);
    int*   tlist  = (int*)alloc((size_t)NSLOT * 4);
    float* slotw  = (float*)alloc((size_t)NSLOT * 4);
    int*   sot    = (int*)alloc((size_t)NTOK * 2 * 4);
    short* he     = (short*)alloc((size_t)NSLOT * TFE * 2);
    short* ye     = (short*)alloc((size_t)NSLOT * TC * 2);
    short* shm    = (short*)alloc((size_t)NTOK * TFS * 2);

    dim3 blk(256);

    k_transp<<<dim3(32, 32, 1), blk, 0, stream>>>(wq, wqkv_t, 1024, 1024, 0, 0);
    k_transp<<<dim3(8, 32, 1), blk, 0, stream>>>(wk, wqkv_t + 1024 * 1024, 1024, 256, 0, 0);
    k_transp<<<dim3(8, 32, 1), blk, 0, stream>>>(wv, wqkv_t + 1280 * 1024, 1024, 256, 0, 0);
    k_transp<<<dim3(32, 32, 1), blk, 0, stream>>>(wo, wo_t, 1024, 1024, 0, 0);
    k_transp<<<dim3(32, 32, 8), blk, 0, stream>>>(ew1, ew1_t, 1024, 1024, 1048576, 1048576);
    k_transp<<<dim3(32, 32, 8), blk, 0, stream>>>(ew2, ew2_t, 1024, 1024, 1048576, 1048576);
    k_transp<<<dim3(32, 32, 8), blk, 0, stream>>>(ewp, ewp_t, 1024, 1024, 1048576, 1048576);
    k_transp<<<dim3(64, 32, 1), blk, 0, stream>>>(sw1, sw1_t, 1024, 2048, 0, 0);
    k_transp<<<dim3(64, 32, 1), blk, 0, stream>>>(sw2, sw2_t, 1024, 2048, 0, 0);
    k_transp<<<dim3(32, 64, 1), blk, 0, stream>>>(swp, swp_t, 2048, 1024, 0, 0);

    k_rope_table<<<(TT * 32 + 255) / 256, blk, 0, stream>>>(rope);

    k_rmsnorm<<<NTOK, blk, 0, stream>>>(x, n1w, h1);
    k_gemm128<0><<<dim3(12, 32), blk, 0, stream>>>(h1, wqkv_t, qkv, nullptr, NTOK, 1536, 1024);
    k_rope_apply<<<(NTOK * 640 + 255) / 256, blk, 0, stream>>>(qkv, rope, q_r, k_r);
    k_transp_v<<<dim3(2, 64, 8), blk, 0, stream>>>(qkv, v_t);

    k_attn<<<dim3(TT / 64, TB * TH), blk, 0, stream>>>(q_r, k_r, v_t, attn_o);

    k_gemm128<1><<<dim3(8, 32), blk, 0, stream>>>(attn_o, wo_t, x1, x, NTOK, 1024, 1024);

    k_rmsnorm<<<NTOK, blk, 0, stream>>>(x1, n2w, h2);

    hipMemsetAsync(cnt, 0, 64, stream);
    k_gate<<<NTOK / 4, blk, 0, stream>>>(x1, n2w, gatew, outp + (size_t)NTOK * TC, cnt, te, tls, tw);
    k_prefix<<<1, 64, 0, stream>>>(cnt, basep);
    k_scatter<<<NTOK / 256, blk, 0, stream>>>(te, tls, tw, basep, tlist, slotw, sot);

    k_dual<1><<<dim3(16, 32, 8), blk, 0, stream>>>(h2, ew1_t, ew2_t, he, cnt, basep, tlist, slotw,
                                                   1024, TFE, 1024);
    k_moe2<<<dim3(8, 32, 8), blk, 0, stream>>>(he, ewp_t, ye, cnt, basep);

    k_dual<0><<<dim3(32, 32, 1), blk, 0, stream>>>(h2, sw1_t, sw2_t, shm, nullptr, nullptr, nullptr,
                                                   nullptr, 0, TFS, 1024);

    k_final<<<dim3(8, 32), blk, 0, stream>>>(shm, swp_t, x1, ye, sot, outp);

    (void)in_sizes; (void)n_in; (void)out_size; (void)ws_size;
}

// Round 3
// 758.461 us; speedup vs baseline: 1.2391x; 1.1166x over previous
//
#include <hip/hip_runtime.h>
#include <hip/hip_bf16.h>

// ---------------------------------------------------------------------------
// Problem constants
// ---------------------------------------------------------------------------
#define TB 2
#define TT 2048
#define TC 1024
#define TH 16
#define TKV 4
#define THD 64
#define TE 8
#define TFE 1024
#define TFS 2048
#define NTOK 4096           // B*T
#define NSLOT 8192          // NTOK * K(=2)

typedef __attribute__((ext_vector_type(4))) float f32x4;
typedef __attribute__((ext_vector_type(16))) float f32x16;
typedef __attribute__((ext_vector_type(8))) short s16x8;

__device__ __forceinline__ float bf2f(short s) {
    unsigned int u = ((unsigned int)(unsigned short)s) << 16;
    return __builtin_bit_cast(float, u);
}
__device__ __forceinline__ short f2bf(float f) {
    unsigned int u = __builtin_bit_cast(unsigned int, f);
    u = u + 0x7fffu + ((u >> 16) & 1u);     // RNE
    return (short)(u >> 16);
}
__device__ __forceinline__ unsigned int cvtpk_bf16(float lo, float hi) {
    unsigned int r;
    asm volatile("v_cvt_pk_bf16_f32 %0, %1, %2" : "=v"(r) : "v"(lo), "v"(hi));
    return r;
}

// async global->LDS, 16B per lane. lds ptr must be wave-uniform base;
// HW writes lane l's 16B to base + l*16. Global source is per-lane.
__device__ __forceinline__ void gl_lds16(const void* g, void* l) {
    __builtin_amdgcn_global_load_lds((const __attribute__((address_space(1))) void*)g,
                                     (__attribute__((address_space(3))) void*)l,
                                     16, 0, 0);
}

// ---------------------------------------------------------------------------
// Transpose + f32->bf16 convert:  in f32 [R][Cd] -> out bf16 [Cd][R], batched
// ---------------------------------------------------------------------------
__global__ __launch_bounds__(256) void k_transp(const float* __restrict__ in,
                                                short* __restrict__ out,
                                                int R, int Cd,
                                                size_t bs_in, size_t bs_out) {
    __shared__ float tile[32][33];
    const float* ip = in + bs_in * blockIdx.z;
    short* op = out + bs_out * blockIdx.z;
    int tx = threadIdx.x & 31, ty = threadIdx.x >> 5;
    int r0 = blockIdx.y * 32, c0 = blockIdx.x * 32;
    #pragma unroll
    for (int r = ty; r < 32; r += 8)
        tile[r][tx] = ip[(size_t)(r0 + r) * Cd + c0 + tx];
    __syncthreads();
    #pragma unroll
    for (int r = ty; r < 32; r += 8)
        op[(size_t)(c0 + r) * R + r0 + tx] = f2bf(tile[tx][r]);
}

// ---------------------------------------------------------------------------
// V transpose (bf16 -> bf16): qkv v-columns [T][64] per (b,kv) -> v_t [64][T]
// ---------------------------------------------------------------------------
__global__ __launch_bounds__(256) void k_transp_v(const short* __restrict__ qkv,
                                                  short* __restrict__ v_t) {
    __shared__ short tile[32][33];
    int z = blockIdx.z;
    int b = z >> 2, kvh = z & 3;
    const short* ip = qkv + (size_t)b * TT * 1536 + 1280 + kvh * 64;
    short* op = v_t + (size_t)z * THD * TT;
    int tx = threadIdx.x & 31, ty = threadIdx.x >> 5;
    int t0 = blockIdx.y * 32, d0 = blockIdx.x * 32;
    #pragma unroll
    for (int r = ty; r < 32; r += 8)
        tile[r][tx] = ip[(size_t)(t0 + r) * 1536 + d0 + tx];
    __syncthreads();
    #pragma unroll
    for (int r = ty; r < 32; r += 8)
        op[(size_t)(d0 + r) * TT + t0 + tx] = tile[tx][r];
}

// ---------------------------------------------------------------------------
// RoPE table: [T][32][2] f32  (cos, sin)
// ---------------------------------------------------------------------------
__global__ void k_rope_table(float* __restrict__ rope) {
    int idx = blockIdx.x * 256 + threadIdx.x;
    if (idx >= TT * 32) return;
    int t = idx >> 5, i = idx & 31;
    float freq = expf(-(float)i * (1.0f / 32.0f) * 9.210340371976184f); // 10000^(-i/32)
    float ang = (float)t * freq;
    rope[idx * 2 + 0] = cosf(ang);
    rope[idx * 2 + 1] = sinf(ang);
}

// ---------------------------------------------------------------------------
// RMSNorm: f32 [4096][1024] -> bf16 [4096][1024].  block 256 = one row
// ---------------------------------------------------------------------------
__global__ __launch_bounds__(256) void k_rmsnorm(const float* __restrict__ x,
                                                 const float* __restrict__ w,
                                                 short* __restrict__ out) {
    int row = blockIdx.x, t = threadIdx.x;
    float4 v = ((const float4*)(x + (size_t)row * TC))[t];
    float ss = v.x * v.x + v.y * v.y + v.z * v.z + v.w * v.w;
    #pragma unroll
    for (int off = 32; off; off >>= 1) ss += __shfl_xor(ss, off);
    __shared__ float red[4];
    if ((t & 63) == 0) red[t >> 6] = ss;
    __syncthreads();
    float rs = rsqrtf((red[0] + red[1] + red[2] + red[3]) * (1.0f / 1024.0f) + 1e-6f);
    float4 wv = ((const float4*)w)[t];
    short4 o;
    o.x = f2bf(v.x * rs * wv.x);
    o.y = f2bf(v.y * rs * wv.y);
    o.z = f2bf(v.z * rs * wv.z);
    o.w = f2bf(v.w * rs * wv.w);
    ((short4*)(out + (size_t)row * TC))[t] = o;
}

// ---------------------------------------------------------------------------
// 128x64 GEMM, global_load_lds staging: C[M,N] = A[M,K](bf16) * Bt[N,K](bf16)
// EPI 0: out bf16 = acc;   EPI 1: out f32 = acc + resid
// grid (N/64, M/128), block 256
// ---------------------------------------------------------------------------
template <int EPI>
__global__ __launch_bounds__(256) void k_gemm64(const short* __restrict__ A,
                                                const short* __restrict__ Bt,
                                                void* __restrict__ outp,
                                                const float* __restrict__ resid,
                                                int M, int N, int K) {
    __shared__ short As[128 * 32];
    __shared__ short Bs[64 * 32];
    int tid = threadIdx.x;
    int brow = blockIdx.y * 128, bcol = blockIdx.x * 64;
    int wid = tid >> 6, lane = tid & 63;
    int wr = wid >> 1, wc = wid & 1, g = lane >> 4, c = lane & 15;
    int srow = wid * 32 + (lane >> 2);
    int scol = (lane & 3) * 8;
    const short* Ag0 = A + (size_t)(brow + srow) * K + scol;
    const short* Ag1 = A + (size_t)(brow + srow + 16) * K + scol;
    int sbrow = wid * 16 + (lane >> 2);
    const short* Bg = Bt + (size_t)(bcol + sbrow) * K + scol;
    int loffA = __builtin_amdgcn_readfirstlane(wid * 2048);
    int loffB = __builtin_amdgcn_readfirstlane(wid * 1024);
    char* Al = (char*)As + loffA;
    char* Bl = (char*)Bs + loffB;
    f32x4 acc[4][2] = {};
    for (int kk = 0; kk < K; kk += 32) {
        __syncthreads();
        gl_lds16(Ag0 + kk, Al);
        gl_lds16(Ag1 + kk, Al + 1024);
        gl_lds16(Bg + kk, Bl);
        __syncthreads();
        s16x8 af[4], bf[2];
        #pragma unroll
        for (int m = 0; m < 4; m++) af[m] = *(const s16x8*)(As + (wr * 64 + m * 16 + c) * 32 + g * 8);
        #pragma unroll
        for (int n = 0; n < 2; n++) bf[n] = *(const s16x8*)(Bs + (wc * 32 + n * 16 + c) * 32 + g * 8);
        #pragma unroll
        for (int m = 0; m < 4; m++)
            #pragma unroll
            for (int n = 0; n < 2; n++)
                acc[m][n] = __builtin_amdgcn_mfma_f32_16x16x32_bf16(af[m], bf[n], acc[m][n], 0, 0, 0);
    }
    #pragma unroll
    for (int m = 0; m < 4; m++)
        #pragma unroll
        for (int n = 0; n < 2; n++)
            #pragma unroll
            for (int j = 0; j < 4; j++) {
                int row = brow + wr * 64 + m * 16 + g * 4 + j;
                int col = bcol + wc * 32 + n * 16 + c;
                float v = acc[m][n][j];
                if (EPI == 0)
                    ((short*)outp)[(size_t)row * N + col] = f2bf(v);
                else
                    ((float*)outp)[(size_t)row * N + col] = v + resid[(size_t)row * N + col];
            }
}

// ---------------------------------------------------------------------------
// RoPE apply + scatter (q, k only; v handled by k_transp_v).
// ---------------------------------------------------------------------------
__global__ void k_rope_apply(const short* __restrict__ qkv,
                             const float* __restrict__ rope,
                             short* __restrict__ q_r,
                             short* __restrict__ k_r) {
    int idx = blockIdx.x * 256 + threadIdx.x;
    if (idx >= NTOK * 640) return;
    int row = idx / 640;
    int p = idx - row * 640;
    int b = row >> 11, t = row & 2047;
    const short* src = qkv + (size_t)row * 1536;
    if (p < 512) {            // q
        int h = p >> 5, i = p & 31;
        float x0 = bf2f(src[h * 64 + 2 * i]);
        float x1 = bf2f(src[h * 64 + 2 * i + 1]);
        float cs = rope[(t * 32 + i) * 2], sn = rope[(t * 32 + i) * 2 + 1];
        size_t o = ((size_t)(b * TH + h) * TT + t) * THD + 2 * i;
        q_r[o]     = f2bf(x0 * cs - x1 * sn);
        q_r[o + 1] = f2bf(x1 * cs + x0 * sn);
    } else {                  // k
        int pk = p - 512;
        int kv = pk >> 5, i = pk & 31;
        float x0 = bf2f(src[1024 + kv * 64 + 2 * i]);
        float x1 = bf2f(src[1024 + kv * 64 + 2 * i + 1]);
        float cs = rope[(t * 32 + i) * 2], sn = rope[(t * 32 + i) * 2 + 1];
        size_t o = ((size_t)(b * TKV + kv) * TT + t) * THD + 2 * i;
        k_r[o]     = f2bf(x0 * cs - x1 * sn);
        k_r[o + 1] = f2bf(x1 * cs + x0 * sn);
    }
}

// ---------------------------------------------------------------------------
// Flash attention, swapped-operand 32x32 structure (m214-style).
// grid (16, B*H), block 256 = 4 independent waves; wave handles 32 q-rows.
// S^T = mfma(K, Q): lane owns full P-row for q = lane&31 (split with lane^32).
// Softmax: in-lane + one shfl_xor(32).  P->bf16 via cvt_pk + permlane32_swap.
// O^T = mfma(V^T, P): rescale factor lane-local.  No LDS, no barriers.
// ---------------------------------------------------------------------------
__global__ __launch_bounds__(256) void k_attn(const short* __restrict__ q_r,
                                              const short* __restrict__ k_r,
                                              const short* __restrict__ v_t,
                                              short* __restrict__ attn_o) {
    int w = threadIdx.x >> 6, lane = threadIdx.x & 63;
    int qt = 63 - (blockIdx.x * 4 + w);     // long waves first
    int qbase = qt * 32;
    int bh = blockIdx.y;
    int b = bh >> 4, h = bh & 15, kv = h >> 2;
    int q32 = lane & 31, hi = lane >> 5;

    const short* qp = q_r + ((size_t)(b * TH + h) * TT + qbase) * THD;
    const short* kp = k_r + ((size_t)(b * TKV + kv) * TT) * THD;
    const short* vp = v_t + ((size_t)(b * TKV + kv) * THD) * TT;

    // Q frags (B-operand): lane holds Q[q32][dc*16 + hi*8 .. +8]
    s16x8 qf[4];
    #pragma unroll
    for (int dc = 0; dc < 4; dc++)
        qf[dc] = *(const s16x8*)(qp + q32 * THD + dc * 16 + hi * 8);

    f32x16 ot0 = {}, ot1 = {};          // O^T: d-rows 0..31 / 32..63, q col = q32
    float mrun = -1e30f, lrun = 0.f;
    int nkt = (qbase + 95) >> 6;

    for (int kt = 0; kt < nkt; kt++) {
        int ktb = kt * 64;
        // K frags (A-operand): rows = kpos
        f32x16 st0 = {}, st1 = {};
        s16x8 kf0[4], kf1[4];
        #pragma unroll
        for (int dc = 0; dc < 4; dc++) {
            kf0[dc] = *(const s16x8*)(kp + (size_t)(ktb + q32) * THD + dc * 16 + hi * 8);
            kf1[dc] = *(const s16x8*)(kp + (size_t)(ktb + 32 + q32) * THD + dc * 16 + hi * 8);
        }
        // V frags (A-operand of PV): rows = d, contig kpos
        s16x8 vf[8];
        #pragma unroll
        for (int dt = 0; dt < 2; dt++)
            #pragma unroll
            for (int kc = 0; kc < 4; kc++)
                vf[dt * 4 + kc] = *(const s16x8*)(vp + (size_t)(dt * 32 + q32) * TT + ktb + kc * 16 + hi * 8);

        __builtin_amdgcn_s_setprio(1);
        #pragma unroll
        for (int dc = 0; dc < 4; dc++) {
            st0 = __builtin_amdgcn_mfma_f32_32x32x16_bf16(kf0[dc], qf[dc], st0, 0, 0, 0);
            st1 = __builtin_amdgcn_mfma_f32_32x32x16_bf16(kf1[dc], qf[dc], st1, 0, 0, 0);
        }
        __builtin_amdgcn_s_setprio(0);

        // scale + causal mask (only last tile can violate causality)
        bool domask = (kt == nkt - 1);
        int qabs = qbase + q32;
        #pragma unroll
        for (int r = 0; r < 16; r++) {
            int kploc = (r & 3) + 8 * (r >> 2) + 4 * hi;
            float s0 = st0[r] * 0.125f;
            float s1 = st1[r] * 0.125f;
            if (domask) {
                if (ktb + kploc > qabs) s0 = -1e30f;
                if (ktb + 32 + kploc > qabs) s1 = -1e30f;
            }
            st0[r] = s0; st1[r] = s1;
        }
        // row max: in-lane + partner
        float pm = st0[0];
        #pragma unroll
        for (int r = 1; r < 16; r++) pm = fmaxf(pm, st0[r]);
        #pragma unroll
        for (int r = 0; r < 16; r++) pm = fmaxf(pm, st1[r]);
        pm = fmaxf(pm, __shfl_xor(pm, 32));
        float mnew = fmaxf(mrun, pm);
        float al = __expf(mrun - mnew);
        mrun = mnew;
        float rs = 0.f;
        #pragma unroll
        for (int r = 0; r < 16; r++) {
            float e0 = __expf(st0[r] - mnew); st0[r] = e0; rs += e0;
            float e1 = __expf(st1[r] - mnew); st1[r] = e1; rs += e1;
        }
        rs += __shfl_xor(rs, 32);
        lrun = lrun * al + rs;
        #pragma unroll
        for (int r = 0; r < 16; r++) { ot0[r] *= al; ot1[r] *= al; }

        // P -> bf16 B-frags: pf[kc] covers kpos [ktb + kc*16, +16)
        unsigned int w0[8], w1[8];
        #pragma unroll
        for (int j = 0; j < 8; j++) {
            w0[j] = cvtpk_bf16(st0[2 * j], st0[2 * j + 1]);
            w1[j] = cvtpk_bf16(st1[2 * j], st1[2 * j + 1]);
        }
        s16x8 pf[4];
        #pragma unroll
        for (int kc = 0; kc < 4; kc++) {
            unsigned int* ww = (kc < 2) ? w0 : w1;
            int kcl = kc & 1;
            unsigned int x0 = ww[4 * kcl + 0], y0 = ww[4 * kcl + 2];
            unsigned int x1 = ww[4 * kcl + 1], y1 = ww[4 * kcl + 3];
            asm volatile("v_permlane32_swap_b32 %0, %1" : "+v"(x0), "+v"(y0));
            asm volatile("v_permlane32_swap_b32 %0, %1" : "+v"(x1), "+v"(y1));
            unsigned int fr[4] = {x0, x1, y0, y1};
            pf[kc] = __builtin_bit_cast(s16x8, *(ulong2*)fr);
        }
        __builtin_amdgcn_s_setprio(1);
        #pragma unroll
        for (int kc = 0; kc < 4; kc++) {
            ot0 = __builtin_amdgcn_mfma_f32_32x32x16_bf16(vf[kc], pf[kc], ot0, 0, 0, 0);
            ot1 = __builtin_amdgcn_mfma_f32_32x32x16_bf16(vf[4 + kc], pf[kc], ot1, 0, 0, 0);
        }
        __builtin_amdgcn_s_setprio(0);
    }
    float inv = 1.0f / lrun;
    short* orow = attn_o + (size_t)(b * TT + qbase + q32) * TC + h * THD;
    #pragma unroll
    for (int s = 0; s < 4; s++) {
        short4 v0, v1;
        v0.x = f2bf(ot0[4 * s + 0] * inv); v0.y = f2bf(ot0[4 * s + 1] * inv);
        v0.z = f2bf(ot0[4 * s + 2] * inv); v0.w = f2bf(ot0[4 * s + 3] * inv);
        v1.x = f2bf(ot1[4 * s + 0] * inv); v1.y = f2bf(ot1[4 * s + 1] * inv);
        v1.z = f2bf(ot1[4 * s + 2] * inv); v1.w = f2bf(ot1[4 * s + 3] * inv);
        *(short4*)(orow + 8 * s + 4 * hi) = v0;
        *(short4*)(orow + 32 + 8 * s + 4 * hi) = v1;
    }
}

// ---------------------------------------------------------------------------
// Gate: f32 logits from x1 (recompute rms in f32), softmax, top-2, counts.
// ---------------------------------------------------------------------------
__global__ __launch_bounds__(256) void k_gate(const float* __restrict__ x1,
                                              const float* __restrict__ n2w,
                                              const float* __restrict__ gate_w,
                                              float* __restrict__ gl,
                                              int* __restrict__ cnt,
                                              int* __restrict__ te,
                                              int* __restrict__ tls,
                                              float* __restrict__ tw) {
    int w = threadIdx.x >> 6, lane = threadIdx.x & 63;
    int n = blockIdx.x * 4 + w;
    const float* xp = x1 + (size_t)n * TC;
    float ss = 0.f;
    for (int i = lane; i < TC; i += 64) { float v = xp[i]; ss += v * v; }
    #pragma unroll
    for (int off = 32; off; off >>= 1) ss += __shfl_xor(ss, off);
    float rs = rsqrtf(ss * (1.0f / 1024.0f) + 1e-6f);
    int e = lane & 7, ch = lane >> 3;
    float acc = 0.f;
    for (int i = 0; i < 128; i++) {
        int cc = ch * 128 + i;
        acc += xp[cc] * rs * n2w[cc] * gate_w[(size_t)cc * TE + e];
    }
    acc += __shfl_xor(acc, 8);
    acc += __shfl_xor(acc, 16);
    acc += __shfl_xor(acc, 32);
    float logit = acc;
    if (lane < 8) gl[(size_t)n * TE + lane] = logit;
    float mx = logit;
    mx = fmaxf(mx, __shfl_xor(mx, 1)); mx = fmaxf(mx, __shfl_xor(mx, 2)); mx = fmaxf(mx, __shfl_xor(mx, 4));
    float ex = __expf(logit - mx);
    float sm = ex;
    sm += __shfl_xor(sm, 1); sm += __shfl_xor(sm, 2); sm += __shfl_xor(sm, 4);
    float pp = ex / sm;
    float m1 = pp;
    m1 = fmaxf(m1, __shfl_xor(m1, 1)); m1 = fmaxf(m1, __shfl_xor(m1, 2)); m1 = fmaxf(m1, __shfl_xor(m1, 4));
    int cand = (pp == m1) ? e : 8;
    int e0 = cand;
    e0 = min(e0, __shfl_xor(e0, 1)); e0 = min(e0, __shfl_xor(e0, 2)); e0 = min(e0, __shfl_xor(e0, 4));
    float p2 = (e == e0) ? -1.0f : pp;
    float m2 = p2;
    m2 = fmaxf(m2, __shfl_xor(m2, 1)); m2 = fmaxf(m2, __shfl_xor(m2, 2)); m2 = fmaxf(m2, __shfl_xor(m2, 4));
    int cand2 = (p2 == m2) ? e : 8;
    int e1 = cand2;
    e1 = min(e1, __shfl_xor(e1, 1)); e1 = min(e1, __shfl_xor(e1, 2)); e1 = min(e1, __shfl_xor(e1, 4));
    if (lane == 0) {
        int ls0 = atomicAdd(&cnt[e0], 1);
        int ls1 = atomicAdd(&cnt[e1], 1);
        te[n * 2] = e0; te[n * 2 + 1] = e1;
        tls[n * 2] = ls0; tls[n * 2 + 1] = ls1;
        tw[n * 2] = m1; tw[n * 2 + 1] = m2;
    }
}

__global__ void k_prefix(const int* __restrict__ cnt, int* __restrict__ basep) {
    if (threadIdx.x == 0) {
        int s = 0;
        for (int e = 0; e < TE; e++) { basep[e] = s; s += cnt[e]; }
    }
}

__global__ void k_scatter(const int* __restrict__ te, const int* __restrict__ tls,
                          const float* __restrict__ tw, const int* __restrict__ basep,
                          int* __restrict__ tlist, float* __restrict__ slotw,
                          int* __restrict__ sot) {
    int n = blockIdx.x * 256 + threadIdx.x;
    if (n >= NTOK) return;
    int s0 = basep[te[n * 2]] + tls[n * 2];
    int s1 = basep[te[n * 2 + 1]] + tls[n * 2 + 1];
    tlist[s0] = n; tlist[s1] = n;
    slotw[s0] = tw[n * 2]; slotw[s1] = tw[n * 2 + 1];
    sot[n * 2] = s0; sot[n * 2 + 1] = s1;
}

// ---------------------------------------------------------------------------
// Fused FFN-up dual GEMM: silu(A*B1t) * (A*B2t).  BM=128, BN=64, BK=32.
// z = 0..7: MoE experts (gathered rows, weight folded), writes he [slot][FE].
// z = 8:    shared FFN, writes shm [n][FS].
// grid (32, 32, 9), block 256
// ---------------------------------------------------------------------------
__global__ __launch_bounds__(256) void k_ffn(const short* __restrict__ A,
                                             const short* __restrict__ eB1,
                                             const short* __restrict__ eB2,
                                             const short* __restrict__ sB1,
                                             const short* __restrict__ sB2,
                                             short* __restrict__ he,
                                             short* __restrict__ shm,
                                             const int* __restrict__ cnt,
                                             const int* __restrict__ basep,
                                             const int* __restrict__ tlist,
                                             const float* __restrict__ slotw) {
    int z = blockIdx.z;
    int moe = (z < 8);
    int nt = blockIdx.x, mt = blockIdx.y;
    int ce = 0, base = 0;
    if (moe) {
        if (nt >= 16) return;
        ce = cnt[z];
        if (mt * 128 >= ce) return;
        base = basep[z];
    }
    __shared__ short As[128 * 32];
    __shared__ short B1s[64 * 32];
    __shared__ short B2s[64 * 32];
    int tid = threadIdx.x, wid = tid >> 6, lane = tid & 63;
    int wr = wid >> 1, wc = wid & 1, g = lane >> 4, c = lane & 15;
    const int K = TC;
    int srow = wid * 32 + (lane >> 2);
    int scol = (lane & 3) * 8;
    size_t arow0, arow1;
    if (moe) {
        int l0 = mt * 128 + srow;      if (l0 >= ce) l0 = ce - 1;
        int l1 = mt * 128 + srow + 16; if (l1 >= ce) l1 = ce - 1;
        arow0 = (size_t)tlist[base + l0];
        arow1 = (size_t)tlist[base + l1];
    } else {
        arow0 = (size_t)(mt * 128 + srow);
        arow1 = arow0 + 16;
    }
    const short* Ag0 = A + arow0 * (size_t)K + scol;
    const short* Ag1 = A + arow1 * (size_t)K + scol;
    int sbrow = wid * 16 + (lane >> 2);
    const short* B1g;
    const short* B2g;
    if (moe) {
        B1g = eB1 + ((size_t)z * TFE + (size_t)(nt * 64 + sbrow)) * K + scol;
        B2g = eB2 + ((size_t)z * TFE + (size_t)(nt * 64 + sbrow)) * K + scol;
    } else {
        B1g = sB1 + (size_t)(nt * 64 + sbrow) * K + scol;
        B2g = sB2 + (size_t)(nt * 64 + sbrow) * K + scol;
    }
    int loffA = __builtin_amdgcn_readfirstlane(wid * 2048);
    int loffB = __builtin_amdgcn_readfirstlane(wid * 1024);
    char* Al = (char*)As + loffA;
    char* B1l = (char*)B1s + loffB;
    char* B2l = (char*)B2s + loffB;
    f32x4 a1[4][2] = {}, a2[4][2] = {};
    for (int kk = 0; kk < K; kk += 32) {
        __syncthreads();
        gl_lds16(Ag0 + kk, Al);
        gl_lds16(Ag1 + kk, Al + 1024);
        gl_lds16(B1g + kk, B1l);
        gl_lds16(B2g + kk, B2l);
        __syncthreads();
        s16x8 af[4], b1[2], b2[2];
        #pragma unroll
        for (int m_ = 0; m_ < 4; m_++) af[m_] = *(const s16x8*)(As + (wr * 64 + m_ * 16 + c) * 32 + g * 8);
        #pragma unroll
        for (int n = 0; n < 2; n++) {
            b1[n] = *(const s16x8*)(B1s + (wc * 32 + n * 16 + c) * 32 + g * 8);
            b2[n] = *(const s16x8*)(B2s + (wc * 32 + n * 16 + c) * 32 + g * 8);
        }
        #pragma unroll
        for (int m_ = 0; m_ < 4; m_++)
            #pragma unroll
            for (int n = 0; n < 2; n++) {
                a1[m_][n] = __builtin_amdgcn_mfma_f32_16x16x32_bf16(af[m_], b1[n], a1[m_][n], 0, 0, 0);
                a2[m_][n] = __builtin_amdgcn_mfma_f32_16x16x32_bf16(af[m_], b2[n], a2[m_][n], 0, 0, 0);
            }
    }
    #pragma unroll
    for (int m_ = 0; m_ < 4; m_++)
        #pragma unroll
        for (int n = 0; n < 2; n++)
            #pragma unroll
            for (int j = 0; j < 4; j++) {
                int lrow = mt * 128 + wr * 64 + m_ * 16 + g * 4 + j;
                if (moe && lrow >= ce) continue;
                int col = nt * 64 + wc * 32 + n * 16 + c;
                float g1 = a1[m_][n][j], g2 = a2[m_][n][j];
                float v = g1 / (1.0f + __expf(-g1)) * g2;
                if (moe) {
                    v *= slotw[base + lrow];
                    he[(size_t)(base + lrow) * TFE + col] = f2bf(v);
                } else {
                    shm[(size_t)lrow * TFS + col] = f2bf(v);
                }
            }
}

// ---------------------------------------------------------------------------
// MoE down-proj per expert: ye[slot] = he[slot] @ wp_e.  BM=128 BN=64.
// grid (16, 32, 8)
// ---------------------------------------------------------------------------
__global__ __launch_bounds__(256) void k_moe2(const short* __restrict__ he,
                                              const short* __restrict__ Wpt,
                                              short* __restrict__ ye,
                                              const int* __restrict__ cnt,
                                              const int* __restrict__ basep) {
    int e = blockIdx.z;
    int ce = cnt[e];
    int mt = blockIdx.y;
    if (mt * 128 >= ce) return;
    int base = basep[e];
    int nt = blockIdx.x;
    __shared__ short As[128 * 32];
    __shared__ short Bs[64 * 32];
    int tid = threadIdx.x, wid = tid >> 6, lane = tid & 63;
    int wr = wid >> 1, wc = wid & 1, g = lane >> 4, c = lane & 15;
    int srow = wid * 32 + (lane >> 2);
    int scol = (lane & 3) * 8;
    const short* Ag0 = he + (size_t)(base + mt * 128 + srow) * TFE + scol;
    const short* Ag1 = Ag0 + (size_t)16 * TFE;
    int sbrow = wid * 16 + (lane >> 2);
    const short* Bg = Wpt + ((size_t)e * 1024 + nt * 64 + sbrow) * TFE + scol;
    int loffA = __builtin_amdgcn_readfirstlane(wid * 2048);
    int loffB = __builtin_amdgcn_readfirstlane(wid * 1024);
    char* Al = (char*)As + loffA;
    char* Bl = (char*)Bs + loffB;
    f32x4 acc[4][2] = {};
    for (int kk = 0; kk < TFE; kk += 32) {
        __syncthreads();
        gl_lds16(Ag0 + kk, Al);
        gl_lds16(Ag1 + kk, Al + 1024);
        gl_lds16(Bg + kk, Bl);
        __syncthreads();
        s16x8 af[4], bf[2];
        #pragma unroll
        for (int m = 0; m < 4; m++) af[m] = *(const s16x8*)(As + (wr * 64 + m * 16 + c) * 32 + g * 8);
        #pragma unroll
        for (int n = 0; n < 2; n++) bf[n] = *(const s16x8*)(Bs + (wc * 32 + n * 16 + c) * 32 + g * 8);
        #pragma unroll
        for (int m = 0; m < 4; m++)
            #pragma unroll
            for (int n = 0; n < 2; n++)
                acc[m][n] = __builtin_amdgcn_mfma_f32_16x16x32_bf16(af[m], bf[n], acc[m][n], 0, 0, 0);
    }
    #pragma unroll
    for (int m = 0; m < 4; m++)
        #pragma unroll
        for (int n = 0; n < 2; n++)
            #pragma unroll
            for (int j = 0; j < 4; j++) {
                int lrow = mt * 128 + wr * 64 + m * 16 + g * 4 + j;
                if (lrow >= ce) continue;
                int col = nt * 64 + wc * 32 + n * 16 + c;
                ye[(size_t)(base + lrow) * TC + col] = f2bf(acc[m][n][j]);
            }
}

// ---------------------------------------------------------------------------
// Final: out = shm @ swp_t + x1 + ye[s0] + ye[s1].  M=4096 N=1024 K=2048
// BM=128 BN=64.  grid (16, 32)
// ---------------------------------------------------------------------------
__global__ __launch_bounds__(256) void k_final(const short* __restrict__ A,
                                               const short* __restrict__ Bt,
                                               const float* __restrict__ x1,
                                               const short* __restrict__ ye,
                                               const int* __restrict__ sot,
                                               float* __restrict__ outp) {
    __shared__ short As[128 * 32];
    __shared__ short Bs[64 * 32];
    const int K = TFS;
    int tid = threadIdx.x;
    int brow = blockIdx.y * 128, bcol = blockIdx.x * 64;
    int wid = tid >> 6, lane = tid & 63;
    int wr = wid >> 1, wc = wid & 1, g = lane >> 4, c = lane & 15;
    int srow = wid * 32 + (lane >> 2);
    int scol = (lane & 3) * 8;
    const short* Ag0 = A + (size_t)(brow + srow) * K + scol;
    const short* Ag1 = A + (size_t)(brow + srow + 16) * K + scol;
    int sbrow = wid * 16 + (lane >> 2);
    const short* Bg = Bt + (size_t)(bcol + sbrow) * K + scol;
    int loffA = __builtin_amdgcn_readfirstlane(wid * 2048);
    int loffB = __builtin_amdgcn_readfirstlane(wid * 1024);
    char* Al = (char*)As + loffA;
    char* Bl = (char*)Bs + loffB;
    f32x4 acc[4][2] = {};
    for (int kk = 0; kk < K; kk += 32) {
        __syncthreads();
        gl_lds16(Ag0 + kk, Al);
        gl_lds16(Ag1 + kk, Al + 1024);
        gl_lds16(Bg + kk, Bl);
        __syncthreads();
        s16x8 af[4], bf[2];
        #pragma unroll
        for (int m = 0; m < 4; m++) af[m] = *(const s16x8*)(As + (wr * 64 + m * 16 + c) * 32 + g * 8);
        #pragma unroll
        for (int n = 0; n < 2; n++) bf[n] = *(const s16x8*)(Bs + (wc * 32 + n * 16 + c) * 32 + g * 8);
        #pragma unroll
        for (int m = 0; m < 4; m++)
            #pragma unroll
            for (int n = 0; n < 2; n++)
                acc[m][n] = __builtin_amdgcn_mfma_f32_16x16x32_bf16(af[m], bf[n], acc[m][n], 0, 0, 0);
    }
    #pragma unroll
    for (int m = 0; m < 4; m++)
        #pragma unroll
        for (int n = 0; n < 2; n++)
            #pragma unroll
            for (int j = 0; j < 4; j++) {
                int row = brow + wr * 64 + m * 16 + g * 4 + j;
                int col = bcol + wc * 32 + n * 16 + c;
                int s0 = sot[row * 2], s1 = sot[row * 2 + 1];
                float v = acc[m][n][j] + x1[(size_t)row * TC + col]
                        + bf2f(ye[(size_t)s0 * TC + col]) + bf2f(ye[(size_t)s1 * TC + col]);
                outp[(size_t)row * TC + col] = v;
            }
}

// ---------------------------------------------------------------------------
// Launch
// ---------------------------------------------------------------------------
extern "C" void kernel_launch(void* const* d_in, const int* in_sizes, int n_in,
                              void* d_out, int out_size, void* d_ws, size_t ws_size,
                              hipStream_t stream) {
    const float* x     = (const float*)d_in[0];
    const float* n1w   = (const float*)d_in[1];
    const float* n2w   = (const float*)d_in[2];
    const float* wq    = (const float*)d_in[3];
    const float* wk    = (const float*)d_in[4];
    const float* wv    = (const float*)d_in[5];
    const float* wo    = (const float*)d_in[6];
    const float* gatew = (const float*)d_in[7];
    const float* ew1   = (const float*)d_in[8];
    const float* ew2   = (const float*)d_in[9];
    const float* ewp   = (const float*)d_in[10];
    const float* sw1   = (const float*)d_in[11];
    const float* sw2   = (const float*)d_in[12];
    const float* swp   = (const float*)d_in[13];
    float* outp = (float*)d_out;

    char* p = (char*)d_ws;
    auto alloc = [&](size_t bytes) -> char* {
        char* r = p;
        p += (bytes + 255) & ~(size_t)255;
        return r;
    };
    short* wqkv_t = (short*)alloc(1536 * 1024 * 2);
    short* wo_t   = (short*)alloc(1024 * 1024 * 2);
    short* ew1_t  = (short*)alloc((size_t)8 * 1024 * 1024 * 2);
    short* ew2_t  = (short*)alloc((size_t)8 * 1024 * 1024 * 2);
    short* ewp_t  = (short*)alloc((size_t)8 * 1024 * 1024 * 2);
    short* sw1_t  = (short*)alloc((size_t)2048 * 1024 * 2);
    short* sw2_t  = (short*)alloc((size_t)2048 * 1024 * 2);
    short* swp_t  = (short*)alloc((size_t)1024 * 2048 * 2);
    short* h1     = (short*)alloc((size_t)NTOK * 1024 * 2);
    short* qkv    = (short*)alloc((size_t)NTOK * 1536 * 2);
    short* q_r    = (short*)alloc((size_t)TB * TH * TT * THD * 2);
    short* k_r    = (short*)alloc((size_t)TB * TKV * TT * THD * 2);
    short* v_t    = (short*)alloc((size_t)TB * TKV * THD * TT * 2);
    short* attn_o = (short*)alloc((size_t)NTOK * 1024 * 2);
    float* x1     = (float*)alloc((size_t)NTOK * 1024 * 4);
    short* h2     = (short*)alloc((size_t)NTOK * 1024 * 2);
    float* rope   = (float*)alloc((size_t)TT * 32 * 2 * 4);
    int*   cnt    = (int*)alloc(256);
    int*   basep  = (int*)alloc(256);
    int*   te     = (int*)alloc((size_t)NTOK * 2 * 4);
    int*   tls    = (int*)alloc((size_t)NTOK * 2 * 4);
    float* tw     = (float*)alloc((size_t)NTOK * 2 * 4);
    int*   tlist  = (int*)alloc((size_t)NSLOT * 4);
    float* slotw  = (float*)alloc((size_t)NSLOT * 4);
    int*   sot    = (int*)alloc((size_t)NTOK * 2 * 4);
    short* he     = (short*)alloc((size_t)NSLOT * TFE * 2);
    short* ye     = (short*)alloc((size_t)NSLOT * TC * 2);
    short* shm    = (short*)alloc((size_t)NTOK * TFS * 2);

    dim3 blk(256);

    k_transp<<<dim3(32, 32, 1), blk, 0, stream>>>(wq, wqkv_t, 1024, 1024, 0, 0);
    k_transp<<<dim3(8, 32, 1), blk, 0, stream>>>(wk, wqkv_t + 1024 * 1024, 1024, 256, 0, 0);
    k_transp<<<dim3(8, 32, 1), blk, 0, stream>>>(wv, wqkv_t + 1280 * 1024, 1024, 256, 0, 0);
    k_transp<<<dim3(32, 32, 1), blk, 0, stream>>>(wo, wo_t, 1024, 1024, 0, 0);
    k_transp<<<dim3(32, 32, 8), blk, 0, stream>>>(ew1, ew1_t, 1024, 1024, 1048576, 1048576);
    k_transp<<<dim3(32, 32, 8), blk, 0, stream>>>(ew2, ew2_t, 1024, 1024, 1048576, 1048576);
    k_transp<<<dim3(32, 32, 8), blk, 0, stream>>>(ewp, ewp_t, 1024, 1024, 1048576, 1048576);
    k_transp<<<dim3(64, 32, 1), blk, 0, stream>>>(sw1, sw1_t, 1024, 2048, 0, 0);
    k_transp<<<dim3(64, 32, 1), blk, 0, stream>>>(sw2, sw2_t, 1024, 2048, 0, 0);
    k_transp<<<dim3(32, 64, 1), blk, 0, stream>>>(swp, swp_t, 2048, 1024, 0, 0);

    k_rope_table<<<(TT * 32 + 255) / 256, blk, 0, stream>>>(rope);

    k_rmsnorm<<<NTOK, blk, 0, stream>>>(x, n1w, h1);
    k_gemm64<0><<<dim3(24, 32), blk, 0, stream>>>(h1, wqkv_t, qkv, nullptr, NTOK, 1536, 1024);
    k_rope_apply<<<(NTOK * 640 + 255) / 256, blk, 0, stream>>>(qkv, rope, q_r, k_r);
    k_transp_v<<<dim3(2, 64, 8), blk, 0, stream>>>(qkv, v_t);

    k_attn<<<dim3(16, TB * TH), blk, 0, stream>>>(q_r, k_r, v_t, attn_o);

    k_gemm64<1><<<dim3(16, 32), blk, 0, stream>>>(attn_o, wo_t, x1, x, NTOK, 1024, 1024);

    k_rmsnorm<<<NTOK, blk, 0, stream>>>(x1, n2w, h2);

    hipMemsetAsync(cnt, 0, 64, stream);
    k_gate<<<NTOK / 4, blk, 0, stream>>>(x1, n2w, gatew, outp + (size_t)NTOK * TC, cnt, te, tls, tw);
    k_prefix<<<1, 64, 0, stream>>>(cnt, basep);
    k_scatter<<<NTOK / 256, blk, 0, stream>>>(te, tls, tw, basep, tlist, slotw, sot);

    k_ffn<<<dim3(32, 32, 9), blk, 0, stream>>>(h2, ew1_t, ew2_t, sw1_t, sw2_t, he, shm,
                                               cnt, basep, tlist, slotw);
    k_moe2<<<dim3(16, 32, 8), blk, 0, stream>>>(he, ewp_t, ye, cnt, basep);

    k_final<<<dim3(16, 32), blk, 0, stream>>>(shm, swp_t, x1, ye, sot, outp);

    (void)in_sizes; (void)n_in; (void)out_size; (void)ws_size;
}

// Round 4
// 746.809 us; speedup vs baseline: 1.2584x; 1.0156x over previous
//
#include <hip/hip_runtime.h>
#include <hip/hip_bf16.h>

// ---------------------------------------------------------------------------
// Problem constants
// ---------------------------------------------------------------------------
#define TB 2
#define TT 2048
#define TC 1024
#define TH 16
#define TKV 4
#define THD 64
#define TE 8
#define TFE 1024
#define TFS 2048
#define NTOK 4096           // B*T
#define NSLOT 8192          // NTOK * K(=2)

typedef __attribute__((ext_vector_type(4))) float f32x4;
typedef __attribute__((ext_vector_type(16))) float f32x16;
typedef __attribute__((ext_vector_type(8))) short s16x8;

__device__ __forceinline__ float bf2f(short s) {
    unsigned int u = ((unsigned int)(unsigned short)s) << 16;
    return __builtin_bit_cast(float, u);
}
__device__ __forceinline__ short f2bf(float f) {
    unsigned int u = __builtin_bit_cast(unsigned int, f);
    u = u + 0x7fffu + ((u >> 16) & 1u);     // RNE
    return (short)(u >> 16);
}
__device__ __forceinline__ unsigned int cvtpk_bf16(float lo, float hi) {
    unsigned int r;
    asm volatile("v_cvt_pk_bf16_f32 %0, %1, %2" : "=v"(r) : "v"(lo), "v"(hi));
    return r;
}

// async global->LDS, 16B per lane. lds ptr must be wave-uniform base;
// HW writes lane l's 16B to base + l*16. Global source is per-lane.
__device__ __forceinline__ void gl_lds16(const void* g, void* l) {
    __builtin_amdgcn_global_load_lds((const __attribute__((address_space(1))) void*)g,
                                     (__attribute__((address_space(3))) void*)l,
                                     16, 0, 0);
}

// ---------------------------------------------------------------------------
// Transpose + f32->bf16 convert:  in f32 [R][Cd] -> out bf16 [Cd][R], batched
// ---------------------------------------------------------------------------
__global__ __launch_bounds__(256) void k_transp(const float* __restrict__ in,
                                                short* __restrict__ out,
                                                int R, int Cd,
                                                size_t bs_in, size_t bs_out) {
    __shared__ float tile[32][33];
    const float* ip = in + bs_in * blockIdx.z;
    short* op = out + bs_out * blockIdx.z;
    int tx = threadIdx.x & 31, ty = threadIdx.x >> 5;
    int r0 = blockIdx.y * 32, c0 = blockIdx.x * 32;
    #pragma unroll
    for (int r = ty; r < 32; r += 8)
        tile[r][tx] = ip[(size_t)(r0 + r) * Cd + c0 + tx];
    __syncthreads();
    #pragma unroll
    for (int r = ty; r < 32; r += 8)
        op[(size_t)(c0 + r) * R + r0 + tx] = f2bf(tile[tx][r]);
}

// ---------------------------------------------------------------------------
// V transpose (bf16 -> bf16): qkv v-columns [T][64] per (b,kv) -> v_t [64][T]
// ---------------------------------------------------------------------------
__global__ __launch_bounds__(256) void k_transp_v(const short* __restrict__ qkv,
                                                  short* __restrict__ v_t) {
    __shared__ short tile[32][33];
    int z = blockIdx.z;
    int b = z >> 2, kvh = z & 3;
    const short* ip = qkv + (size_t)b * TT * 1536 + 1280 + kvh * 64;
    short* op = v_t + (size_t)z * THD * TT;
    int tx = threadIdx.x & 31, ty = threadIdx.x >> 5;
    int t0 = blockIdx.y * 32, d0 = blockIdx.x * 32;
    #pragma unroll
    for (int r = ty; r < 32; r += 8)
        tile[r][tx] = ip[(size_t)(t0 + r) * 1536 + d0 + tx];
    __syncthreads();
    #pragma unroll
    for (int r = ty; r < 32; r += 8)
        op[(size_t)(d0 + r) * TT + t0 + tx] = tile[tx][r];
}

// ---------------------------------------------------------------------------
// RoPE table: [T][32][2] f32  (cos, sin)
// ---------------------------------------------------------------------------
__global__ void k_rope_table(float* __restrict__ rope) {
    int idx = blockIdx.x * 256 + threadIdx.x;
    if (idx >= TT * 32) return;
    int t = idx >> 5, i = idx & 31;
    float freq = expf(-(float)i * (1.0f / 32.0f) * 9.210340371976184f); // 10000^(-i/32)
    float ang = (float)t * freq;
    rope[idx * 2 + 0] = cosf(ang);
    rope[idx * 2 + 1] = sinf(ang);
}

// ---------------------------------------------------------------------------
// RMSNorm: f32 [4096][1024] -> bf16 [4096][1024].  block 256 = one row
// ---------------------------------------------------------------------------
__global__ __launch_bounds__(256) void k_rmsnorm(const float* __restrict__ x,
                                                 const float* __restrict__ w,
                                                 short* __restrict__ out) {
    int row = blockIdx.x, t = threadIdx.x;
    float4 v = ((const float4*)(x + (size_t)row * TC))[t];
    float ss = v.x * v.x + v.y * v.y + v.z * v.z + v.w * v.w;
    #pragma unroll
    for (int off = 32; off; off >>= 1) ss += __shfl_xor(ss, off);
    __shared__ float red[4];
    if ((t & 63) == 0) red[t >> 6] = ss;
    __syncthreads();
    float rs = rsqrtf((red[0] + red[1] + red[2] + red[3]) * (1.0f / 1024.0f) + 1e-6f);
    float4 wv = ((const float4*)w)[t];
    short4 o;
    o.x = f2bf(v.x * rs * wv.x);
    o.y = f2bf(v.y * rs * wv.y);
    o.z = f2bf(v.z * rs * wv.z);
    o.w = f2bf(v.w * rs * wv.w);
    ((short4*)(out + (size_t)row * TC))[t] = o;
}

// ---------------------------------------------------------------------------
// 128x128 GEMM, global_load_lds staging (m97 pattern):
// C[M,N] = A[M,K](bf16) * Bt[N,K](bf16)
// EPI 0: out bf16 = acc;   EPI 1: out f32 = acc + resid
// grid (N/128, M/128), block 256
// ---------------------------------------------------------------------------
template <int EPI>
__global__ __launch_bounds__(256) void k_gemm128(const short* __restrict__ A,
                                                 const short* __restrict__ Bt,
                                                 void* __restrict__ outp,
                                                 const float* __restrict__ resid,
                                                 int M, int N, int K) {
    __shared__ short As[128 * 32];
    __shared__ short Bs[128 * 32];
    int tid = threadIdx.x;
    int brow = blockIdx.y * 128, bcol = blockIdx.x * 128;
    int wid = tid >> 6, lane = tid & 63;
    int wr = wid >> 1, wc = wid & 1, g = lane >> 4, c = lane & 15;
    int srow = wid * 32 + (lane >> 2);
    int scol = (lane & 3) * 8;
    const short* Ag0 = A + (size_t)(brow + srow) * K + scol;
    const short* Ag1 = A + (size_t)(brow + srow + 16) * K + scol;
    const short* Bg0 = Bt + (size_t)(bcol + srow) * K + scol;
    const short* Bg1 = Bt + (size_t)(bcol + srow + 16) * K + scol;
    int loff = __builtin_amdgcn_readfirstlane(wid * 2048);
    char* Al0 = (char*)As + loff;
    char* Bl0 = (char*)Bs + loff;
    f32x4 acc[4][4] = {};
    for (int kk = 0; kk < K; kk += 32) {
        __syncthreads();
        gl_lds16(Ag0 + kk, Al0);
        gl_lds16(Ag1 + kk, Al0 + 1024);
        gl_lds16(Bg0 + kk, Bl0);
        gl_lds16(Bg1 + kk, Bl0 + 1024);
        __syncthreads();
        s16x8 af[4], bf[4];
        #pragma unroll
        for (int m = 0; m < 4; m++) af[m] = *(const s16x8*)(As + (wr * 64 + m * 16 + c) * 32 + g * 8);
        #pragma unroll
        for (int n = 0; n < 4; n++) bf[n] = *(const s16x8*)(Bs + (wc * 64 + n * 16 + c) * 32 + g * 8);
        #pragma unroll
        for (int m = 0; m < 4; m++)
            #pragma unroll
            for (int n = 0; n < 4; n++)
                acc[m][n] = __builtin_amdgcn_mfma_f32_16x16x32_bf16(af[m], bf[n], acc[m][n], 0, 0, 0);
    }
    #pragma unroll
    for (int m = 0; m < 4; m++)
        #pragma unroll
        for (int n = 0; n < 4; n++)
            #pragma unroll
            for (int j = 0; j < 4; j++) {
                int row = brow + wr * 64 + m * 16 + g * 4 + j;
                int col = bcol + wc * 64 + n * 16 + c;
                float v = acc[m][n][j];
                if (EPI == 0)
                    ((short*)outp)[(size_t)row * N + col] = f2bf(v);
                else
                    ((float*)outp)[(size_t)row * N + col] = v + resid[(size_t)row * N + col];
            }
}

// ---------------------------------------------------------------------------
// 128x64 GEMM, global_load_lds staging (for N=1024 outputs: wo, final-ish)
// ---------------------------------------------------------------------------
template <int EPI>
__global__ __launch_bounds__(256) void k_gemm64(const short* __restrict__ A,
                                                const short* __restrict__ Bt,
                                                void* __restrict__ outp,
                                                const float* __restrict__ resid,
                                                int M, int N, int K) {
    __shared__ short As[128 * 32];
    __shared__ short Bs[64 * 32];
    int tid = threadIdx.x;
    int brow = blockIdx.y * 128, bcol = blockIdx.x * 64;
    int wid = tid >> 6, lane = tid & 63;
    int wr = wid >> 1, wc = wid & 1, g = lane >> 4, c = lane & 15;
    int srow = wid * 32 + (lane >> 2);
    int scol = (lane & 3) * 8;
    const short* Ag0 = A + (size_t)(brow + srow) * K + scol;
    const short* Ag1 = A + (size_t)(brow + srow + 16) * K + scol;
    int sbrow = wid * 16 + (lane >> 2);
    const short* Bg = Bt + (size_t)(bcol + sbrow) * K + scol;
    int loffA = __builtin_amdgcn_readfirstlane(wid * 2048);
    int loffB = __builtin_amdgcn_readfirstlane(wid * 1024);
    char* Al = (char*)As + loffA;
    char* Bl = (char*)Bs + loffB;
    f32x4 acc[4][2] = {};
    for (int kk = 0; kk < K; kk += 32) {
        __syncthreads();
        gl_lds16(Ag0 + kk, Al);
        gl_lds16(Ag1 + kk, Al + 1024);
        gl_lds16(Bg + kk, Bl);
        __syncthreads();
        s16x8 af[4], bf[2];
        #pragma unroll
        for (int m = 0; m < 4; m++) af[m] = *(const s16x8*)(As + (wr * 64 + m * 16 + c) * 32 + g * 8);
        #pragma unroll
        for (int n = 0; n < 2; n++) bf[n] = *(const s16x8*)(Bs + (wc * 32 + n * 16 + c) * 32 + g * 8);
        #pragma unroll
        for (int m = 0; m < 4; m++)
            #pragma unroll
            for (int n = 0; n < 2; n++)
                acc[m][n] = __builtin_amdgcn_mfma_f32_16x16x32_bf16(af[m], bf[n], acc[m][n], 0, 0, 0);
    }
    #pragma unroll
    for (int m = 0; m < 4; m++)
        #pragma unroll
        for (int n = 0; n < 2; n++)
            #pragma unroll
            for (int j = 0; j < 4; j++) {
                int row = brow + wr * 64 + m * 16 + g * 4 + j;
                int col = bcol + wc * 32 + n * 16 + c;
                float v = acc[m][n][j];
                if (EPI == 0)
                    ((short*)outp)[(size_t)row * N + col] = f2bf(v);
                else
                    ((float*)outp)[(size_t)row * N + col] = v + resid[(size_t)row * N + col];
            }
}

// ---------------------------------------------------------------------------
// RoPE apply + scatter (q, k only; v handled by k_transp_v).
// ---------------------------------------------------------------------------
__global__ void k_rope_apply(const short* __restrict__ qkv,
                             const float* __restrict__ rope,
                             short* __restrict__ q_r,
                             short* __restrict__ k_r) {
    int idx = blockIdx.x * 256 + threadIdx.x;
    if (idx >= NTOK * 640) return;
    int row = idx / 640;
    int p = idx - row * 640;
    int b = row >> 11, t = row & 2047;
    const short* src = qkv + (size_t)row * 1536;
    if (p < 512) {            // q
        int h = p >> 5, i = p & 31;
        float x0 = bf2f(src[h * 64 + 2 * i]);
        float x1 = bf2f(src[h * 64 + 2 * i + 1]);
        float cs = rope[(t * 32 + i) * 2], sn = rope[(t * 32 + i) * 2 + 1];
        size_t o = ((size_t)(b * TH + h) * TT + t) * THD + 2 * i;
        q_r[o]     = f2bf(x0 * cs - x1 * sn);
        q_r[o + 1] = f2bf(x1 * cs + x0 * sn);
    } else {                  // k
        int pk = p - 512;
        int kv = pk >> 5, i = pk & 31;
        float x0 = bf2f(src[1024 + kv * 64 + 2 * i]);
        float x1 = bf2f(src[1024 + kv * 64 + 2 * i + 1]);
        float cs = rope[(t * 32 + i) * 2], sn = rope[(t * 32 + i) * 2 + 1];
        size_t o = ((size_t)(b * TKV + kv) * TT + t) * THD + 2 * i;
        k_r[o]     = f2bf(x0 * cs - x1 * sn);
        k_r[o + 1] = f2bf(x1 * cs + x0 * sn);
    }
}

// ---------------------------------------------------------------------------
// Flash attention, swapped-operand 32x32 structure (m214-style).
// grid (16, B*H), block 256 = 4 independent waves; wave handles 32 q-rows.
// ---------------------------------------------------------------------------
__global__ __launch_bounds__(256) void k_attn(const short* __restrict__ q_r,
                                              const short* __restrict__ k_r,
                                              const short* __restrict__ v_t,
                                              short* __restrict__ attn_o) {
    int w = threadIdx.x >> 6, lane = threadIdx.x & 63;
    int qt = 63 - (blockIdx.x * 4 + w);     // long waves first
    int qbase = qt * 32;
    int bh = blockIdx.y;
    int b = bh >> 4, h = bh & 15, kv = h >> 2;
    int q32 = lane & 31, hi = lane >> 5;

    const short* qp = q_r + ((size_t)(b * TH + h) * TT + qbase) * THD;
    const short* kp = k_r + ((size_t)(b * TKV + kv) * TT) * THD;
    const short* vp = v_t + ((size_t)(b * TKV + kv) * THD) * TT;

    s16x8 qf[4];
    #pragma unroll
    for (int dc = 0; dc < 4; dc++)
        qf[dc] = *(const s16x8*)(qp + q32 * THD + dc * 16 + hi * 8);

    f32x16 ot0 = {}, ot1 = {};
    float mrun = -1e30f, lrun = 0.f;
    int nkt = (qbase + 95) >> 6;

    for (int kt = 0; kt < nkt; kt++) {
        int ktb = kt * 64;
        f32x16 st0 = {}, st1 = {};
        s16x8 kf0[4], kf1[4];
        #pragma unroll
        for (int dc = 0; dc < 4; dc++) {
            kf0[dc] = *(const s16x8*)(kp + (size_t)(ktb + q32) * THD + dc * 16 + hi * 8);
            kf1[dc] = *(const s16x8*)(kp + (size_t)(ktb + 32 + q32) * THD + dc * 16 + hi * 8);
        }
        s16x8 vf[8];
        #pragma unroll
        for (int dt = 0; dt < 2; dt++)
            #pragma unroll
            for (int kc = 0; kc < 4; kc++)
                vf[dt * 4 + kc] = *(const s16x8*)(vp + (size_t)(dt * 32 + q32) * TT + ktb + kc * 16 + hi * 8);

        __builtin_amdgcn_s_setprio(1);
        #pragma unroll
        for (int dc = 0; dc < 4; dc++) {
            st0 = __builtin_amdgcn_mfma_f32_32x32x16_bf16(kf0[dc], qf[dc], st0, 0, 0, 0);
            st1 = __builtin_amdgcn_mfma_f32_32x32x16_bf16(kf1[dc], qf[dc], st1, 0, 0, 0);
        }
        __builtin_amdgcn_s_setprio(0);

        bool domask = (kt == nkt - 1);
        int qabs = qbase + q32;
        #pragma unroll
        for (int r = 0; r < 16; r++) {
            int kploc = (r & 3) + 8 * (r >> 2) + 4 * hi;
            float s0 = st0[r] * 0.125f;
            float s1 = st1[r] * 0.125f;
            if (domask) {
                if (ktb + kploc > qabs) s0 = -1e30f;
                if (ktb + 32 + kploc > qabs) s1 = -1e30f;
            }
            st0[r] = s0; st1[r] = s1;
        }
        float pm = st0[0];
        #pragma unroll
        for (int r = 1; r < 16; r++) pm = fmaxf(pm, st0[r]);
        #pragma unroll
        for (int r = 0; r < 16; r++) pm = fmaxf(pm, st1[r]);
        pm = fmaxf(pm, __shfl_xor(pm, 32));
        float mnew = fmaxf(mrun, pm);
        float al = __expf(mrun - mnew);
        mrun = mnew;
        float rs = 0.f;
        #pragma unroll
        for (int r = 0; r < 16; r++) {
            float e0 = __expf(st0[r] - mnew); st0[r] = e0; rs += e0;
            float e1 = __expf(st1[r] - mnew); st1[r] = e1; rs += e1;
        }
        rs += __shfl_xor(rs, 32);
        lrun = lrun * al + rs;
        #pragma unroll
        for (int r = 0; r < 16; r++) { ot0[r] *= al; ot1[r] *= al; }

        unsigned int w0[8], w1[8];
        #pragma unroll
        for (int j = 0; j < 8; j++) {
            w0[j] = cvtpk_bf16(st0[2 * j], st0[2 * j + 1]);
            w1[j] = cvtpk_bf16(st1[2 * j], st1[2 * j + 1]);
        }
        s16x8 pf[4];
        #pragma unroll
        for (int kc = 0; kc < 4; kc++) {
            unsigned int* ww = (kc < 2) ? w0 : w1;
            int kcl = kc & 1;
            unsigned int x0 = ww[4 * kcl + 0], y0 = ww[4 * kcl + 2];
            unsigned int x1 = ww[4 * kcl + 1], y1 = ww[4 * kcl + 3];
            asm volatile("v_permlane32_swap_b32 %0, %1" : "+v"(x0), "+v"(y0));
            asm volatile("v_permlane32_swap_b32 %0, %1" : "+v"(x1), "+v"(y1));
            unsigned int fr[4] = {x0, x1, y0, y1};
            pf[kc] = __builtin_bit_cast(s16x8, *(ulong2*)fr);
        }
        __builtin_amdgcn_s_setprio(1);
        #pragma unroll
        for (int kc = 0; kc < 4; kc++) {
            ot0 = __builtin_amdgcn_mfma_f32_32x32x16_bf16(vf[kc], pf[kc], ot0, 0, 0, 0);
            ot1 = __builtin_amdgcn_mfma_f32_32x32x16_bf16(vf[4 + kc], pf[kc], ot1, 0, 0, 0);
        }
        __builtin_amdgcn_s_setprio(0);
    }
    float inv = 1.0f / lrun;
    short* orow = attn_o + (size_t)(b * TT + qbase + q32) * TC + h * THD;
    #pragma unroll
    for (int s = 0; s < 4; s++) {
        short4 v0, v1;
        v0.x = f2bf(ot0[4 * s + 0] * inv); v0.y = f2bf(ot0[4 * s + 1] * inv);
        v0.z = f2bf(ot0[4 * s + 2] * inv); v0.w = f2bf(ot0[4 * s + 3] * inv);
        v1.x = f2bf(ot1[4 * s + 0] * inv); v1.y = f2bf(ot1[4 * s + 1] * inv);
        v1.z = f2bf(ot1[4 * s + 2] * inv); v1.w = f2bf(ot1[4 * s + 3] * inv);
        *(short4*)(orow + 8 * s + 4 * hi) = v0;
        *(short4*)(orow + 32 + 8 * s + 4 * hi) = v1;
    }
}

// ---------------------------------------------------------------------------
// Gate: f32 logits from x1 (recompute rms in f32), softmax, top-2, counts.
// ---------------------------------------------------------------------------
__global__ __launch_bounds__(256) void k_gate(const float* __restrict__ x1,
                                              const float* __restrict__ n2w,
                                              const float* __restrict__ gate_w,
                                              float* __restrict__ gl,
                                              int* __restrict__ cnt,
                                              int* __restrict__ te,
                                              int* __restrict__ tls,
                                              float* __restrict__ tw) {
    int w = threadIdx.x >> 6, lane = threadIdx.x & 63;
    int n = blockIdx.x * 4 + w;
    const float* xp = x1 + (size_t)n * TC;
    float ss = 0.f;
    for (int i = lane; i < TC; i += 64) { float v = xp[i]; ss += v * v; }
    #pragma unroll
    for (int off = 32; off; off >>= 1) ss += __shfl_xor(ss, off);
    float rs = rsqrtf(ss * (1.0f / 1024.0f) + 1e-6f);
    int e = lane & 7, ch = lane >> 3;
    float acc = 0.f;
    for (int i = 0; i < 128; i++) {
        int cc = ch * 128 + i;
        acc += xp[cc] * rs * n2w[cc] * gate_w[(size_t)cc * TE + e];
    }
    acc += __shfl_xor(acc, 8);
    acc += __shfl_xor(acc, 16);
    acc += __shfl_xor(acc, 32);
    float logit = acc;
    if (lane < 8) gl[(size_t)n * TE + lane] = logit;
    float mx = logit;
    mx = fmaxf(mx, __shfl_xor(mx, 1)); mx = fmaxf(mx, __shfl_xor(mx, 2)); mx = fmaxf(mx, __shfl_xor(mx, 4));
    float ex = __expf(logit - mx);
    float sm = ex;
    sm += __shfl_xor(sm, 1); sm += __shfl_xor(sm, 2); sm += __shfl_xor(sm, 4);
    float pp = ex / sm;
    float m1 = pp;
    m1 = fmaxf(m1, __shfl_xor(m1, 1)); m1 = fmaxf(m1, __shfl_xor(m1, 2)); m1 = fmaxf(m1, __shfl_xor(m1, 4));
    int cand = (pp == m1) ? e : 8;
    int e0 = cand;
    e0 = min(e0, __shfl_xor(e0, 1)); e0 = min(e0, __shfl_xor(e0, 2)); e0 = min(e0, __shfl_xor(e0, 4));
    float p2 = (e == e0) ? -1.0f : pp;
    float m2 = p2;
    m2 = fmaxf(m2, __shfl_xor(m2, 1)); m2 = fmaxf(m2, __shfl_xor(m2, 2)); m2 = fmaxf(m2, __shfl_xor(m2, 4));
    int cand2 = (p2 == m2) ? e : 8;
    int e1 = cand2;
    e1 = min(e1, __shfl_xor(e1, 1)); e1 = min(e1, __shfl_xor(e1, 2)); e1 = min(e1, __shfl_xor(e1, 4));
    if (lane == 0) {
        int ls0 = atomicAdd(&cnt[e0], 1);
        int ls1 = atomicAdd(&cnt[e1], 1);
        te[n * 2] = e0; te[n * 2 + 1] = e1;
        tls[n * 2] = ls0; tls[n * 2 + 1] = ls1;
        tw[n * 2] = m1; tw[n * 2 + 1] = m2;
    }
}

__global__ void k_prefix(const int* __restrict__ cnt, int* __restrict__ basep) {
    if (threadIdx.x == 0) {
        int s = 0;
        for (int e = 0; e < TE; e++) { basep[e] = s; s += cnt[e]; }
    }
}

__global__ void k_scatter(const int* __restrict__ te, const int* __restrict__ tls,
                          const float* __restrict__ tw, const int* __restrict__ basep,
                          int* __restrict__ tlist, float* __restrict__ slotw,
                          int* __restrict__ sot) {
    int n = blockIdx.x * 256 + threadIdx.x;
    if (n >= NTOK) return;
    int s0 = basep[te[n * 2]] + tls[n * 2];
    int s1 = basep[te[n * 2 + 1]] + tls[n * 2 + 1];
    tlist[s0] = n; tlist[s1] = n;
    slotw[s0] = tw[n * 2]; slotw[s1] = tw[n * 2 + 1];
    sot[n * 2] = s0; sot[n * 2 + 1] = s1;
}

// ---------------------------------------------------------------------------
// Fused FFN-up dual GEMM: silu(A*B1t) * (A*B2t).  BM=128, BN=128, BK=32.
// 512 threads = 8 waves (2 M-halves x 4 N-quarters); each wave 64x32 per mat.
// Per wave per K-step: 3 gload_lds, 8 ds_read_b128, 16 MFMA (m97 ratio).
// z = 0..7: MoE experts (gathered rows, weight folded) -> he [slot][FE]
// z = 8:    shared FFN -> shm [n][FS]
// grid (16, 32, 9), block 512
// ---------------------------------------------------------------------------
__global__ __launch_bounds__(512) void k_ffn(const short* __restrict__ A,
                                             const short* __restrict__ eB1,
                                             const short* __restrict__ eB2,
                                             const short* __restrict__ sB1,
                                             const short* __restrict__ sB2,
                                             short* __restrict__ he,
                                             short* __restrict__ shm,
                                             const int* __restrict__ cnt,
                                             const int* __restrict__ basep,
                                             const int* __restrict__ tlist,
                                             const float* __restrict__ slotw) {
    int z = blockIdx.z;
    int moe = (z < 8);
    int nt = blockIdx.x, mt = blockIdx.y;
    int ce = 0, base = 0;
    if (moe) {
        if (nt >= 8) return;              // expert FE = 1024 -> 8 col tiles
        ce = cnt[z];
        if (mt * 128 >= ce) return;
        base = basep[z];
    }
    __shared__ short As[128 * 32];
    __shared__ short B1s[128 * 32];
    __shared__ short B2s[128 * 32];
    int tid = threadIdx.x, wid = tid >> 6, lane = tid & 63;
    int wr = wid >> 2, wc = wid & 3, g = lane >> 4, c = lane & 15;
    const int K = TC;
    // staging: each wave covers 16 rows (1 KiB chunk) of each buffer
    int srow = wid * 16 + (lane >> 2);
    int scol = (lane & 3) * 8;
    size_t arow;
    if (moe) {
        int l0 = mt * 128 + srow; if (l0 >= ce) l0 = ce - 1;
        arow = (size_t)tlist[base + l0];
    } else {
        arow = (size_t)(mt * 128 + srow);
    }
    const short* Ag = A + arow * (size_t)K + scol;
    const short* B1g;
    const short* B2g;
    if (moe) {
        B1g = eB1 + ((size_t)z * TFE + (size_t)(nt * 128 + srow)) * K + scol;
        B2g = eB2 + ((size_t)z * TFE + (size_t)(nt * 128 + srow)) * K + scol;
    } else {
        B1g = sB1 + (size_t)(nt * 128 + srow) * K + scol;
        B2g = sB2 + (size_t)(nt * 128 + srow) * K + scol;
    }
    int loff = __builtin_amdgcn_readfirstlane(wid * 1024);
    char* Al = (char*)As + loff;
    char* B1l = (char*)B1s + loff;
    char* B2l = (char*)B2s + loff;
    f32x4 a1[4][2] = {}, a2[4][2] = {};
    for (int kk = 0; kk < K; kk += 32) {
        __syncthreads();
        gl_lds16(Ag + kk, Al);
        gl_lds16(B1g + kk, B1l);
        gl_lds16(B2g + kk, B2l);
        __syncthreads();
        s16x8 af[4], b1[2], b2[2];
        #pragma unroll
        for (int m_ = 0; m_ < 4; m_++) af[m_] = *(const s16x8*)(As + (wr * 64 + m_ * 16 + c) * 32 + g * 8);
        #pragma unroll
        for (int n = 0; n < 2; n++) {
            b1[n] = *(const s16x8*)(B1s + (wc * 32 + n * 16 + c) * 32 + g * 8);
            b2[n] = *(const s16x8*)(B2s + (wc * 32 + n * 16 + c) * 32 + g * 8);
        }
        #pragma unroll
        for (int m_ = 0; m_ < 4; m_++)
            #pragma unroll
            for (int n = 0; n < 2; n++) {
                a1[m_][n] = __builtin_amdgcn_mfma_f32_16x16x32_bf16(af[m_], b1[n], a1[m_][n], 0, 0, 0);
                a2[m_][n] = __builtin_amdgcn_mfma_f32_16x16x32_bf16(af[m_], b2[n], a2[m_][n], 0, 0, 0);
            }
    }
    #pragma unroll
    for (int m_ = 0; m_ < 4; m_++)
        #pragma unroll
        for (int n = 0; n < 2; n++)
            #pragma unroll
            for (int j = 0; j < 4; j++) {
                int lrow = mt * 128 + wr * 64 + m_ * 16 + g * 4 + j;
                if (moe && lrow >= ce) continue;
                int col = nt * 128 + wc * 32 + n * 16 + c;
                float g1 = a1[m_][n][j], g2 = a2[m_][n][j];
                float v = g1 / (1.0f + __expf(-g1)) * g2;
                if (moe) {
                    v *= slotw[base + lrow];
                    he[(size_t)(base + lrow) * TFE + col] = f2bf(v);
                } else {
                    shm[(size_t)lrow * TFS + col] = f2bf(v);
                }
            }
}

// ---------------------------------------------------------------------------
// MoE down-proj per expert: ye[slot] = he[slot] @ wp_e.  128x128 m97-clone.
// grid (8, 32, 8), block 256
// ---------------------------------------------------------------------------
__global__ __launch_bounds__(256) void k_moe2(const short* __restrict__ he,
                                              const short* __restrict__ Wpt,
                                              short* __restrict__ ye,
                                              const int* __restrict__ cnt,
                                              const int* __restrict__ basep) {
    int e = blockIdx.z;
    int ce = cnt[e];
    int mt = blockIdx.y;
    if (mt * 128 >= ce) return;
    int base = basep[e];
    int nt = blockIdx.x;
    __shared__ short As[128 * 32];
    __shared__ short Bs[128 * 32];
    int tid = threadIdx.x, wid = tid >> 6, lane = tid & 63;
    int wr = wid >> 1, wc = wid & 1, g = lane >> 4, c = lane & 15;
    int srow = wid * 32 + (lane >> 2);
    int scol = (lane & 3) * 8;
    const short* Ag0 = he + (size_t)(base + mt * 128 + srow) * TFE + scol;
    const short* Ag1 = Ag0 + (size_t)16 * TFE;
    const short* Bg0 = Wpt + ((size_t)e * 1024 + nt * 128 + srow) * TFE + scol;
    const short* Bg1 = Bg0 + (size_t)16 * TFE;
    int loff = __builtin_amdgcn_readfirstlane(wid * 2048);
    char* Al = (char*)As + loff;
    char* Bl = (char*)Bs + loff;
    f32x4 acc[4][4] = {};
    for (int kk = 0; kk < TFE; kk += 32) {
        __syncthreads();
        gl_lds16(Ag0 + kk, Al);
        gl_lds16(Ag1 + kk, Al + 1024);
        gl_lds16(Bg0 + kk, Bl);
        gl_lds16(Bg1 + kk, Bl + 1024);
        __syncthreads();
        s16x8 af[4], bf[4];
        #pragma unroll
        for (int m = 0; m < 4; m++) af[m] = *(const s16x8*)(As + (wr * 64 + m * 16 + c) * 32 + g * 8);
        #pragma unroll
        for (int n = 0; n < 4; n++) bf[n] = *(const s16x8*)(Bs + (wc * 64 + n * 16 + c) * 32 + g * 8);
        #pragma unroll
        for (int m = 0; m < 4; m++)
            #pragma unroll
            for (int n = 0; n < 4; n++)
                acc[m][n] = __builtin_amdgcn_mfma_f32_16x16x32_bf16(af[m], bf[n], acc[m][n], 0, 0, 0);
    }
    #pragma unroll
    for (int m = 0; m < 4; m++)
        #pragma unroll
        for (int n = 0; n < 4; n++)
            #pragma unroll
            for (int j = 0; j < 4; j++) {
                int lrow = mt * 128 + wr * 64 + m * 16 + g * 4 + j;
                if (lrow >= ce) continue;
                int col = nt * 128 + wc * 64 + n * 16 + c;
                ye[(size_t)(base + lrow) * TC + col] = f2bf(acc[m][n][j]);
            }
}

// ---------------------------------------------------------------------------
// Final: out = shm @ swp_t + x1 + ye[s0] + ye[s1].  M=4096 N=1024 K=2048
// BM=128 BN=64.  grid (16, 32)
// ---------------------------------------------------------------------------
__global__ __launch_bounds__(256) void k_final(const short* __restrict__ A,
                                               const short* __restrict__ Bt,
                                               const float* __restrict__ x1,
                                               const short* __restrict__ ye,
                                               const int* __restrict__ sot,
                                               float* __restrict__ outp) {
    __shared__ short As[128 * 32];
    __shared__ short Bs[64 * 32];
    const int K = TFS;
    int tid = threadIdx.x;
    int brow = blockIdx.y * 128, bcol = blockIdx.x * 64;
    int wid = tid >> 6, lane = tid & 63;
    int wr = wid >> 1, wc = wid & 1, g = lane >> 4, c = lane & 15;
    int srow = wid * 32 + (lane >> 2);
    int scol = (lane & 3) * 8;
    const short* Ag0 = A + (size_t)(brow + srow) * K + scol;
    const short* Ag1 = A + (size_t)(brow + srow + 16) * K + scol;
    int sbrow = wid * 16 + (lane >> 2);
    const short* Bg = Bt + (size_t)(bcol + sbrow) * K + scol;
    int loffA = __builtin_amdgcn_readfirstlane(wid * 2048);
    int loffB = __builtin_amdgcn_readfirstlane(wid * 1024);
    char* Al = (char*)As + loffA;
    char* Bl = (char*)Bs + loffB;
    f32x4 acc[4][2] = {};
    for (int kk = 0; kk < K; kk += 32) {
        __syncthreads();
        gl_lds16(Ag0 + kk, Al);
        gl_lds16(Ag1 + kk, Al + 1024);
        gl_lds16(Bg + kk, Bl);
        __syncthreads();
        s16x8 af[4], bf[2];
        #pragma unroll
        for (int m = 0; m < 4; m++) af[m] = *(const s16x8*)(As + (wr * 64 + m * 16 + c) * 32 + g * 8);
        #pragma unroll
        for (int n = 0; n < 2; n++) bf[n] = *(const s16x8*)(Bs + (wc * 32 + n * 16 + c) * 32 + g * 8);
        #pragma unroll
        for (int m = 0; m < 4; m++)
            #pragma unroll
            for (int n = 0; n < 2; n++)
                acc[m][n] = __builtin_amdgcn_mfma_f32_16x16x32_bf16(af[m], bf[n], acc[m][n], 0, 0, 0);
    }
    #pragma unroll
    for (int m = 0; m < 4; m++)
        #pragma unroll
        for (int n = 0; n < 2; n++)
            #pragma unroll
            for (int j = 0; j < 4; j++) {
                int row = brow + wr * 64 + m * 16 + g * 4 + j;
                int col = bcol + wc * 32 + n * 16 + c;
                int s0 = sot[row * 2], s1 = sot[row * 2 + 1];
                float v = acc[m][n][j] + x1[(size_t)row * TC + col]
                        + bf2f(ye[(size_t)s0 * TC + col]) + bf2f(ye[(size_t)s1 * TC + col]);
                outp[(size_t)row * TC + col] = v;
            }
}

// ---------------------------------------------------------------------------
// Launch
// ---------------------------------------------------------------------------
extern "C" void kernel_launch(void* const* d_in, const int* in_sizes, int n_in,
                              void* d_out, int out_size, void* d_ws, size_t ws_size,
                              hipStream_t stream) {
    const float* x     = (const float*)d_in[0];
    const float* n1w   = (const float*)d_in[1];
    const float* n2w   = (const float*)d_in[2];
    const float* wq    = (const float*)d_in[3];
    const float* wk    = (const float*)d_in[4];
    const float* wv    = (const float*)d_in[5];
    const float* wo    = (const float*)d_in[6];
    const float* gatew = (const float*)d_in[7];
    const float* ew1   = (const float*)d_in[8];
    const float* ew2   = (const float*)d_in[9];
    const float* ewp   = (const float*)d_in[10];
    const float* sw1   = (const float*)d_in[11];
    const float* sw2   = (const float*)d_in[12];
    const float* swp   = (const float*)d_in[13];
    float* outp = (float*)d_out;

    char* p = (char*)d_ws;
    auto alloc = [&](size_t bytes) -> char* {
        char* r = p;
        p += (bytes + 255) & ~(size_t)255;
        return r;
    };
    short* wqkv_t = (short*)alloc(1536 * 1024 * 2);
    short* wo_t   = (short*)alloc(1024 * 1024 * 2);
    short* ew1_t  = (short*)alloc((size_t)8 * 1024 * 1024 * 2);
    short* ew2_t  = (short*)alloc((size_t)8 * 1024 * 1024 * 2);
    short* ewp_t  = (short*)alloc((size_t)8 * 1024 * 1024 * 2);
    short* sw1_t  = (short*)alloc((size_t)2048 * 1024 * 2);
    short* sw2_t  = (short*)alloc((size_t)2048 * 1024 * 2);
    short* swp_t  = (short*)alloc((size_t)1024 * 2048 * 2);
    short* h1     = (short*)alloc((size_t)NTOK * 1024 * 2);
    short* qkv    = (short*)alloc((size_t)NTOK * 1536 * 2);
    short* q_r    = (short*)alloc((size_t)TB * TH * TT * THD * 2);
    short* k_r    = (short*)alloc((size_t)TB * TKV * TT * THD * 2);
    short* v_t    = (short*)alloc((size_t)TB * TKV * THD * TT * 2);
    short* attn_o = (short*)alloc((size_t)NTOK * 1024 * 2);
    float* x1     = (float*)alloc((size_t)NTOK * 1024 * 4);
    short* h2     = (short*)alloc((size_t)NTOK * 1024 * 2);
    float* rope   = (float*)alloc((size_t)TT * 32 * 2 * 4);
    int*   cnt    = (int*)alloc(256);
    int*   basep  = (int*)alloc(256);
    int*   te     = (int*)alloc((size_t)NTOK * 2 * 4);
    int*   tls    = (int*)alloc((size_t)NTOK * 2 * 4);
    float* tw     = (float*)alloc((size_t)NTOK * 2 * 4);
    int*   tlist  = (int*)alloc((size_t)NSLOT * 4);
    float* slotw  = (float*)alloc((size_t)NSLOT * 4);
    int*   sot    = (int*)alloc((size_t)NTOK * 2 * 4);
    short* he     = (short*)alloc((size_t)NSLOT * TFE * 2);
    short* ye     = (short*)alloc((size_t)NSLOT * TC * 2);
    short* shm    = (short*)alloc((size_t)NTOK * TFS * 2);

    dim3 blk(256);

    k_transp<<<dim3(32, 32, 1), blk, 0, stream>>>(wq, wqkv_t, 1024, 1024, 0, 0);
    k_transp<<<dim3(8, 32, 1), blk, 0, stream>>>(wk, wqkv_t + 1024 * 1024, 1024, 256, 0, 0);
    k_transp<<<dim3(8, 32, 1), blk, 0, stream>>>(wv, wqkv_t + 1280 * 1024, 1024, 256, 0, 0);
    k_transp<<<dim3(32, 32, 1), blk, 0, stream>>>(wo, wo_t, 1024, 1024, 0, 0);
    k_transp<<<dim3(32, 32, 8), blk, 0, stream>>>(ew1, ew1_t, 1024, 1024, 1048576, 1048576);
    k_transp<<<dim3(32, 32, 8), blk, 0, stream>>>(ew2, ew2_t, 1024, 1024, 1048576, 1048576);
    k_transp<<<dim3(32, 32, 8), blk, 0, stream>>>(ewp, ewp_t, 1024, 1024, 1048576, 1048576);
    k_transp<<<dim3(64, 32, 1), blk, 0, stream>>>(sw1, sw1_t, 1024, 2048, 0, 0);
    k_transp<<<dim3(64, 32, 1), blk, 0, stream>>>(sw2, sw2_t, 1024, 2048, 0, 0);
    k_transp<<<dim3(32, 64, 1), blk, 0, stream>>>(swp, swp_t, 2048, 1024, 0, 0);

    k_rope_table<<<(TT * 32 + 255) / 256, blk, 0, stream>>>(rope);

    k_rmsnorm<<<NTOK, blk, 0, stream>>>(x, n1w, h1);
    k_gemm128<0><<<dim3(12, 32), blk, 0, stream>>>(h1, wqkv_t, qkv, nullptr, NTOK, 1536, 1024);
    k_rope_apply<<<(NTOK * 640 + 255) / 256, blk, 0, stream>>>(qkv, rope, q_r, k_r);
    k_transp_v<<<dim3(2, 64, 8), blk, 0, stream>>>(qkv, v_t);

    k_attn<<<dim3(16, TB * TH), blk, 0, stream>>>(q_r, k_r, v_t, attn_o);

    k_gemm64<1><<<dim3(16, 32), blk, 0, stream>>>(attn_o, wo_t, x1, x, NTOK, 1024, 1024);

    k_rmsnorm<<<NTOK, blk, 0, stream>>>(x1, n2w, h2);

    hipMemsetAsync(cnt, 0, 64, stream);
    k_gate<<<NTOK / 4, blk, 0, stream>>>(x1, n2w, gatew, outp + (size_t)NTOK * TC, cnt, te, tls, tw);
    k_prefix<<<1, 64, 0, stream>>>(cnt, basep);
    k_scatter<<<NTOK / 256, blk, 0, stream>>>(te, tls, tw, basep, tlist, slotw, sot);

    k_ffn<<<dim3(16, 32, 9), dim3(512), 0, stream>>>(h2, ew1_t, ew2_t, sw1_t, sw2_t, he, shm,
                                                     cnt, basep, tlist, slotw);
    k_moe2<<<dim3(8, 32, 8), blk, 0, stream>>>(he, ewp_t, ye, cnt, basep);

    k_final<<<dim3(16, 32), blk, 0, stream>>>(shm, swp_t, x1, ye, sot, outp);

    (void)in_sizes; (void)n_in; (void)out_size; (void)ws_size;
}

// Round 5
// 724.403 us; speedup vs baseline: 1.2973x; 1.0309x over previous
//
#include <hip/hip_runtime.h>
#include <hip/hip_bf16.h>

// ---------------------------------------------------------------------------
// Problem constants
// ---------------------------------------------------------------------------
#define TB 2
#define TT 2048
#define TC 1024
#define TH 16
#define TKV 4
#define THD 64
#define TE 8
#define TFE 1024
#define TFS 2048
#define NTOK 4096           // B*T
#define NSLOT 8192          // NTOK * K(=2)

typedef __attribute__((ext_vector_type(4))) float f32x4;
typedef __attribute__((ext_vector_type(16))) float f32x16;
typedef __attribute__((ext_vector_type(8))) short s16x8;

__device__ __forceinline__ float bf2f(short s) {
    unsigned int u = ((unsigned int)(unsigned short)s) << 16;
    return __builtin_bit_cast(float, u);
}
__device__ __forceinline__ short f2bf(float f) {
    unsigned int u = __builtin_bit_cast(unsigned int, f);
    u = u + 0x7fffu + ((u >> 16) & 1u);     // RNE
    return (short)(u >> 16);
}
__device__ __forceinline__ unsigned int cvtpk_bf16(float lo, float hi) {
    unsigned int r;
    asm volatile("v_cvt_pk_bf16_f32 %0, %1, %2" : "=v"(r) : "v"(lo), "v"(hi));
    return r;
}

// async global->LDS, 16B per lane. lds ptr must be wave-uniform base;
// HW writes lane l's 16B to base + l*16. Global source is per-lane.
__device__ __forceinline__ void gl_lds16(const void* g, void* l) {
    __builtin_amdgcn_global_load_lds((const __attribute__((address_space(1))) void*)g,
                                     (__attribute__((address_space(3))) void*)l,
                                     16, 0, 0);
}

// ---------------------------------------------------------------------------
// Transpose + f32->bf16 convert:  in f32 [R][Cd] -> out bf16 [Cd][R], batched
// ---------------------------------------------------------------------------
__global__ __launch_bounds__(256) void k_transp(const float* __restrict__ in,
                                                short* __restrict__ out,
                                                int R, int Cd,
                                                size_t bs_in, size_t bs_out) {
    __shared__ float tile[32][33];
    const float* ip = in + bs_in * blockIdx.z;
    short* op = out + bs_out * blockIdx.z;
    int tx = threadIdx.x & 31, ty = threadIdx.x >> 5;
    int r0 = blockIdx.y * 32, c0 = blockIdx.x * 32;
    #pragma unroll
    for (int r = ty; r < 32; r += 8)
        tile[r][tx] = ip[(size_t)(r0 + r) * Cd + c0 + tx];
    __syncthreads();
    #pragma unroll
    for (int r = ty; r < 32; r += 8)
        op[(size_t)(c0 + r) * R + r0 + tx] = f2bf(tile[tx][r]);
}

// ---------------------------------------------------------------------------
// V transpose (bf16 -> bf16): qkv v-columns [T][64] per (b,kv) -> v_t [64][T]
// ---------------------------------------------------------------------------
__global__ __launch_bounds__(256) void k_transp_v(const short* __restrict__ qkv,
                                                  short* __restrict__ v_t) {
    __shared__ short tile[32][33];
    int z = blockIdx.z;
    int b = z >> 2, kvh = z & 3;
    const short* ip = qkv + (size_t)b * TT * 1536 + 1280 + kvh * 64;
    short* op = v_t + (size_t)z * THD * TT;
    int tx = threadIdx.x & 31, ty = threadIdx.x >> 5;
    int t0 = blockIdx.y * 32, d0 = blockIdx.x * 32;
    #pragma unroll
    for (int r = ty; r < 32; r += 8)
        tile[r][tx] = ip[(size_t)(t0 + r) * 1536 + d0 + tx];
    __syncthreads();
    #pragma unroll
    for (int r = ty; r < 32; r += 8)
        op[(size_t)(d0 + r) * TT + t0 + tx] = tile[tx][r];
}

// ---------------------------------------------------------------------------
// RoPE table: [T][32][2] f32  (cos, sin)
// ---------------------------------------------------------------------------
__global__ void k_rope_table(float* __restrict__ rope) {
    int idx = blockIdx.x * 256 + threadIdx.x;
    if (idx >= TT * 32) return;
    int t = idx >> 5, i = idx & 31;
    float freq = expf(-(float)i * (1.0f / 32.0f) * 9.210340371976184f); // 10000^(-i/32)
    float ang = (float)t * freq;
    rope[idx * 2 + 0] = cosf(ang);
    rope[idx * 2 + 1] = sinf(ang);
}

// ---------------------------------------------------------------------------
// RMSNorm: f32 [4096][1024] -> bf16 [4096][1024].  block 256 = one row
// ---------------------------------------------------------------------------
__global__ __launch_bounds__(256) void k_rmsnorm(const float* __restrict__ x,
                                                 const float* __restrict__ w,
                                                 short* __restrict__ out) {
    int row = blockIdx.x, t = threadIdx.x;
    float4 v = ((const float4*)(x + (size_t)row * TC))[t];
    float ss = v.x * v.x + v.y * v.y + v.z * v.z + v.w * v.w;
    #pragma unroll
    for (int off = 32; off; off >>= 1) ss += __shfl_xor(ss, off);
    __shared__ float red[4];
    if ((t & 63) == 0) red[t >> 6] = ss;
    __syncthreads();
    float rs = rsqrtf((red[0] + red[1] + red[2] + red[3]) * (1.0f / 1024.0f) + 1e-6f);
    float4 wv = ((const float4*)w)[t];
    short4 o;
    o.x = f2bf(v.x * rs * wv.x);
    o.y = f2bf(v.y * rs * wv.y);
    o.z = f2bf(v.z * rs * wv.z);
    o.w = f2bf(v.w * rs * wv.w);
    ((short4*)(out + (size_t)row * TC))[t] = o;
}

// ---------------------------------------------------------------------------
// 128x128 GEMM, double-buffered prefetch (T3 minimum 2-phase):
// stage(next) -> compute(cur) -> ONE barrier.  C = A[M,K] * Bt[N,K], bf16.
// EPI 0: out bf16 = acc;   EPI 1: out f32 = acc + resid
// grid (N/128, M/128), block 256
// ---------------------------------------------------------------------------
template <int EPI>
__global__ __launch_bounds__(256) void k_gemm128(const short* __restrict__ A,
                                                 const short* __restrict__ Bt,
                                                 void* __restrict__ outp,
                                                 const float* __restrict__ resid,
                                                 int M, int N, int K) {
    __shared__ short As0[128 * 32], As1[128 * 32];
    __shared__ short Bs0[128 * 32], Bs1[128 * 32];
    int tid = threadIdx.x;
    int brow = blockIdx.y * 128, bcol = blockIdx.x * 128;
    int wid = tid >> 6, lane = tid & 63;
    int wr = wid >> 1, wc = wid & 1, g = lane >> 4, c = lane & 15;
    int srow = wid * 32 + (lane >> 2);
    int scol = (lane & 3) * 8;
    const short* Ag0 = A + (size_t)(brow + srow) * K + scol;
    const short* Ag1 = A + (size_t)(brow + srow + 16) * K + scol;
    const short* Bg0 = Bt + (size_t)(bcol + srow) * K + scol;
    const short* Bg1 = Bt + (size_t)(bcol + srow + 16) * K + scol;
    int loff = __builtin_amdgcn_readfirstlane(wid * 2048);
    f32x4 acc[4][4] = {};

    // prologue: stage tile 0 into buf0
    gl_lds16(Ag0, (char*)As0 + loff);
    gl_lds16(Ag1, (char*)As0 + loff + 1024);
    gl_lds16(Bg0, (char*)Bs0 + loff);
    gl_lds16(Bg1, (char*)Bs0 + loff + 1024);
    __syncthreads();

    short* Ac = As0; short* Bc = Bs0;
    short* Aa = As1; short* Ba = Bs1;
    for (int kk = 0; kk < K; kk += 32) {
        int kn = kk + 32;
        if (kn < K) {
            gl_lds16(Ag0 + kn, (char*)Aa + loff);
            gl_lds16(Ag1 + kn, (char*)Aa + loff + 1024);
            gl_lds16(Bg0 + kn, (char*)Ba + loff);
            gl_lds16(Bg1 + kn, (char*)Ba + loff + 1024);
        }
        s16x8 af[4], bf[4];
        #pragma unroll
        for (int m = 0; m < 4; m++) af[m] = *(const s16x8*)(Ac + (wr * 64 + m * 16 + c) * 32 + g * 8);
        #pragma unroll
        for (int n = 0; n < 4; n++) bf[n] = *(const s16x8*)(Bc + (wc * 64 + n * 16 + c) * 32 + g * 8);
        #pragma unroll
        for (int m = 0; m < 4; m++)
            #pragma unroll
            for (int n = 0; n < 4; n++)
                acc[m][n] = __builtin_amdgcn_mfma_f32_16x16x32_bf16(af[m], bf[n], acc[m][n], 0, 0, 0);
        __syncthreads();
        short* t;
        t = Ac; Ac = Aa; Aa = t;
        t = Bc; Bc = Ba; Ba = t;
    }
    #pragma unroll
    for (int m = 0; m < 4; m++)
        #pragma unroll
        for (int n = 0; n < 4; n++)
            #pragma unroll
            for (int j = 0; j < 4; j++) {
                int row = brow + wr * 64 + m * 16 + g * 4 + j;
                int col = bcol + wc * 64 + n * 16 + c;
                float v = acc[m][n][j];
                if (EPI == 0)
                    ((short*)outp)[(size_t)row * N + col] = f2bf(v);
                else
                    ((float*)outp)[(size_t)row * N + col] = v + resid[(size_t)row * N + col];
            }
}

// ---------------------------------------------------------------------------
// 128x64 GEMM, double-buffered prefetch.
// grid (N/64, M/128), block 256
// ---------------------------------------------------------------------------
template <int EPI>
__global__ __launch_bounds__(256) void k_gemm64(const short* __restrict__ A,
                                                const short* __restrict__ Bt,
                                                void* __restrict__ outp,
                                                const float* __restrict__ resid,
                                                int M, int N, int K) {
    __shared__ short As0[128 * 32], As1[128 * 32];
    __shared__ short Bs0[64 * 32], Bs1[64 * 32];
    int tid = threadIdx.x;
    int brow = blockIdx.y * 128, bcol = blockIdx.x * 64;
    int wid = tid >> 6, lane = tid & 63;
    int wr = wid >> 1, wc = wid & 1, g = lane >> 4, c = lane & 15;
    int srow = wid * 32 + (lane >> 2);
    int scol = (lane & 3) * 8;
    const short* Ag0 = A + (size_t)(brow + srow) * K + scol;
    const short* Ag1 = A + (size_t)(brow + srow + 16) * K + scol;
    int sbrow = wid * 16 + (lane >> 2);
    const short* Bg = Bt + (size_t)(bcol + sbrow) * K + scol;
    int loffA = __builtin_amdgcn_readfirstlane(wid * 2048);
    int loffB = __builtin_amdgcn_readfirstlane(wid * 1024);
    f32x4 acc[4][2] = {};

    gl_lds16(Ag0, (char*)As0 + loffA);
    gl_lds16(Ag1, (char*)As0 + loffA + 1024);
    gl_lds16(Bg, (char*)Bs0 + loffB);
    __syncthreads();

    short* Ac = As0; short* Bc = Bs0;
    short* Aa = As1; short* Ba = Bs1;
    for (int kk = 0; kk < K; kk += 32) {
        int kn = kk + 32;
        if (kn < K) {
            gl_lds16(Ag0 + kn, (char*)Aa + loffA);
            gl_lds16(Ag1 + kn, (char*)Aa + loffA + 1024);
            gl_lds16(Bg + kn, (char*)Ba + loffB);
        }
        s16x8 af[4], bf[2];
        #pragma unroll
        for (int m = 0; m < 4; m++) af[m] = *(const s16x8*)(Ac + (wr * 64 + m * 16 + c) * 32 + g * 8);
        #pragma unroll
        for (int n = 0; n < 2; n++) bf[n] = *(const s16x8*)(Bc + (wc * 32 + n * 16 + c) * 32 + g * 8);
        #pragma unroll
        for (int m = 0; m < 4; m++)
            #pragma unroll
            for (int n = 0; n < 2; n++)
                acc[m][n] = __builtin_amdgcn_mfma_f32_16x16x32_bf16(af[m], bf[n], acc[m][n], 0, 0, 0);
        __syncthreads();
        short* t;
        t = Ac; Ac = Aa; Aa = t;
        t = Bc; Bc = Ba; Ba = t;
    }
    #pragma unroll
    for (int m = 0; m < 4; m++)
        #pragma unroll
        for (int n = 0; n < 2; n++)
            #pragma unroll
            for (int j = 0; j < 4; j++) {
                int row = brow + wr * 64 + m * 16 + g * 4 + j;
                int col = bcol + wc * 32 + n * 16 + c;
                float v = acc[m][n][j];
                if (EPI == 0)
                    ((short*)outp)[(size_t)row * N + col] = f2bf(v);
                else
                    ((float*)outp)[(size_t)row * N + col] = v + resid[(size_t)row * N + col];
            }
}

// ---------------------------------------------------------------------------
// RoPE apply + scatter (q, k only; v handled by k_transp_v).
// ---------------------------------------------------------------------------
__global__ void k_rope_apply(const short* __restrict__ qkv,
                             const float* __restrict__ rope,
                             short* __restrict__ q_r,
                             short* __restrict__ k_r) {
    int idx = blockIdx.x * 256 + threadIdx.x;
    if (idx >= NTOK * 640) return;
    int row = idx / 640;
    int p = idx - row * 640;
    int b = row >> 11, t = row & 2047;
    const short* src = qkv + (size_t)row * 1536;
    if (p < 512) {            // q
        int h = p >> 5, i = p & 31;
        float x0 = bf2f(src[h * 64 + 2 * i]);
        float x1 = bf2f(src[h * 64 + 2 * i + 1]);
        float cs = rope[(t * 32 + i) * 2], sn = rope[(t * 32 + i) * 2 + 1];
        size_t o = ((size_t)(b * TH + h) * TT + t) * THD + 2 * i;
        q_r[o]     = f2bf(x0 * cs - x1 * sn);
        q_r[o + 1] = f2bf(x1 * cs + x0 * sn);
    } else {                  // k
        int pk = p - 512;
        int kv = pk >> 5, i = pk & 31;
        float x0 = bf2f(src[1024 + kv * 64 + 2 * i]);
        float x1 = bf2f(src[1024 + kv * 64 + 2 * i + 1]);
        float cs = rope[(t * 32 + i) * 2], sn = rope[(t * 32 + i) * 2 + 1];
        size_t o = ((size_t)(b * TKV + kv) * TT + t) * THD + 2 * i;
        k_r[o]     = f2bf(x0 * cs - x1 * sn);
        k_r[o + 1] = f2bf(x1 * cs + x0 * sn);
    }
}

// ---------------------------------------------------------------------------
// Flash attention, swapped-operand 32x32 structure (m214-style).
// grid (16, B*H), block 256 = 4 independent waves; wave handles 32 q-rows.
// ---------------------------------------------------------------------------
__global__ __launch_bounds__(256) void k_attn(const short* __restrict__ q_r,
                                              const short* __restrict__ k_r,
                                              const short* __restrict__ v_t,
                                              short* __restrict__ attn_o) {
    int w = threadIdx.x >> 6, lane = threadIdx.x & 63;
    int qt = 63 - (blockIdx.x * 4 + w);     // long waves first
    int qbase = qt * 32;
    int bh = blockIdx.y;
    int b = bh >> 4, h = bh & 15, kv = h >> 2;
    int q32 = lane & 31, hi = lane >> 5;

    const short* qp = q_r + ((size_t)(b * TH + h) * TT + qbase) * THD;
    const short* kp = k_r + ((size_t)(b * TKV + kv) * TT) * THD;
    const short* vp = v_t + ((size_t)(b * TKV + kv) * THD) * TT;

    s16x8 qf[4];
    #pragma unroll
    for (int dc = 0; dc < 4; dc++)
        qf[dc] = *(const s16x8*)(qp + q32 * THD + dc * 16 + hi * 8);

    f32x16 ot0 = {}, ot1 = {};
    float mrun = -1e30f, lrun = 0.f;
    int nkt = (qbase + 95) >> 6;

    for (int kt = 0; kt < nkt; kt++) {
        int ktb = kt * 64;
        f32x16 st0 = {}, st1 = {};
        s16x8 kf0[4], kf1[4];
        #pragma unroll
        for (int dc = 0; dc < 4; dc++) {
            kf0[dc] = *(const s16x8*)(kp + (size_t)(ktb + q32) * THD + dc * 16 + hi * 8);
            kf1[dc] = *(const s16x8*)(kp + (size_t)(ktb + 32 + q32) * THD + dc * 16 + hi * 8);
        }
        s16x8 vf[8];
        #pragma unroll
        for (int dt = 0; dt < 2; dt++)
            #pragma unroll
            for (int kc = 0; kc < 4; kc++)
                vf[dt * 4 + kc] = *(const s16x8*)(vp + (size_t)(dt * 32 + q32) * TT + ktb + kc * 16 + hi * 8);

        __builtin_amdgcn_s_setprio(1);
        #pragma unroll
        for (int dc = 0; dc < 4; dc++) {
            st0 = __builtin_amdgcn_mfma_f32_32x32x16_bf16(kf0[dc], qf[dc], st0, 0, 0, 0);
            st1 = __builtin_amdgcn_mfma_f32_32x32x16_bf16(kf1[dc], qf[dc], st1, 0, 0, 0);
        }
        __builtin_amdgcn_s_setprio(0);

        bool domask = (kt == nkt - 1);
        int qabs = qbase + q32;
        #pragma unroll
        for (int r = 0; r < 16; r++) {
            int kploc = (r & 3) + 8 * (r >> 2) + 4 * hi;
            float s0 = st0[r] * 0.125f;
            float s1 = st1[r] * 0.125f;
            if (domask) {
                if (ktb + kploc > qabs) s0 = -1e30f;
                if (ktb + 32 + kploc > qabs) s1 = -1e30f;
            }
            st0[r] = s0; st1[r] = s1;
        }
        float pm = st0[0];
        #pragma unroll
        for (int r = 1; r < 16; r++) pm = fmaxf(pm, st0[r]);
        #pragma unroll
        for (int r = 0; r < 16; r++) pm = fmaxf(pm, st1[r]);
        pm = fmaxf(pm, __shfl_xor(pm, 32));
        float mnew = fmaxf(mrun, pm);
        float al = __expf(mrun - mnew);
        mrun = mnew;
        float rs = 0.f;
        #pragma unroll
        for (int r = 0; r < 16; r++) {
            float e0 = __expf(st0[r] - mnew); st0[r] = e0; rs += e0;
            float e1 = __expf(st1[r] - mnew); st1[r] = e1; rs += e1;
        }
        rs += __shfl_xor(rs, 32);
        lrun = lrun * al + rs;
        #pragma unroll
        for (int r = 0; r < 16; r++) { ot0[r] *= al; ot1[r] *= al; }

        unsigned int w0[8], w1[8];
        #pragma unroll
        for (int j = 0; j < 8; j++) {
            w0[j] = cvtpk_bf16(st0[2 * j], st0[2 * j + 1]);
            w1[j] = cvtpk_bf16(st1[2 * j], st1[2 * j + 1]);
        }
        s16x8 pf[4];
        #pragma unroll
        for (int kc = 0; kc < 4; kc++) {
            unsigned int* ww = (kc < 2) ? w0 : w1;
            int kcl = kc & 1;
            unsigned int x0 = ww[4 * kcl + 0], y0 = ww[4 * kcl + 2];
            unsigned int x1 = ww[4 * kcl + 1], y1 = ww[4 * kcl + 3];
            asm volatile("v_permlane32_swap_b32 %0, %1" : "+v"(x0), "+v"(y0));
            asm volatile("v_permlane32_swap_b32 %0, %1" : "+v"(x1), "+v"(y1));
            unsigned int fr[4] = {x0, x1, y0, y1};
            pf[kc] = __builtin_bit_cast(s16x8, *(ulong2*)fr);
        }
        __builtin_amdgcn_s_setprio(1);
        #pragma unroll
        for (int kc = 0; kc < 4; kc++) {
            ot0 = __builtin_amdgcn_mfma_f32_32x32x16_bf16(vf[kc], pf[kc], ot0, 0, 0, 0);
            ot1 = __builtin_amdgcn_mfma_f32_32x32x16_bf16(vf[4 + kc], pf[kc], ot1, 0, 0, 0);
        }
        __builtin_amdgcn_s_setprio(0);
    }
    float inv = 1.0f / lrun;
    short* orow = attn_o + (size_t)(b * TT + qbase + q32) * TC + h * THD;
    #pragma unroll
    for (int s = 0; s < 4; s++) {
        short4 v0, v1;
        v0.x = f2bf(ot0[4 * s + 0] * inv); v0.y = f2bf(ot0[4 * s + 1] * inv);
        v0.z = f2bf(ot0[4 * s + 2] * inv); v0.w = f2bf(ot0[4 * s + 3] * inv);
        v1.x = f2bf(ot1[4 * s + 0] * inv); v1.y = f2bf(ot1[4 * s + 1] * inv);
        v1.z = f2bf(ot1[4 * s + 2] * inv); v1.w = f2bf(ot1[4 * s + 3] * inv);
        *(short4*)(orow + 8 * s + 4 * hi) = v0;
        *(short4*)(orow + 32 + 8 * s + 4 * hi) = v1;
    }
}

// ---------------------------------------------------------------------------
// Gate: f32 logits from x1 (recompute rms in f32), softmax, top-2, counts.
// ---------------------------------------------------------------------------
__global__ __launch_bounds__(256) void k_gate(const float* __restrict__ x1,
                                              const float* __restrict__ n2w,
                                              const float* __restrict__ gate_w,
                                              float* __restrict__ gl,
                                              int* __restrict__ cnt,
                                              int* __restrict__ te,
                                              int* __restrict__ tls,
                                              float* __restrict__ tw) {
    int w = threadIdx.x >> 6, lane = threadIdx.x & 63;
    int n = blockIdx.x * 4 + w;
    const float* xp = x1 + (size_t)n * TC;
    float ss = 0.f;
    for (int i = lane; i < TC; i += 64) { float v = xp[i]; ss += v * v; }
    #pragma unroll
    for (int off = 32; off; off >>= 1) ss += __shfl_xor(ss, off);
    float rs = rsqrtf(ss * (1.0f / 1024.0f) + 1e-6f);
    int e = lane & 7, ch = lane >> 3;
    float acc = 0.f;
    for (int i = 0; i < 128; i++) {
        int cc = ch * 128 + i;
        acc += xp[cc] * rs * n2w[cc] * gate_w[(size_t)cc * TE + e];
    }
    acc += __shfl_xor(acc, 8);
    acc += __shfl_xor(acc, 16);
    acc += __shfl_xor(acc, 32);
    float logit = acc;
    if (lane < 8) gl[(size_t)n * TE + lane] = logit;
    float mx = logit;
    mx = fmaxf(mx, __shfl_xor(mx, 1)); mx = fmaxf(mx, __shfl_xor(mx, 2)); mx = fmaxf(mx, __shfl_xor(mx, 4));
    float ex = __expf(logit - mx);
    float sm = ex;
    sm += __shfl_xor(sm, 1); sm += __shfl_xor(sm, 2); sm += __shfl_xor(sm, 4);
    float pp = ex / sm;
    float m1 = pp;
    m1 = fmaxf(m1, __shfl_xor(m1, 1)); m1 = fmaxf(m1, __shfl_xor(m1, 2)); m1 = fmaxf(m1, __shfl_xor(m1, 4));
    int cand = (pp == m1) ? e : 8;
    int e0 = cand;
    e0 = min(e0, __shfl_xor(e0, 1)); e0 = min(e0, __shfl_xor(e0, 2)); e0 = min(e0, __shfl_xor(e0, 4));
    float p2 = (e == e0) ? -1.0f : pp;
    float m2 = p2;
    m2 = fmaxf(m2, __shfl_xor(m2, 1)); m2 = fmaxf(m2, __shfl_xor(m2, 2)); m2 = fmaxf(m2, __shfl_xor(m2, 4));
    int cand2 = (p2 == m2) ? e : 8;
    int e1 = cand2;
    e1 = min(e1, __shfl_xor(e1, 1)); e1 = min(e1, __shfl_xor(e1, 2)); e1 = min(e1, __shfl_xor(e1, 4));
    if (lane == 0) {
        int ls0 = atomicAdd(&cnt[e0], 1);
        int ls1 = atomicAdd(&cnt[e1], 1);
        te[n * 2] = e0; te[n * 2 + 1] = e1;
        tls[n * 2] = ls0; tls[n * 2 + 1] = ls1;
        tw[n * 2] = m1; tw[n * 2 + 1] = m2;
    }
}

__global__ void k_prefix(const int* __restrict__ cnt, int* __restrict__ basep) {
    if (threadIdx.x == 0) {
        int s = 0;
        for (int e = 0; e < TE; e++) { basep[e] = s; s += cnt[e]; }
    }
}

__global__ void k_scatter(const int* __restrict__ te, const int* __restrict__ tls,
                          const float* __restrict__ tw, const int* __restrict__ basep,
                          int* __restrict__ tlist, float* __restrict__ slotw,
                          int* __restrict__ sot) {
    int n = blockIdx.x * 256 + threadIdx.x;
    if (n >= NTOK) return;
    int s0 = basep[te[n * 2]] + tls[n * 2];
    int s1 = basep[te[n * 2 + 1]] + tls[n * 2 + 1];
    tlist[s0] = n; tlist[s1] = n;
    slotw[s0] = tw[n * 2]; slotw[s1] = tw[n * 2 + 1];
    sot[n * 2] = s0; sot[n * 2 + 1] = s1;
}

// ---------------------------------------------------------------------------
// Fused FFN-up dual GEMM, double-buffered prefetch.
// BM=128, BN=128 (2x64 dual), BK=32, 512 threads = 8 waves.
// z = 0..7: MoE experts (gathered rows, weight folded) -> he [slot][FE]
// z = 8:    shared FFN -> shm [n][FS]
// grid (16, 32, 9), block 512
// ---------------------------------------------------------------------------
__global__ __launch_bounds__(512) void k_ffn(const short* __restrict__ A,
                                             const short* __restrict__ eB1,
                                             const short* __restrict__ eB2,
                                             const short* __restrict__ sB1,
                                             const short* __restrict__ sB2,
                                             short* __restrict__ he,
                                             short* __restrict__ shm,
                                             const int* __restrict__ cnt,
                                             const int* __restrict__ basep,
                                             const int* __restrict__ tlist,
                                             const float* __restrict__ slotw) {
    int z = blockIdx.z;
    int moe = (z < 8);
    int nt = blockIdx.x, mt = blockIdx.y;
    int ce = 0, base = 0;
    if (moe) {
        if (nt >= 8) return;              // expert FE = 1024 -> 8 col tiles
        ce = cnt[z];
        if (mt * 128 >= ce) return;
        base = basep[z];
    }
    __shared__ short As0[128 * 32], As1[128 * 32];
    __shared__ short B1s0[128 * 32], B1s1[128 * 32];
    __shared__ short B2s0[128 * 32], B2s1[128 * 32];
    int tid = threadIdx.x, wid = tid >> 6, lane = tid & 63;
    int wr = wid >> 2, wc = wid & 3, g = lane >> 4, c = lane & 15;
    const int K = TC;
    int srow = wid * 16 + (lane >> 2);
    int scol = (lane & 3) * 8;
    size_t arow;
    if (moe) {
        int l0 = mt * 128 + srow; if (l0 >= ce) l0 = ce - 1;
        arow = (size_t)tlist[base + l0];
    } else {
        arow = (size_t)(mt * 128 + srow);
    }
    const short* Ag = A + arow * (size_t)K + scol;
    const short* B1g;
    const short* B2g;
    if (moe) {
        B1g = eB1 + ((size_t)z * TFE + (size_t)(nt * 128 + srow)) * K + scol;
        B2g = eB2 + ((size_t)z * TFE + (size_t)(nt * 128 + srow)) * K + scol;
    } else {
        B1g = sB1 + (size_t)(nt * 128 + srow) * K + scol;
        B2g = sB2 + (size_t)(nt * 128 + srow) * K + scol;
    }
    int loff = __builtin_amdgcn_readfirstlane(wid * 1024);
    f32x4 a1[4][2] = {}, a2[4][2] = {};

    gl_lds16(Ag, (char*)As0 + loff);
    gl_lds16(B1g, (char*)B1s0 + loff);
    gl_lds16(B2g, (char*)B2s0 + loff);
    __syncthreads();

    short* Ac = As0;  short* B1c = B1s0;  short* B2c = B2s0;
    short* Aa = As1;  short* B1a = B1s1;  short* B2a = B2s1;
    for (int kk = 0; kk < K; kk += 32) {
        int kn = kk + 32;
        if (kn < K) {
            gl_lds16(Ag + kn, (char*)Aa + loff);
            gl_lds16(B1g + kn, (char*)B1a + loff);
            gl_lds16(B2g + kn, (char*)B2a + loff);
        }
        s16x8 af[4], b1[2], b2[2];
        #pragma unroll
        for (int m_ = 0; m_ < 4; m_++) af[m_] = *(const s16x8*)(Ac + (wr * 64 + m_ * 16 + c) * 32 + g * 8);
        #pragma unroll
        for (int n = 0; n < 2; n++) {
            b1[n] = *(const s16x8*)(B1c + (wc * 32 + n * 16 + c) * 32 + g * 8);
            b2[n] = *(const s16x8*)(B2c + (wc * 32 + n * 16 + c) * 32 + g * 8);
        }
        #pragma unroll
        for (int m_ = 0; m_ < 4; m_++)
            #pragma unroll
            for (int n = 0; n < 2; n++) {
                a1[m_][n] = __builtin_amdgcn_mfma_f32_16x16x32_bf16(af[m_], b1[n], a1[m_][n], 0, 0, 0);
                a2[m_][n] = __builtin_amdgcn_mfma_f32_16x16x32_bf16(af[m_], b2[n], a2[m_][n], 0, 0, 0);
            }
        __syncthreads();
        short* t;
        t = Ac; Ac = Aa; Aa = t;
        t = B1c; B1c = B1a; B1a = t;
        t = B2c; B2c = B2a; B2a = t;
    }
    #pragma unroll
    for (int m_ = 0; m_ < 4; m_++)
        #pragma unroll
        for (int n = 0; n < 2; n++)
            #pragma unroll
            for (int j = 0; j < 4; j++) {
                int lrow = mt * 128 + wr * 64 + m_ * 16 + g * 4 + j;
                if (moe && lrow >= ce) continue;
                int col = nt * 128 + wc * 32 + n * 16 + c;
                float g1 = a1[m_][n][j], g2 = a2[m_][n][j];
                float v = g1 / (1.0f + __expf(-g1)) * g2;
                if (moe) {
                    v *= slotw[base + lrow];
                    he[(size_t)(base + lrow) * TFE + col] = f2bf(v);
                } else {
                    shm[(size_t)lrow * TFS + col] = f2bf(v);
                }
            }
}

// ---------------------------------------------------------------------------
// MoE down-proj per expert: ye[slot] = he[slot] @ wp_e.  128x128, dbuf.
// grid (8, 32, 8), block 256
// ---------------------------------------------------------------------------
__global__ __launch_bounds__(256) void k_moe2(const short* __restrict__ he,
                                              const short* __restrict__ Wpt,
                                              short* __restrict__ ye,
                                              const int* __restrict__ cnt,
                                              const int* __restrict__ basep) {
    int e = blockIdx.z;
    int ce = cnt[e];
    int mt = blockIdx.y;
    if (mt * 128 >= ce) return;
    int base = basep[e];
    int nt = blockIdx.x;
    __shared__ short As0[128 * 32], As1[128 * 32];
    __shared__ short Bs0[128 * 32], Bs1[128 * 32];
    int tid = threadIdx.x, wid = tid >> 6, lane = tid & 63;
    int wr = wid >> 1, wc = wid & 1, g = lane >> 4, c = lane & 15;
    int srow = wid * 32 + (lane >> 2);
    int scol = (lane & 3) * 8;
    const short* Ag0 = he + (size_t)(base + mt * 128 + srow) * TFE + scol;
    const short* Ag1 = Ag0 + (size_t)16 * TFE;
    const short* Bg0 = Wpt + ((size_t)e * 1024 + nt * 128 + srow) * TFE + scol;
    const short* Bg1 = Bg0 + (size_t)16 * TFE;
    int loff = __builtin_amdgcn_readfirstlane(wid * 2048);
    f32x4 acc[4][4] = {};

    gl_lds16(Ag0, (char*)As0 + loff);
    gl_lds16(Ag1, (char*)As0 + loff + 1024);
    gl_lds16(Bg0, (char*)Bs0 + loff);
    gl_lds16(Bg1, (char*)Bs0 + loff + 1024);
    __syncthreads();

    short* Ac = As0; short* Bc = Bs0;
    short* Aa = As1; short* Ba = Bs1;
    for (int kk = 0; kk < TFE; kk += 32) {
        int kn = kk + 32;
        if (kn < TFE) {
            gl_lds16(Ag0 + kn, (char*)Aa + loff);
            gl_lds16(Ag1 + kn, (char*)Aa + loff + 1024);
            gl_lds16(Bg0 + kn, (char*)Ba + loff);
            gl_lds16(Bg1 + kn, (char*)Ba + loff + 1024);
        }
        s16x8 af[4], bf[4];
        #pragma unroll
        for (int m = 0; m < 4; m++) af[m] = *(const s16x8*)(Ac + (wr * 64 + m * 16 + c) * 32 + g * 8);
        #pragma unroll
        for (int n = 0; n < 4; n++) bf[n] = *(const s16x8*)(Bc + (wc * 64 + n * 16 + c) * 32 + g * 8);
        #pragma unroll
        for (int m = 0; m < 4; m++)
            #pragma unroll
            for (int n = 0; n < 4; n++)
                acc[m][n] = __builtin_amdgcn_mfma_f32_16x16x32_bf16(af[m], bf[n], acc[m][n], 0, 0, 0);
        __syncthreads();
        short* t;
        t = Ac; Ac = Aa; Aa = t;
        t = Bc; Bc = Ba; Ba = t;
    }
    #pragma unroll
    for (int m = 0; m < 4; m++)
        #pragma unroll
        for (int n = 0; n < 4; n++)
            #pragma unroll
            for (int j = 0; j < 4; j++) {
                int lrow = mt * 128 + wr * 64 + m * 16 + g * 4 + j;
                if (lrow >= ce) continue;
                int col = nt * 128 + wc * 64 + n * 16 + c;
                ye[(size_t)(base + lrow) * TC + col] = f2bf(acc[m][n][j]);
            }
}

// ---------------------------------------------------------------------------
// Final: out = shm @ swp_t + x1 + ye[s0] + ye[s1].  M=4096 N=1024 K=2048
// BM=128 BN=64, dbuf.  grid (16, 32)
// ---------------------------------------------------------------------------
__global__ __launch_bounds__(256) void k_final(const short* __restrict__ A,
                                               const short* __restrict__ Bt,
                                               const float* __restrict__ x1,
                                               const short* __restrict__ ye,
                                               const int* __restrict__ sot,
                                               float* __restrict__ outp) {
    __shared__ short As0[128 * 32], As1[128 * 32];
    __shared__ short Bs0[64 * 32], Bs1[64 * 32];
    const int K = TFS;
    int tid = threadIdx.x;
    int brow = blockIdx.y * 128, bcol = blockIdx.x * 64;
    int wid = tid >> 6, lane = tid & 63;
    int wr = wid >> 1, wc = wid & 1, g = lane >> 4, c = lane & 15;
    int srow = wid * 32 + (lane >> 2);
    int scol = (lane & 3) * 8;
    const short* Ag0 = A + (size_t)(brow + srow) * K + scol;
    const short* Ag1 = A + (size_t)(brow + srow + 16) * K + scol;
    int sbrow = wid * 16 + (lane >> 2);
    const short* Bg = Bt + (size_t)(bcol + sbrow) * K + scol;
    int loffA = __builtin_amdgcn_readfirstlane(wid * 2048);
    int loffB = __builtin_amdgcn_readfirstlane(wid * 1024);
    f32x4 acc[4][2] = {};

    gl_lds16(Ag0, (char*)As0 + loffA);
    gl_lds16(Ag1, (char*)As0 + loffA + 1024);
    gl_lds16(Bg, (char*)Bs0 + loffB);
    __syncthreads();

    short* Ac = As0; short* Bc = Bs0;
    short* Aa = As1; short* Ba = Bs1;
    for (int kk = 0; kk < K; kk += 32) {
        int kn = kk + 32;
        if (kn < K) {
            gl_lds16(Ag0 + kn, (char*)Aa + loffA);
            gl_lds16(Ag1 + kn, (char*)Aa + loffA + 1024);
            gl_lds16(Bg + kn, (char*)Ba + loffB);
        }
        s16x8 af[4], bf[2];
        #pragma unroll
        for (int m = 0; m < 4; m++) af[m] = *(const s16x8*)(Ac + (wr * 64 + m * 16 + c) * 32 + g * 8);
        #pragma unroll
        for (int n = 0; n < 2; n++) bf[n] = *(const s16x8*)(Bc + (wc * 32 + n * 16 + c) * 32 + g * 8);
        #pragma unroll
        for (int m = 0; m < 4; m++)
            #pragma unroll
            for (int n = 0; n < 2; n++)
                acc[m][n] = __builtin_amdgcn_mfma_f32_16x16x32_bf16(af[m], bf[n], acc[m][n], 0, 0, 0);
        __syncthreads();
        short* t;
        t = Ac; Ac = Aa; Aa = t;
        t = Bc; Bc = Ba; Ba = t;
    }
    #pragma unroll
    for (int m = 0; m < 4; m++)
        #pragma unroll
        for (int n = 0; n < 2; n++)
            #pragma unroll
            for (int j = 0; j < 4; j++) {
                int row = brow + wr * 64 + m * 16 + g * 4 + j;
                int col = bcol + wc * 32 + n * 16 + c;
                int s0 = sot[row * 2], s1 = sot[row * 2 + 1];
                float v = acc[m][n][j] + x1[(size_t)row * TC + col]
                        + bf2f(ye[(size_t)s0 * TC + col]) + bf2f(ye[(size_t)s1 * TC + col]);
                outp[(size_t)row * TC + col] = v;
            }
}

// ---------------------------------------------------------------------------
// Launch
// ---------------------------------------------------------------------------
extern "C" void kernel_launch(void* const* d_in, const int* in_sizes, int n_in,
                              void* d_out, int out_size, void* d_ws, size_t ws_size,
                              hipStream_t stream) {
    const float* x     = (const float*)d_in[0];
    const float* n1w   = (const float*)d_in[1];
    const float* n2w   = (const float*)d_in[2];
    const float* wq    = (const float*)d_in[3];
    const float* wk    = (const float*)d_in[4];
    const float* wv    = (const float*)d_in[5];
    const float* wo    = (const float*)d_in[6];
    const float* gatew = (const float*)d_in[7];
    const float* ew1   = (const float*)d_in[8];
    const float* ew2   = (const float*)d_in[9];
    const float* ewp   = (const float*)d_in[10];
    const float* sw1   = (const float*)d_in[11];
    const float* sw2   = (const float*)d_in[12];
    const float* swp   = (const float*)d_in[13];
    float* outp = (float*)d_out;

    char* p = (char*)d_ws;
    auto alloc = [&](size_t bytes) -> char* {
        char* r = p;
        p += (bytes + 255) & ~(size_t)255;
        return r;
    };
    short* wqkv_t = (short*)alloc(1536 * 1024 * 2);
    short* wo_t   = (short*)alloc(1024 * 1024 * 2);
    short* ew1_t  = (short*)alloc((size_t)8 * 1024 * 1024 * 2);
    short* ew2_t  = (short*)alloc((size_t)8 * 1024 * 1024 * 2);
    short* ewp_t  = (short*)alloc((size_t)8 * 1024 * 1024 * 2);
    short* sw1_t  = (short*)alloc((size_t)2048 * 1024 * 2);
    short* sw2_t  = (short*)alloc((size_t)2048 * 1024 * 2);
    short* swp_t  = (short*)alloc((size_t)1024 * 2048 * 2);
    short* h1     = (short*)alloc((size_t)NTOK * 1024 * 2);
    short* qkv    = (short*)alloc((size_t)NTOK * 1536 * 2);
    short* q_r    = (short*)alloc((size_t)TB * TH * TT * THD * 2);
    short* k_r    = (short*)alloc((size_t)TB * TKV * TT * THD * 2);
    short* v_t    = (short*)alloc((size_t)TB * TKV * THD * TT * 2);
    short* attn_o = (short*)alloc((size_t)NTOK * 1024 * 2);
    float* x1     = (float*)alloc((size_t)NTOK * 1024 * 4);
    short* h2     = (short*)alloc((size_t)NTOK * 1024 * 2);
    float* rope   = (float*)alloc((size_t)TT * 32 * 2 * 4);
    int*   cnt    = (int*)alloc(256);
    int*   basep  = (int*)alloc(256);
    int*   te     = (int*)alloc((size_t)NTOK * 2 * 4);
    int*   tls    = (int*)alloc((size_t)NTOK * 2 * 4);
    float* tw     = (float*)alloc((size_t)NTOK * 2 * 4);
    int*   tlist  = (int*)alloc((size_t)NSLOT * 4);
    float* slotw  = (float*)alloc((size_t)NSLOT * 4);
    int*   sot    = (int*)alloc((size_t)NTOK * 2 * 4);
    short* he     = (short*)alloc((size_t)NSLOT * TFE * 2);
    short* ye     = (short*)alloc((size_t)NSLOT * TC * 2);
    short* shm    = (short*)alloc((size_t)NTOK * TFS * 2);

    dim3 blk(256);

    k_transp<<<dim3(32, 32, 1), blk, 0, stream>>>(wq, wqkv_t, 1024, 1024, 0, 0);
    k_transp<<<dim3(8, 32, 1), blk, 0, stream>>>(wk, wqkv_t + 1024 * 1024, 1024, 256, 0, 0);
    k_transp<<<dim3(8, 32, 1), blk, 0, stream>>>(wv, wqkv_t + 1280 * 1024, 1024, 256, 0, 0);
    k_transp<<<dim3(32, 32, 1), blk, 0, stream>>>(wo, wo_t, 1024, 1024, 0, 0);
    k_transp<<<dim3(32, 32, 8), blk, 0, stream>>>(ew1, ew1_t, 1024, 1024, 1048576, 1048576);
    k_transp<<<dim3(32, 32, 8), blk, 0, stream>>>(ew2, ew2_t, 1024, 1024, 1048576, 1048576);
    k_transp<<<dim3(32, 32, 8), blk, 0, stream>>>(ewp, ewp_t, 1024, 1024, 1048576, 1048576);
    k_transp<<<dim3(64, 32, 1), blk, 0, stream>>>(sw1, sw1_t, 1024, 2048, 0, 0);
    k_transp<<<dim3(64, 32, 1), blk, 0, stream>>>(sw2, sw2_t, 1024, 2048, 0, 0);
    k_transp<<<dim3(32, 64, 1), blk, 0, stream>>>(swp, swp_t, 2048, 1024, 0, 0);

    k_rope_table<<<(TT * 32 + 255) / 256, blk, 0, stream>>>(rope);

    k_rmsnorm<<<NTOK, blk, 0, stream>>>(x, n1w, h1);
    k_gemm128<0><<<dim3(12, 32), blk, 0, stream>>>(h1, wqkv_t, qkv, nullptr, NTOK, 1536, 1024);
    k_rope_apply<<<(NTOK * 640 + 255) / 256, blk, 0, stream>>>(qkv, rope, q_r, k_r);
    k_transp_v<<<dim3(2, 64, 8), blk, 0, stream>>>(qkv, v_t);

    k_attn<<<dim3(16, TB * TH), blk, 0, stream>>>(q_r, k_r, v_t, attn_o);

    k_gemm64<1><<<dim3(16, 32), blk, 0, stream>>>(attn_o, wo_t, x1, x, NTOK, 1024, 1024);

    k_rmsnorm<<<NTOK, blk, 0, stream>>>(x1, n2w, h2);

    hipMemsetAsync(cnt, 0, 64, stream);
    k_gate<<<NTOK / 4, blk, 0, stream>>>(x1, n2w, gatew, outp + (size_t)NTOK * TC, cnt, te, tls, tw);
    k_prefix<<<1, 64, 0, stream>>>(cnt, basep);
    k_scatter<<<NTOK / 256, blk, 0, stream>>>(te, tls, tw, basep, tlist, slotw, sot);

    k_ffn<<<dim3(16, 32, 9), dim3(512), 0, stream>>>(h2, ew1_t, ew2_t, sw1_t, sw2_t, he, shm,
                                                     cnt, basep, tlist, slotw);
    k_moe2<<<dim3(8, 32, 8), blk, 0, stream>>>(he, ewp_t, ye, cnt, basep);

    k_final<<<dim3(16, 32), blk, 0, stream>>>(shm, swp_t, x1, ye, sot, outp);

    (void)in_sizes; (void)n_in; (void)out_size; (void)ws_size;
}

// Round 7
// 715.394 us; speedup vs baseline: 1.3137x; 1.0126x over previous
//
#include <hip/hip_runtime.h>
#include <hip/hip_bf16.h>

// ---------------------------------------------------------------------------
// Problem constants
// ---------------------------------------------------------------------------
#define TB 2
#define TT 2048
#define TC 1024
#define TH 16
#define TKV 4
#define THD 64
#define TE 8
#define TFE 1024
#define TFS 2048
#define NTOK 4096           // B*T
#define NSLOT 8192          // NTOK * K(=2)

typedef __attribute__((ext_vector_type(4))) float f32x4;
typedef __attribute__((ext_vector_type(16))) float f32x16;
typedef __attribute__((ext_vector_type(8))) short s16x8;

__device__ __forceinline__ float bf2f(short s) {
    unsigned int u = ((unsigned int)(unsigned short)s) << 16;
    return __builtin_bit_cast(float, u);
}
__device__ __forceinline__ short f2bf(float f) {
    unsigned int u = __builtin_bit_cast(unsigned int, f);
    u = u + 0x7fffu + ((u >> 16) & 1u);     // RNE
    return (short)(u >> 16);
}
__device__ __forceinline__ unsigned int cvtpk_bf16(float lo, float hi) {
    unsigned int r;
    asm volatile("v_cvt_pk_bf16_f32 %0, %1, %2" : "=v"(r) : "v"(lo), "v"(hi));
    return r;
}

// async global->LDS, 16B per lane. lds ptr must be wave-uniform base;
// HW writes lane l's 16B to base + l*16. Global source is per-lane.
__device__ __forceinline__ void gl_lds16(const void* g, void* l) {
    __builtin_amdgcn_global_load_lds((const __attribute__((address_space(1))) void*)g,
                                     (__attribute__((address_space(3))) void*)l,
                                     16, 0, 0);
}

#define WAIT_VM(N) asm volatile("s_waitcnt vmcnt(" #N ")" ::: "memory")
#define WAIT_LGKM0() asm volatile("s_waitcnt lgkmcnt(0)" ::: "memory")

// ---------------------------------------------------------------------------
// Transpose + f32->bf16 convert:  in f32 [R][Cd] -> out bf16 [Cd][R], batched
// ---------------------------------------------------------------------------
__global__ __launch_bounds__(256) void k_transp(const float* __restrict__ in,
                                                short* __restrict__ out,
                                                int R, int Cd,
                                                size_t bs_in, size_t bs_out) {
    __shared__ float tile[32][33];
    const float* ip = in + bs_in * blockIdx.z;
    short* op = out + bs_out * blockIdx.z;
    int tx = threadIdx.x & 31, ty = threadIdx.x >> 5;
    int r0 = blockIdx.y * 32, c0 = blockIdx.x * 32;
    #pragma unroll
    for (int r = ty; r < 32; r += 8)
        tile[r][tx] = ip[(size_t)(r0 + r) * Cd + c0 + tx];
    __syncthreads();
    #pragma unroll
    for (int r = ty; r < 32; r += 8)
        op[(size_t)(c0 + r) * R + r0 + tx] = f2bf(tile[tx][r]);
}

// ---------------------------------------------------------------------------
// V transpose (bf16 -> bf16): qkv v-columns [T][64] per (b,kv) -> v_t [64][T]
// ---------------------------------------------------------------------------
__global__ __launch_bounds__(256) void k_transp_v(const short* __restrict__ qkv,
                                                  short* __restrict__ v_t) {
    __shared__ short tile[32][33];
    int z = blockIdx.z;
    int b = z >> 2, kvh = z & 3;
    const short* ip = qkv + (size_t)b * TT * 1536 + 1280 + kvh * 64;
    short* op = v_t + (size_t)z * THD * TT;
    int tx = threadIdx.x & 31, ty = threadIdx.x >> 5;
    int t0 = blockIdx.y * 32, d0 = blockIdx.x * 32;
    #pragma unroll
    for (int r = ty; r < 32; r += 8)
        tile[r][tx] = ip[(size_t)(t0 + r) * 1536 + d0 + tx];
    __syncthreads();
    #pragma unroll
    for (int r = ty; r < 32; r += 8)
        op[(size_t)(d0 + r) * TT + t0 + tx] = tile[tx][r];
}

// ---------------------------------------------------------------------------
// RoPE table: [T][32][2] f32  (cos, sin)
// ---------------------------------------------------------------------------
__global__ void k_rope_table(float* __restrict__ rope) {
    int idx = blockIdx.x * 256 + threadIdx.x;
    if (idx >= TT * 32) return;
    int t = idx >> 5, i = idx & 31;
    float freq = expf(-(float)i * (1.0f / 32.0f) * 9.210340371976184f); // 10000^(-i/32)
    float ang = (float)t * freq;
    rope[idx * 2 + 0] = cosf(ang);
    rope[idx * 2 + 1] = sinf(ang);
}

// ---------------------------------------------------------------------------
// RMSNorm: f32 [4096][1024] -> bf16 [4096][1024].  block 256 = one row
// ---------------------------------------------------------------------------
__global__ __launch_bounds__(256) void k_rmsnorm(const float* __restrict__ x,
                                                 const float* __restrict__ w,
                                                 short* __restrict__ out) {
    int row = blockIdx.x, t = threadIdx.x;
    float4 v = ((const float4*)(x + (size_t)row * TC))[t];
    float ss = v.x * v.x + v.y * v.y + v.z * v.z + v.w * v.w;
    #pragma unroll
    for (int off = 32; off; off >>= 1) ss += __shfl_xor(ss, off);
    __shared__ float red[4];
    if ((t & 63) == 0) red[t >> 6] = ss;
    __syncthreads();
    float rs = rsqrtf((red[0] + red[1] + red[2] + red[3]) * (1.0f / 1024.0f) + 1e-6f);
    float4 wv = ((const float4*)w)[t];
    short4 o;
    o.x = f2bf(v.x * rs * wv.x);
    o.y = f2bf(v.y * rs * wv.y);
    o.z = f2bf(v.z * rs * wv.z);
    o.w = f2bf(v.w * rs * wv.w);
    ((short4*)(out + (size_t)row * TC))[t] = o;
}

// ---------------------------------------------------------------------------
// 128x128 GEMM, counted-vmcnt double-buffer (T4): loads never drained to 0.
// C[M,N] = A[M,K](bf16) * Bt[N,K](bf16)
// EPI 0: out bf16 = acc;   EPI 1: out f32 = acc + resid
// grid (N/128, M/128), block 256
// ---------------------------------------------------------------------------
template <int EPI>
__global__ __launch_bounds__(256) void k_gemm128(const short* __restrict__ A,
                                                 const short* __restrict__ Bt,
                                                 void* __restrict__ outp,
                                                 const float* __restrict__ resid,
                                                 int M, int N, int K) {
    __shared__ short As0[128 * 32], As1[128 * 32];
    __shared__ short Bs0[128 * 32], Bs1[128 * 32];
    int tid = threadIdx.x;
    int brow = blockIdx.y * 128, bcol = blockIdx.x * 128;
    int wid = tid >> 6, lane = tid & 63;
    int wr = wid >> 1, wc = wid & 1, g = lane >> 4, c = lane & 15;
    int srow = wid * 32 + (lane >> 2);
    int scol = (lane & 3) * 8;
    const short* Ag0 = A + (size_t)(brow + srow) * K + scol;
    const short* Ag1 = A + (size_t)(brow + srow + 16) * K + scol;
    const short* Bg0 = Bt + (size_t)(bcol + srow) * K + scol;
    const short* Bg1 = Bt + (size_t)(bcol + srow + 16) * K + scol;
    int loff = __builtin_amdgcn_readfirstlane(wid * 2048);
    f32x4 acc[4][4] = {};
    auto stage = [&](int kq, short* A_, short* B_) {
        gl_lds16(Ag0 + kq, (char*)A_ + loff);
        gl_lds16(Ag1 + kq, (char*)A_ + loff + 1024);
        gl_lds16(Bg0 + kq, (char*)B_ + loff);
        gl_lds16(Bg1 + kq, (char*)B_ + loff + 1024);
    };
    stage(0, As0, Bs0);
    stage(32, As1, Bs1);
    WAIT_VM(4);
    __builtin_amdgcn_s_barrier();
    const int T = K >> 5;
    for (int t = 0; t < T; ++t) {
        short* Ac = (t & 1) ? As1 : As0;
        short* Bc = (t & 1) ? Bs1 : Bs0;
        s16x8 af[4], bf[4];
        #pragma unroll
        for (int m = 0; m < 4; m++) af[m] = *(const s16x8*)(Ac + (wr * 64 + m * 16 + c) * 32 + g * 8);
        #pragma unroll
        for (int n = 0; n < 4; n++) bf[n] = *(const s16x8*)(Bc + (wc * 64 + n * 16 + c) * 32 + g * 8);
        WAIT_LGKM0();
        __builtin_amdgcn_sched_barrier(0);
        __builtin_amdgcn_s_barrier();               // all waves done reading buf[cur]
        if (t + 2 < T) {
            stage((t + 2) << 5, Ac, Bc);            // overwrite consumed buffer
            WAIT_VM(4);                             // tile t+1 landed (mine)
        } else if (t + 1 < T) {
            WAIT_VM(0);
        }
        __builtin_amdgcn_s_barrier();               // everyone's t+1 landed
        __builtin_amdgcn_sched_barrier(0);
        __builtin_amdgcn_s_setprio(1);
        #pragma unroll
        for (int m = 0; m < 4; m++)
            #pragma unroll
            for (int n = 0; n < 4; n++)
                acc[m][n] = __builtin_amdgcn_mfma_f32_16x16x32_bf16(af[m], bf[n], acc[m][n], 0, 0, 0);
        __builtin_amdgcn_s_setprio(0);
    }
    #pragma unroll
    for (int m = 0; m < 4; m++)
        #pragma unroll
        for (int n = 0; n < 4; n++)
            #pragma unroll
            for (int j = 0; j < 4; j++) {
                int row = brow + wr * 64 + m * 16 + g * 4 + j;
                int col = bcol + wc * 64 + n * 16 + c;
                float v = acc[m][n][j];
                if (EPI == 0)
                    ((short*)outp)[(size_t)row * N + col] = f2bf(v);
                else
                    ((float*)outp)[(size_t)row * N + col] = v + resid[(size_t)row * N + col];
            }
}

// ---------------------------------------------------------------------------
// 128x64 GEMM, counted-vmcnt double-buffer.
// grid (N/64, M/128), block 256
// ---------------------------------------------------------------------------
template <int EPI>
__global__ __launch_bounds__(256) void k_gemm64(const short* __restrict__ A,
                                                const short* __restrict__ Bt,
                                                void* __restrict__ outp,
                                                const float* __restrict__ resid,
                                                int M, int N, int K) {
    __shared__ short As0[128 * 32], As1[128 * 32];
    __shared__ short Bs0[64 * 32], Bs1[64 * 32];
    int tid = threadIdx.x;
    int brow = blockIdx.y * 128, bcol = blockIdx.x * 64;
    int wid = tid >> 6, lane = tid & 63;
    int wr = wid >> 1, wc = wid & 1, g = lane >> 4, c = lane & 15;
    int srow = wid * 32 + (lane >> 2);
    int scol = (lane & 3) * 8;
    const short* Ag0 = A + (size_t)(brow + srow) * K + scol;
    const short* Ag1 = A + (size_t)(brow + srow + 16) * K + scol;
    int sbrow = wid * 16 + (lane >> 2);
    const short* Bg = Bt + (size_t)(bcol + sbrow) * K + scol;
    int loffA = __builtin_amdgcn_readfirstlane(wid * 2048);
    int loffB = __builtin_amdgcn_readfirstlane(wid * 1024);
    f32x4 acc[4][2] = {};
    auto stage = [&](int kq, short* A_, short* B_) {
        gl_lds16(Ag0 + kq, (char*)A_ + loffA);
        gl_lds16(Ag1 + kq, (char*)A_ + loffA + 1024);
        gl_lds16(Bg + kq, (char*)B_ + loffB);
    };
    stage(0, As0, Bs0);
    stage(32, As1, Bs1);
    WAIT_VM(3);
    __builtin_amdgcn_s_barrier();
    const int T = K >> 5;
    for (int t = 0; t < T; ++t) {
        short* Ac = (t & 1) ? As1 : As0;
        short* Bc = (t & 1) ? Bs1 : Bs0;
        s16x8 af[4], bf[2];
        #pragma unroll
        for (int m = 0; m < 4; m++) af[m] = *(const s16x8*)(Ac + (wr * 64 + m * 16 + c) * 32 + g * 8);
        #pragma unroll
        for (int n = 0; n < 2; n++) bf[n] = *(const s16x8*)(Bc + (wc * 32 + n * 16 + c) * 32 + g * 8);
        WAIT_LGKM0();
        __builtin_amdgcn_sched_barrier(0);
        __builtin_amdgcn_s_barrier();
        if (t + 2 < T) {
            stage((t + 2) << 5, Ac, Bc);
            WAIT_VM(3);
        } else if (t + 1 < T) {
            WAIT_VM(0);
        }
        __builtin_amdgcn_s_barrier();
        __builtin_amdgcn_sched_barrier(0);
        __builtin_amdgcn_s_setprio(1);
        #pragma unroll
        for (int m = 0; m < 4; m++)
            #pragma unroll
            for (int n = 0; n < 2; n++)
                acc[m][n] = __builtin_amdgcn_mfma_f32_16x16x32_bf16(af[m], bf[n], acc[m][n], 0, 0, 0);
        __builtin_amdgcn_s_setprio(0);
    }
    #pragma unroll
    for (int m = 0; m < 4; m++)
        #pragma unroll
        for (int n = 0; n < 2; n++)
            #pragma unroll
            for (int j = 0; j < 4; j++) {
                int row = brow + wr * 64 + m * 16 + g * 4 + j;
                int col = bcol + wc * 32 + n * 16 + c;
                float v = acc[m][n][j];
                if (EPI == 0)
                    ((short*)outp)[(size_t)row * N + col] = f2bf(v);
                else
                    ((float*)outp)[(size_t)row * N + col] = v + resid[(size_t)row * N + col];
            }
}

// ---------------------------------------------------------------------------
// RoPE apply (vectorized: short8 per thread).  q: 128 chunks, k: 32 chunks/row.
// grid (NTOK*160/256), block 256
// ---------------------------------------------------------------------------
__global__ void k_rope_apply(const short* __restrict__ qkv,
                             const float* __restrict__ rope,
                             short* __restrict__ q_r,
                             short* __restrict__ k_r) {
    int idx = blockIdx.x * 256 + threadIdx.x;
    if (idx >= NTOK * 160) return;
    int row = idx / 160;
    int p8 = idx - row * 160;
    int b = row >> 11, t = row & 2047;
    const short* src = qkv + (size_t)row * 1536;
    bool isq = p8 < 128;
    int pk = isq ? p8 : (p8 - 128);
    int hh = pk >> 3;
    int i0 = (pk & 7) * 8;
    int srcoff = (isq ? 0 : 1024) + hh * 64 + i0;
    s16x8 v = *(const s16x8*)(src + srcoff);
    const float* rp = rope + ((size_t)t * 32 + (i0 >> 1)) * 2;
    float4 r0 = *(const float4*)rp;
    float4 r1 = *(const float4*)(rp + 4);
    s16x8 ov;
    float cc, ss, x0, x1;
    cc = r0.x; ss = r0.y; x0 = bf2f(v[0]); x1 = bf2f(v[1]);
    ov[0] = f2bf(x0 * cc - x1 * ss); ov[1] = f2bf(x1 * cc + x0 * ss);
    cc = r0.z; ss = r0.w; x0 = bf2f(v[2]); x1 = bf2f(v[3]);
    ov[2] = f2bf(x0 * cc - x1 * ss); ov[3] = f2bf(x1 * cc + x0 * ss);
    cc = r1.x; ss = r1.y; x0 = bf2f(v[4]); x1 = bf2f(v[5]);
    ov[4] = f2bf(x0 * cc - x1 * ss); ov[5] = f2bf(x1 * cc + x0 * ss);
    cc = r1.z; ss = r1.w; x0 = bf2f(v[6]); x1 = bf2f(v[7]);
    ov[6] = f2bf(x0 * cc - x1 * ss); ov[7] = f2bf(x1 * cc + x0 * ss);
    if (isq)
        *(s16x8*)(q_r + ((size_t)(b * TH + hh) * TT + t) * THD + i0) = ov;
    else
        *(s16x8*)(k_r + ((size_t)(b * TKV + hh) * TT + t) * THD + i0) = ov;
}

// ---------------------------------------------------------------------------
// Flash attention, swapped-operand 32x32 structure (m214-style).
// exp2-domain softmax + defer-max (T13, THR=8 in log2 units).
// grid (16, B*H), block 256 = 4 independent waves; wave handles 32 q-rows.
// ---------------------------------------------------------------------------
__global__ __launch_bounds__(256) void k_attn(const short* __restrict__ q_r,
                                              const short* __restrict__ k_r,
                                              const short* __restrict__ v_t,
                                              short* __restrict__ attn_o) {
    int w = threadIdx.x >> 6, lane = threadIdx.x & 63;
    int qt = 63 - (blockIdx.x * 4 + w);     // long waves first
    int qbase = qt * 32;
    int bh = blockIdx.y;
    int b = bh >> 4, h = bh & 15, kv = h >> 2;
    int q32 = lane & 31, hi = lane >> 5;

    const short* qp = q_r + ((size_t)(b * TH + h) * TT + qbase) * THD;
    const short* kp = k_r + ((size_t)(b * TKV + kv) * TT) * THD;
    const short* vp = v_t + ((size_t)(b * TKV + kv) * THD) * TT;

    s16x8 qf[4];
    #pragma unroll
    for (int dc = 0; dc < 4; dc++)
        qf[dc] = *(const s16x8*)(qp + q32 * THD + dc * 16 + hi * 8);

    f32x16 ot0 = {}, ot1 = {};
    float mrun = -1e30f, lrun = 0.f;
    int nkt = (qbase + 95) >> 6;
    const float SC = 0.125f * 1.44269504088896f;   // 1/sqrt(64) * log2(e)

    for (int kt = 0; kt < nkt; kt++) {
        int ktb = kt * 64;
        f32x16 st0 = {}, st1 = {};
        s16x8 kf0[4], kf1[4];
        #pragma unroll
        for (int dc = 0; dc < 4; dc++) {
            kf0[dc] = *(const s16x8*)(kp + (size_t)(ktb + q32) * THD + dc * 16 + hi * 8);
            kf1[dc] = *(const s16x8*)(kp + (size_t)(ktb + 32 + q32) * THD + dc * 16 + hi * 8);
        }
        s16x8 vf[8];
        #pragma unroll
        for (int dt = 0; dt < 2; dt++)
            #pragma unroll
            for (int kc = 0; kc < 4; kc++)
                vf[dt * 4 + kc] = *(const s16x8*)(vp + (size_t)(dt * 32 + q32) * TT + ktb + kc * 16 + hi * 8);

        __builtin_amdgcn_s_setprio(1);
        #pragma unroll
        for (int dc = 0; dc < 4; dc++) {
            st0 = __builtin_amdgcn_mfma_f32_32x32x16_bf16(kf0[dc], qf[dc], st0, 0, 0, 0);
            st1 = __builtin_amdgcn_mfma_f32_32x32x16_bf16(kf1[dc], qf[dc], st1, 0, 0, 0);
        }
        __builtin_amdgcn_s_setprio(0);

        bool domask = (kt == nkt - 1);
        int qabs = qbase + q32;
        #pragma unroll
        for (int r = 0; r < 16; r++) {
            int kploc = (r & 3) + 8 * (r >> 2) + 4 * hi;
            float s0 = st0[r] * SC;
            float s1 = st1[r] * SC;
            if (domask) {
                if (ktb + kploc > qabs) s0 = -1e30f;
                if (ktb + 32 + kploc > qabs) s1 = -1e30f;
            }
            st0[r] = s0; st1[r] = s1;
        }
        float pm = st0[0];
        #pragma unroll
        for (int r = 1; r < 16; r++) pm = fmaxf(pm, st0[r]);
        #pragma unroll
        for (int r = 0; r < 16; r++) pm = fmaxf(pm, st1[r]);
        pm = fmaxf(pm, __shfl_xor(pm, 32));
        // defer-max: only rescale when some row grew by > 8 (P bounded by 2^8)
        if (__any(pm > mrun + 8.0f)) {
            float mnew = fmaxf(mrun, pm);
            float al = exp2f(mrun - mnew);
            mrun = mnew;
            lrun *= al;
            #pragma unroll
            for (int r = 0; r < 16; r++) { ot0[r] *= al; ot1[r] *= al; }
        }
        float rs = 0.f;
        #pragma unroll
        for (int r = 0; r < 16; r++) {
            float e0 = exp2f(st0[r] - mrun); st0[r] = e0; rs += e0;
            float e1 = exp2f(st1[r] - mrun); st1[r] = e1; rs += e1;
        }
        rs += __shfl_xor(rs, 32);
        lrun += rs;

        unsigned int w0[8], w1[8];
        #pragma unroll
        for (int j = 0; j < 8; j++) {
            w0[j] = cvtpk_bf16(st0[2 * j], st0[2 * j + 1]);
            w1[j] = cvtpk_bf16(st1[2 * j], st1[2 * j + 1]);
        }
        s16x8 pf[4];
        #pragma unroll
        for (int kc = 0; kc < 4; kc++) {
            unsigned int* ww = (kc < 2) ? w0 : w1;
            int kcl = kc & 1;
            unsigned int x0 = ww[4 * kcl + 0], y0 = ww[4 * kcl + 2];
            unsigned int x1 = ww[4 * kcl + 1], y1 = ww[4 * kcl + 3];
            asm volatile("v_permlane32_swap_b32 %0, %1" : "+v"(x0), "+v"(y0));
            asm volatile("v_permlane32_swap_b32 %0, %1" : "+v"(x1), "+v"(y1));
            unsigned int fr[4] = {x0, x1, y0, y1};
            pf[kc] = __builtin_bit_cast(s16x8, *(ulong2*)fr);
        }
        __builtin_amdgcn_s_setprio(1);
        #pragma unroll
        for (int kc = 0; kc < 4; kc++) {
            ot0 = __builtin_amdgcn_mfma_f32_32x32x16_bf16(vf[kc], pf[kc], ot0, 0, 0, 0);
            ot1 = __builtin_amdgcn_mfma_f32_32x32x16_bf16(vf[4 + kc], pf[kc], ot1, 0, 0, 0);
        }
        __builtin_amdgcn_s_setprio(0);
    }
    float inv = 1.0f / lrun;
    short* orow = attn_o + (size_t)(b * TT + qbase + q32) * TC + h * THD;
    #pragma unroll
    for (int s = 0; s < 4; s++) {
        short4 v0, v1;
        v0.x = f2bf(ot0[4 * s + 0] * inv); v0.y = f2bf(ot0[4 * s + 1] * inv);
        v0.z = f2bf(ot0[4 * s + 2] * inv); v0.w = f2bf(ot0[4 * s + 3] * inv);
        v1.x = f2bf(ot1[4 * s + 0] * inv); v1.y = f2bf(ot1[4 * s + 1] * inv);
        v1.z = f2bf(ot1[4 * s + 2] * inv); v1.w = f2bf(ot1[4 * s + 3] * inv);
        *(short4*)(orow + 8 * s + 4 * hi) = v0;
        *(short4*)(orow + 32 + 8 * s + 4 * hi) = v1;
    }
}

// ---------------------------------------------------------------------------
// Gate: f32 logits from x1 (recompute rms in f32), softmax, top-2, counts.
// ---------------------------------------------------------------------------
__global__ __launch_bounds__(256) void k_gate(const float* __restrict__ x1,
                                              const float* __restrict__ n2w,
                                              const float* __restrict__ gate_w,
                                              float* __restrict__ gl,
                                              int* __restrict__ cnt,
                                              int* __restrict__ te,
                                              int* __restrict__ tls,
                                              float* __restrict__ tw) {
    int w = threadIdx.x >> 6, lane = threadIdx.x & 63;
    int n = blockIdx.x * 4 + w;
    const float* xp = x1 + (size_t)n * TC;
    float ss = 0.f;
    for (int i = lane; i < TC; i += 64) { float v = xp[i]; ss += v * v; }
    #pragma unroll
    for (int off = 32; off; off >>= 1) ss += __shfl_xor(ss, off);
    float rs = rsqrtf(ss * (1.0f / 1024.0f) + 1e-6f);
    int e = lane & 7, ch = lane >> 3;
    float acc = 0.f;
    for (int i = 0; i < 128; i++) {
        int cc = ch * 128 + i;
        acc += xp[cc] * rs * n2w[cc] * gate_w[(size_t)cc * TE + e];
    }
    acc += __shfl_xor(acc, 8);
    acc += __shfl_xor(acc, 16);
    acc += __shfl_xor(acc, 32);
    float logit = acc;
    if (lane < 8) gl[(size_t)n * TE + lane] = logit;
    float mx = logit;
    mx = fmaxf(mx, __shfl_xor(mx, 1)); mx = fmaxf(mx, __shfl_xor(mx, 2)); mx = fmaxf(mx, __shfl_xor(mx, 4));
    float ex = __expf(logit - mx);
    float sm = ex;
    sm += __shfl_xor(sm, 1); sm += __shfl_xor(sm, 2); sm += __shfl_xor(sm, 4);
    float pp = ex / sm;
    float m1 = pp;
    m1 = fmaxf(m1, __shfl_xor(m1, 1)); m1 = fmaxf(m1, __shfl_xor(m1, 2)); m1 = fmaxf(m1, __shfl_xor(m1, 4));
    int cand = (pp == m1) ? e : 8;
    int e0 = cand;
    e0 = min(e0, __shfl_xor(e0, 1)); e0 = min(e0, __shfl_xor(e0, 2)); e0 = min(e0, __shfl_xor(e0, 4));
    float p2 = (e == e0) ? -1.0f : pp;
    float m2 = p2;
    m2 = fmaxf(m2, __shfl_xor(m2, 1)); m2 = fmaxf(m2, __shfl_xor(m2, 2)); m2 = fmaxf(m2, __shfl_xor(m2, 4));
    int cand2 = (p2 == m2) ? e : 8;
    int e1 = cand2;
    e1 = min(e1, __shfl_xor(e1, 1)); e1 = min(e1, __shfl_xor(e1, 2)); e1 = min(e1, __shfl_xor(e1, 4));
    if (lane == 0) {
        int ls0 = atomicAdd(&cnt[e0], 1);
        int ls1 = atomicAdd(&cnt[e1], 1);
        te[n * 2] = e0; te[n * 2 + 1] = e1;
        tls[n * 2] = ls0; tls[n * 2 + 1] = ls1;
        tw[n * 2] = m1; tw[n * 2 + 1] = m2;
    }
}

__global__ void k_prefix(const int* __restrict__ cnt, int* __restrict__ basep) {
    if (threadIdx.x == 0) {
        int s = 0;
        for (int e = 0; e < TE; e++) { basep[e] = s; s += cnt[e]; }
    }
}

__global__ void k_scatter(const int* __restrict__ te, const int* __restrict__ tls,
                          const float* __restrict__ tw, const int* __restrict__ basep,
                          int* __restrict__ tlist, float* __restrict__ slotw,
                          int* __restrict__ sot) {
    int n = blockIdx.x * 256 + threadIdx.x;
    if (n >= NTOK) return;
    int s0 = basep[te[n * 2]] + tls[n * 2];
    int s1 = basep[te[n * 2 + 1]] + tls[n * 2 + 1];
    tlist[s0] = n; tlist[s1] = n;
    slotw[s0] = tw[n * 2]; slotw[s1] = tw[n * 2 + 1];
    sot[n * 2] = s0; sot[n * 2 + 1] = s1;
}

// ---------------------------------------------------------------------------
// Fused FFN-up dual GEMM, counted-vmcnt double-buffer.
// BM=128, BN=128 (2x64 dual), BK=32, 512 threads = 8 waves.
// z = 0..7: MoE experts (gathered rows, weight folded) -> he [slot][FE]
// z = 8:    shared FFN -> shm [n][FS]
// grid (16, 32, 9), block 512
// ---------------------------------------------------------------------------
__global__ __launch_bounds__(512) void k_ffn(const short* __restrict__ A,
                                             const short* __restrict__ eB1,
                                             const short* __restrict__ eB2,
                                             const short* __restrict__ sB1,
                                             const short* __restrict__ sB2,
                                             short* __restrict__ he,
                                             short* __restrict__ shm,
                                             const int* __restrict__ cnt,
                                             const int* __restrict__ basep,
                                             const int* __restrict__ tlist,
                                             const float* __restrict__ slotw) {
    int z = blockIdx.z;
    int moe = (z < 8);
    int nt = blockIdx.x, mt = blockIdx.y;
    int ce = 0, base = 0;
    if (moe) {
        if (nt >= 8) return;              // expert FE = 1024 -> 8 col tiles
        ce = cnt[z];
        if (mt * 128 >= ce) return;
        base = basep[z];
    }
    __shared__ short As0[128 * 32], As1[128 * 32];
    __shared__ short B1s0[128 * 32], B1s1[128 * 32];
    __shared__ short B2s0[128 * 32], B2s1[128 * 32];
    int tid = threadIdx.x, wid = tid >> 6, lane = tid & 63;
    int wr = wid >> 2, wc = wid & 3, g = lane >> 4, c = lane & 15;
    const int K = TC;
    int srow = wid * 16 + (lane >> 2);
    int scol = (lane & 3) * 8;
    size_t arow;
    if (moe) {
        int l0 = mt * 128 + srow; if (l0 >= ce) l0 = ce - 1;
        arow = (size_t)tlist[base + l0];
    } else {
        arow = (size_t)(mt * 128 + srow);
    }
    const short* Ag = A + arow * (size_t)K + scol;
    const short* B1g;
    const short* B2g;
    if (moe) {
        B1g = eB1 + ((size_t)z * TFE + (size_t)(nt * 128 + srow)) * K + scol;
        B2g = eB2 + ((size_t)z * TFE + (size_t)(nt * 128 + srow)) * K + scol;
    } else {
        B1g = sB1 + (size_t)(nt * 128 + srow) * K + scol;
        B2g = sB2 + (size_t)(nt * 128 + srow) * K + scol;
    }
    int loff = __builtin_amdgcn_readfirstlane(wid * 1024);
    f32x4 a1[4][2] = {}, a2[4][2] = {};
    auto stage = [&](int kq, short* A_, short* B1_, short* B2_) {
        gl_lds16(Ag + kq, (char*)A_ + loff);
        gl_lds16(B1g + kq, (char*)B1_ + loff);
        gl_lds16(B2g + kq, (char*)B2_ + loff);
    };
    stage(0, As0, B1s0, B2s0);
    stage(32, As1, B1s1, B2s1);
    WAIT_VM(3);
    __builtin_amdgcn_s_barrier();
    const int T = K >> 5;   // 32
    for (int t = 0; t < T; ++t) {
        short* Ac = (t & 1) ? As1 : As0;
        short* B1c = (t & 1) ? B1s1 : B1s0;
        short* B2c = (t & 1) ? B2s1 : B2s0;
        s16x8 af[4], b1[2], b2[2];
        #pragma unroll
        for (int m_ = 0; m_ < 4; m_++) af[m_] = *(const s16x8*)(Ac + (wr * 64 + m_ * 16 + c) * 32 + g * 8);
        #pragma unroll
        for (int n = 0; n < 2; n++) {
            b1[n] = *(const s16x8*)(B1c + (wc * 32 + n * 16 + c) * 32 + g * 8);
            b2[n] = *(const s16x8*)(B2c + (wc * 32 + n * 16 + c) * 32 + g * 8);
        }
        WAIT_LGKM0();
        __builtin_amdgcn_sched_barrier(0);
        __builtin_amdgcn_s_barrier();
        if (t + 2 < T) {
            stage((t + 2) << 5, Ac, B1c, B2c);
            WAIT_VM(3);
        } else if (t + 1 < T) {
            WAIT_VM(0);
        }
        __builtin_amdgcn_s_barrier();
        __builtin_amdgcn_sched_barrier(0);
        __builtin_amdgcn_s_setprio(1);
        #pragma unroll
        for (int m_ = 0; m_ < 4; m_++)
            #pragma unroll
            for (int n = 0; n < 2; n++) {
                a1[m_][n] = __builtin_amdgcn_mfma_f32_16x16x32_bf16(af[m_], b1[n], a1[m_][n], 0, 0, 0);
                a2[m_][n] = __builtin_amdgcn_mfma_f32_16x16x32_bf16(af[m_], b2[n], a2[m_][n], 0, 0, 0);
            }
        __builtin_amdgcn_s_setprio(0);
    }
    #pragma unroll
    for (int m_ = 0; m_ < 4; m_++)
        #pragma unroll
        for (int n = 0; n < 2; n++)
            #pragma unroll
            for (int j = 0; j < 4; j++) {
                int lrow = mt * 128 + wr * 64 + m_ * 16 + g * 4 + j;
                if (moe && lrow >= ce) continue;
                int col = nt * 128 + wc * 32 + n * 16 + c;
                float g1 = a1[m_][n][j], g2 = a2[m_][n][j];
                float v = g1 / (1.0f + __expf(-g1)) * g2;
                if (moe) {
                    v *= slotw[base + lrow];
                    he[(size_t)(base + lrow) * TFE + col] = f2bf(v);
                } else {
                    shm[(size_t)lrow * TFS + col] = f2bf(v);
                }
            }
}

// ---------------------------------------------------------------------------
// MoE down-proj per expert: ye[slot] = he[slot] @ wp_e.  128x128, counted dbuf.
// grid (8, 32, 8), block 256
// ---------------------------------------------------------------------------
__global__ __launch_bounds__(256) void k_moe2(const short* __restrict__ he,
                                              const short* __restrict__ Wpt,
                                              short* __restrict__ ye,
                                              const int* __restrict__ cnt,
                                              const int* __restrict__ basep) {
    int e = blockIdx.z;
    int ce = cnt[e];
    int mt = blockIdx.y;
    if (mt * 128 >= ce) return;
    int base = basep[e];
    int nt = blockIdx.x;
    __shared__ short As0[128 * 32], As1[128 * 32];
    __shared__ short Bs0[128 * 32], Bs1[128 * 32];
    int tid = threadIdx.x, wid = tid >> 6, lane = tid & 63;
    int wr = wid >> 1, wc = wid & 1, g = lane >> 4, c = lane & 15;
    int srow = wid * 32 + (lane >> 2);
    int scol = (lane & 3) * 8;
    const short* Ag0 = he + (size_t)(base + mt * 128 + srow) * TFE + scol;
    const short* Ag1 = Ag0 + (size_t)16 * TFE;
    const short* Bg0 = Wpt + ((size_t)e * 1024 + nt * 128 + srow) * TFE + scol;
    const short* Bg1 = Bg0 + (size_t)16 * TFE;
    int loff = __builtin_amdgcn_readfirstlane(wid * 2048);
    f32x4 acc[4][4] = {};
    auto stage = [&](int kq, short* A_, short* B_) {
        gl_lds16(Ag0 + kq, (char*)A_ + loff);
        gl_lds16(Ag1 + kq, (char*)A_ + loff + 1024);
        gl_lds16(Bg0 + kq, (char*)B_ + loff);
        gl_lds16(Bg1 + kq, (char*)B_ + loff + 1024);
    };
    stage(0, As0, Bs0);
    stage(32, As1, Bs1);
    WAIT_VM(4);
    __builtin_amdgcn_s_barrier();
    const int T = TFE >> 5;
    for (int t = 0; t < T; ++t) {
        short* Ac = (t & 1) ? As1 : As0;
        short* Bc = (t & 1) ? Bs1 : Bs0;
        s16x8 af[4], bf[4];
        #pragma unroll
        for (int m = 0; m < 4; m++) af[m] = *(const s16x8*)(Ac + (wr * 64 + m * 16 + c) * 32 + g * 8);
        #pragma unroll
        for (int n = 0; n < 4; n++) bf[n] = *(const s16x8*)(Bc + (wc * 64 + n * 16 + c) * 32 + g * 8);
        WAIT_LGKM0();
        __builtin_amdgcn_sched_barrier(0);
        __builtin_amdgcn_s_barrier();
        if (t + 2 < T) {
            stage((t + 2) << 5, Ac, Bc);
            WAIT_VM(4);
        } else if (t + 1 < T) {
            WAIT_VM(0);
        }
        __builtin_amdgcn_s_barrier();
        __builtin_amdgcn_sched_barrier(0);
        __builtin_amdgcn_s_setprio(1);
        #pragma unroll
        for (int m = 0; m < 4; m++)
            #pragma unroll
            for (int n = 0; n < 4; n++)
                acc[m][n] = __builtin_amdgcn_mfma_f32_16x16x32_bf16(af[m], bf[n], acc[m][n], 0, 0, 0);
        __builtin_amdgcn_s_setprio(0);
    }
    #pragma unroll
    for (int m = 0; m < 4; m++)
        #pragma unroll
        for (int n = 0; n < 4; n++)
            #pragma unroll
            for (int j = 0; j < 4; j++) {
                int lrow = mt * 128 + wr * 64 + m * 16 + g * 4 + j;
                if (lrow >= ce) continue;
                int col = nt * 128 + wc * 64 + n * 16 + c;
                ye[(size_t)(base + lrow) * TC + col] = f2bf(acc[m][n][j]);
            }
}

// ---------------------------------------------------------------------------
// Final: out = shm @ swp_t + x1 + ye[s0] + ye[s1].  M=4096 N=1024 K=2048
// BM=128 BN=64, counted dbuf.  grid (16, 32)
// ---------------------------------------------------------------------------
__global__ __launch_bounds__(256) void k_final(const short* __restrict__ A,
                                               const short* __restrict__ Bt,
                                               const float* __restrict__ x1,
                                               const short* __restrict__ ye,
                                               const int* __restrict__ sot,
                                               float* __restrict__ outp) {
    __shared__ short As0[128 * 32], As1[128 * 32];
    __shared__ short Bs0[64 * 32], Bs1[64 * 32];
    const int K = TFS;
    int tid = threadIdx.x;
    int brow = blockIdx.y * 128, bcol = blockIdx.x * 64;
    int wid = tid >> 6, lane = tid & 63;
    int wr = wid >> 1, wc = wid & 1, g = lane >> 4, c = lane & 15;
    int srow = wid * 32 + (lane >> 2);
    int scol = (lane & 3) * 8;
    const short* Ag0 = A + (size_t)(brow + srow) * K + scol;
    const short* Ag1 = A + (size_t)(brow + srow + 16) * K + scol;
    int sbrow = wid * 16 + (lane >> 2);
    const short* Bg = Bt + (size_t)(bcol + sbrow) * K + scol;
    int loffA = __builtin_amdgcn_readfirstlane(wid * 2048);
    int loffB = __builtin_amdgcn_readfirstlane(wid * 1024);
    f32x4 acc[4][2] = {};
    auto stage = [&](int kq, short* A_, short* B_) {
        gl_lds16(Ag0 + kq, (char*)A_ + loffA);
        gl_lds16(Ag1 + kq, (char*)A_ + loffA + 1024);
        gl_lds16(Bg + kq, (char*)B_ + loffB);
    };
    stage(0, As0, Bs0);
    stage(32, As1, Bs1);
    WAIT_VM(3);
    __builtin_amdgcn_s_barrier();
    const int T = K >> 5;   // 64
    for (int t = 0; t < T; ++t) {
        short* Ac = (t & 1) ? As1 : As0;
        short* Bc = (t & 1) ? Bs1 : Bs0;
        s16x8 af[4], bf[2];
        #pragma unroll
        for (int m = 0; m < 4; m++) af[m] = *(const s16x8*)(Ac + (wr * 64 + m * 16 + c) * 32 + g * 8);
        #pragma unroll
        for (int n = 0; n < 2; n++) bf[n] = *(const s16x8*)(Bc + (wc * 32 + n * 16 + c) * 32 + g * 8);
        WAIT_LGKM0();
        __builtin_amdgcn_sched_barrier(0);
        __builtin_amdgcn_s_barrier();
        if (t + 2 < T) {
            stage((t + 2) << 5, Ac, Bc);
            WAIT_VM(3);
        } else if (t + 1 < T) {
            WAIT_VM(0);
        }
        __builtin_amdgcn_s_barrier();
        __builtin_amdgcn_sched_barrier(0);
        __builtin_amdgcn_s_setprio(1);
        #pragma unroll
        for (int m = 0; m < 4; m++)
            #pragma unroll
            for (int n = 0; n < 2; n++)
                acc[m][n] = __builtin_amdgcn_mfma_f32_16x16x32_bf16(af[m], bf[n], acc[m][n], 0, 0, 0);
        __builtin_amdgcn_s_setprio(0);
    }
    #pragma unroll
    for (int m = 0; m < 4; m++)
        #pragma unroll
        for (int n = 0; n < 2; n++)
            #pragma unroll
            for (int j = 0; j < 4; j++) {
                int row = brow + wr * 64 + m * 16 + g * 4 + j;
                int col = bcol + wc * 32 + n * 16 + c;
                int s0 = sot[row * 2], s1 = sot[row * 2 + 1];
                float v = acc[m][n][j] + x1[(size_t)row * TC + col]
                        + bf2f(ye[(size_t)s0 * TC + col]) + bf2f(ye[(size_t)s1 * TC + col]);
                outp[(size_t)row * TC + col] = v;
            }
}

// ---------------------------------------------------------------------------
// Launch
// ---------------------------------------------------------------------------
extern "C" void kernel_launch(void* const* d_in, const int* in_sizes, int n_in,
                              void* d_out, int out_size, void* d_ws, size_t ws_size,
                              hipStream_t stream) {
    const float* x     = (const float*)d_in[0];
    const float* n1w   = (const float*)d_in[1];
    const float* n2w   = (const float*)d_in[2];
    const float* wq    = (const float*)d_in[3];
    const float* wk    = (const float*)d_in[4];
    const float* wv    = (const float*)d_in[5];
    const float* wo    = (const float*)d_in[6];
    const float* gatew = (const float*)d_in[7];
    const float* ew1   = (const float*)d_in[8];
    const float* ew2   = (const float*)d_in[9];
    const float* ewp   = (const float*)d_in[10];
    const float* sw1   = (const float*)d_in[11];
    const float* sw2   = (const float*)d_in[12];
    const float* swp   = (const float*)d_in[13];
    float* outp = (float*)d_out;

    char* p = (char*)d_ws;
    auto alloc = [&](size_t bytes) -> char* {
        char* r = p;
        p += (bytes + 255) & ~(size_t)255;
        return r;
    };
    short* wqkv_t = (short*)alloc(1536 * 1024 * 2);
    short* wo_t   = (short*)alloc(1024 * 1024 * 2);
    short* ew1_t  = (short*)alloc((size_t)8 * 1024 * 1024 * 2);
    short* ew2_t  = (short*)alloc((size_t)8 * 1024 * 1024 * 2);
    short* ewp_t  = (short*)alloc((size_t)8 * 1024 * 1024 * 2);
    short* sw1_t  = (short*)alloc((size_t)2048 * 1024 * 2);
    short* sw2_t  = (short*)alloc((size_t)2048 * 1024 * 2);
    short* swp_t  = (short*)alloc((size_t)1024 * 2048 * 2);
    short* h1     = (short*)alloc((size_t)NTOK * 1024 * 2);
    short* qkv    = (short*)alloc((size_t)NTOK * 1536 * 2);
    short* q_r    = (short*)alloc((size_t)TB * TH * TT * THD * 2);
    short* k_r    = (short*)alloc((size_t)TB * TKV * TT * THD * 2);
    short* v_t    = (short*)alloc((size_t)TB * TKV * THD * TT * 2);
    short* attn_o = (short*)alloc((size_t)NTOK * 1024 * 2);
    float* x1     = (float*)alloc((size_t)NTOK * 1024 * 4);
    short* h2     = (short*)alloc((size_t)NTOK * 1024 * 2);
    float* rope   = (float*)alloc((size_t)TT * 32 * 2 * 4);
    int*   cnt    = (int*)alloc(256);
    int*   basep  = (int*)alloc(256);
    int*   te     = (int*)alloc((size_t)NTOK * 2 * 4);
    int*   tls    = (int*)alloc((size_t)NTOK * 2 * 4);
    float* tw     = (float*)alloc((size_t)NTOK * 2 * 4);
    int*   tlist  = (int*)alloc((size_t)NSLOT * 4);
    float* slotw  = (float*)alloc((size_t)NSLOT * 4);
    int*   sot    = (int*)alloc((size_t)NTOK * 2 * 4);
    short* he     = (short*)alloc((size_t)NSLOT * TFE * 2);
    short* ye     = (short*)alloc((size_t)NSLOT * TC * 2);
    short* shm    = (short*)alloc((size_t)NTOK * TFS * 2);

    dim3 blk(256);

    k_transp<<<dim3(32, 32, 1), blk, 0, stream>>>(wq, wqkv_t, 1024, 1024, 0, 0);
    k_transp<<<dim3(8, 32, 1), blk, 0, stream>>>(wk, wqkv_t + 1024 * 1024, 1024, 256, 0, 0);
    k_transp<<<dim3(8, 32, 1), blk, 0, stream>>>(wv, wqkv_t + 1280 * 1024, 1024, 256, 0, 0);
    k_transp<<<dim3(32, 32, 1), blk, 0, stream>>>(wo, wo_t, 1024, 1024, 0, 0);
    k_transp<<<dim3(32, 32, 8), blk, 0, stream>>>(ew1, ew1_t, 1024, 1024, 1048576, 1048576);
    k_transp<<<dim3(32, 32, 8), blk, 0, stream>>>(ew2, ew2_t, 1024, 1024, 1048576, 1048576);
    k_transp<<<dim3(32, 32, 8), blk, 0, stream>>>(ewp, ewp_t, 1024, 1024, 1048576, 1048576);
    k_transp<<<dim3(64, 32, 1), blk, 0, stream>>>(sw1, sw1_t, 1024, 2048, 0, 0);
    k_transp<<<dim3(64, 32, 1), blk, 0, stream>>>(sw2, sw2_t, 1024, 2048, 0, 0);
    k_transp<<<dim3(32, 64, 1), blk, 0, stream>>>(swp, swp_t, 2048, 1024, 0, 0);

    k_rope_table<<<(TT * 32 + 255) / 256, blk, 0, stream>>>(rope);

    k_rmsnorm<<<NTOK, blk, 0, stream>>>(x, n1w, h1);
    k_gemm128<0><<<dim3(12, 32), blk, 0, stream>>>(h1, wqkv_t, qkv, nullptr, NTOK, 1536, 1024);
    k_rope_apply<<<(NTOK * 160 + 255) / 256, blk, 0, stream>>>(qkv, rope, q_r, k_r);
    k_transp_v<<<dim3(2, 64, 8), blk, 0, stream>>>(qkv, v_t);

    k_attn<<<dim3(16, TB * TH), blk, 0, stream>>>(q_r, k_r, v_t, attn_o);

    k_gemm64<1><<<dim3(16, 32), blk, 0, stream>>>(attn_o, wo_t, x1, x, NTOK, 1024, 1024);

    k_rmsnorm<<<NTOK, blk, 0, stream>>>(x1, n2w, h2);

    hipMemsetAsync(cnt, 0, 64, stream);
    k_gate<<<NTOK / 4, blk, 0, stream>>>(x1, n2w, gatew, outp + (size_t)NTOK * TC, cnt, te, tls, tw);
    k_prefix<<<1, 64, 0, stream>>>(cnt, basep);
    k_scatter<<<NTOK / 256, blk, 0, stream>>>(te, tls, tw, basep, tlist, slotw, sot);

    k_ffn<<<dim3(16, 32, 9), dim3(512), 0, stream>>>(h2, ew1_t, ew2_t, sw1_t, sw2_t, he, shm,
                                                     cnt, basep, tlist, slotw);
    k_moe2<<<dim3(8, 32, 8), blk, 0, stream>>>(he, ewp_t, ye, cnt, basep);

    k_final<<<dim3(16, 32), blk, 0, stream>>>(shm, swp_t, x1, ye, sot, outp);

    (void)in_sizes; (void)n_in; (void)out_size; (void)ws_size;
}